// Round 1
// baseline (7016.511 us; speedup 1.0000x reference)
//
#include <hip/hip_runtime.h>
#include <hip/hip_bf16.h>

// Problem dims
#define B4 4
#define S128 128
#define T129 129
#define H800 800
#define G3200 3200
#define E256 256
#define NE 66
#define NR 122

// ---------------------------------------------------------------------------
// gelu (jax approximate=True): 0.5*x*(1+tanh(sqrt(2/pi)*(x+0.044715 x^3)))
__device__ __forceinline__ float gelu_f(float x) {
    float t = 0.7978845608028654f * (x + 0.044715f * x * x * x);
    float e = __expf(2.f * t);           // overflow -> inf -> th=1 ; underflow -> 0 -> th=-1
    float th = 1.f - 2.f / (e + 1.f);
    return 0.5f * x * (1.f + th);
}

// ---------------------------------------------------------------------------
// K_embed: x[b,t,0:768]=bert, x[b,t,768:800]=pos_table[pos_ids[b,t-1]] (0 for t=0)
__global__ void k_embed(const float* __restrict__ bert, const int* __restrict__ pos_ids,
                        const float* __restrict__ ptab, float* __restrict__ x)
{
    int idx = blockIdx.x * 256 + threadIdx.x;
    if (idx >= B4 * T129 * H800) return;
    int c = idx % H800;
    int bt = idx / H800;
    int t = bt % T129, b = bt / T129;
    float v;
    if (c < 768) v = bert[(size_t)bt * 768 + c];
    else         v = (t == 0) ? 0.f : ptab[pos_ids[b * S128 + t - 1] * 32 + (c - 768)];
    x[idx] = v;
}

// ---------------------------------------------------------------------------
// Generic fp32 tiled GEMM. C[M,N] = A(M,K) * B  (+bias) with optional epilogue.
// AMODE: 0 direct row, 1 xg-view (row -> row + row/128 + 1)  [x[:,1:,:] view]
// BTRANS: 0: B is [K,N]; 1: B is [N,K] (A @ B^T)
// EPI: 0: C = acc (+bias); 1: C = res + relu(acc+bias)
template<int AMODE, int BTRANS, int EPI>
__global__ __launch_bounds__(256) void k_gemm(const float* __restrict__ A, const float* __restrict__ Bm,
                                              const float* __restrict__ bias, const float* __restrict__ res,
                                              float* __restrict__ C, int M, int N, int K)
{
    __shared__ float As[16][68];
    __shared__ float Bs[16][68];
    int m0 = blockIdx.x * 64, n0 = blockIdx.y * 64;
    int tid = threadIdx.x;
    int tm = tid & 15, tn = tid >> 4;
    float acc[4][4] = {};
    for (int k0 = 0; k0 < K; k0 += 16) {
        // A tile: As[kk][mm]
        {
            int kk = tid & 15, mmb = tid >> 4;
            #pragma unroll
            for (int q = 0; q < 4; q++) {
                int mm = mmb + q * 16;
                int m = m0 + mm;
                float v = 0.f;
                if (m < M) {
                    int row = (AMODE == 1) ? (m + (m >> 7) + 1) : m;
                    v = A[(size_t)row * K + k0 + kk];
                }
                As[kk][mm] = v;
            }
        }
        // B tile: Bs[kk][nn]
        if (BTRANS == 0) {
            int nn = (tid & 15) * 4, kk2 = tid >> 4;
            int n = n0 + nn;
            float t0, t1, t2, t3;
            if (n + 3 < N) {
                const float4 bv = *(const float4*)&Bm[(size_t)(k0 + kk2) * N + n];
                t0 = bv.x; t1 = bv.y; t2 = bv.z; t3 = bv.w;
            } else {
                t0 = (n + 0 < N) ? Bm[(size_t)(k0 + kk2) * N + n + 0] : 0.f;
                t1 = (n + 1 < N) ? Bm[(size_t)(k0 + kk2) * N + n + 1] : 0.f;
                t2 = (n + 2 < N) ? Bm[(size_t)(k0 + kk2) * N + n + 2] : 0.f;
                t3 = (n + 3 < N) ? Bm[(size_t)(k0 + kk2) * N + n + 3] : 0.f;
            }
            Bs[kk2][nn + 0] = t0; Bs[kk2][nn + 1] = t1; Bs[kk2][nn + 2] = t2; Bs[kk2][nn + 3] = t3;
        } else {
            int kk = tid & 15, nnb = tid >> 4;
            #pragma unroll
            for (int q = 0; q < 4; q++) {
                int nn = nnb + q * 16;
                int n = n0 + nn;
                Bs[kk][nn] = (n < N) ? Bm[(size_t)n * K + k0 + kk] : 0.f;
            }
        }
        __syncthreads();
        #pragma unroll
        for (int kk = 0; kk < 16; kk++) {
            float4 a = *(const float4*)&As[kk][tm * 4];
            float4 bb = *(const float4*)&Bs[kk][tn * 4];
            float av[4] = {a.x, a.y, a.z, a.w};
            float bv[4] = {bb.x, bb.y, bb.z, bb.w};
            #pragma unroll
            for (int xx = 0; xx < 4; xx++)
                #pragma unroll
                for (int yy = 0; yy < 4; yy++)
                    acc[xx][yy] += av[xx] * bv[yy];
        }
        __syncthreads();
    }
    #pragma unroll
    for (int xx = 0; xx < 4; xx++) {
        int m = m0 + tm * 4 + xx;
        if (m >= M) continue;
        #pragma unroll
        for (int yy = 0; yy < 4; yy++) {
            int n = n0 + tn * 4 + yy;
            if (n >= N) continue;
            float v = acc[xx][yy];
            if (bias) v += bias[n];
            if (EPI == 1) v = res[(size_t)m * N + n] + fmaxf(v, 0.f);
            C[(size_t)m * N + n] = v;
        }
    }
}

// ---------------------------------------------------------------------------
// Persistent BiLSTM recurrence. Grid: 400 WGs x 256 thr. WGs [0,200) fwd, [200,400) bwd.
// Each WG owns 4 h-dims (all 4 gates, all 4 batches); Whh rows staged in LDS.
// h exchanged through lstm_out via agent-scope atomics; per-step spin barrier.
__global__ __launch_bounds__(256) void k_lstm(const float* __restrict__ xWf, const float* __restrict__ xWb,
                                              const float* __restrict__ Whhf, const float* __restrict__ Whhb,
                                              float* __restrict__ lstm, int* __restrict__ cnt)
{
    __shared__ float wl[16][802];   // 16 gate rows x 800 (pad 802)
    __shared__ float hb[4][800];    // current h, 4 batches
    __shared__ float gb[4][4][4];   // [gate][dim][batch]
    int wg = blockIdx.x;
    int dir = (wg >= 200) ? 1 : 0;
    int wgd = dir ? (wg - 200) : wg;
    const float* Whh = dir ? Whhb : Whhf;
    const float* xW  = dir ? xWb  : xWf;
    int d0 = wgd * 4;
    int tid = threadIdx.x;

    // one-time stage of the 16 Whh rows: row rr = gate(rr>>2)*800 + d0 + (rr&3)
    for (int rr = 0; rr < 16; rr++) {
        int g = (rr >> 2) * 800 + d0 + (rr & 3);
        for (int k = tid; k < 800; k += 256) wl[rr][k] = Whh[(size_t)g * 800 + k];
    }
    for (int i = tid; i < 3200; i += 256) (&hb[0][0])[i] = 0.f;
    __syncthreads();

    int wv = tid >> 6, l = tid & 63;
    int dl = l & 3;           // dim-local
    int slice = l >> 2;       // k-slice 0..15 (50 k each)
    int k0s = slice * 50;
    int gglob = wv * 800 + d0 + dl;   // this wave computes gate 'wv'
    float cst = 0.f;                  // c state (threads tid<16 only)

    for (int step = 0; step < 129; step++) {
        int t = dir ? (128 - step) : step;
        if (step > 0) {
            int tprev = dir ? (t + 1) : (t - 1);
            for (int i = tid; i < 3200; i += 256) {
                int bb = i / 800, dd = i - bb * 800;
                hb[bb][dd] = __hip_atomic_load(
                    &lstm[(size_t)((bb * T129 + tprev) * 1600) + dir * 800 + dd],
                    __ATOMIC_RELAXED, __HIP_MEMORY_SCOPE_AGENT);
            }
        }
        __syncthreads();
        // partial dot: gate row (wv, dl) x h[b], k in [k0s, k0s+50)
        float a0 = 0.f, a1 = 0.f, a2 = 0.f, a3 = 0.f;
        const float* wrow = &wl[(wv << 2) | dl][0];
        #pragma unroll 5
        for (int kk = k0s; kk < k0s + 50; kk += 2) {
            float w0 = wrow[kk], w1 = wrow[kk + 1];
            a0 += w0 * hb[0][kk] + w1 * hb[0][kk + 1];
            a1 += w0 * hb[1][kk] + w1 * hb[1][kk + 1];
            a2 += w0 * hb[2][kk] + w1 * hb[2][kk + 1];
            a3 += w0 * hb[3][kk] + w1 * hb[3][kk + 1];
        }
        // reduce over the 16 k-slices (lanes differing in bits 2..5)
        #pragma unroll
        for (int s = 4; s <= 32; s <<= 1) {
            a0 += __shfl_xor(a0, s, 64);
            a1 += __shfl_xor(a1, s, 64);
            a2 += __shfl_xor(a2, s, 64);
            a3 += __shfl_xor(a3, s, 64);
        }
        if (slice == 0) {
            gb[wv][dl][0] = a0 + xW[(size_t)(0 * T129 + t) * G3200 + gglob];
            gb[wv][dl][1] = a1 + xW[(size_t)(1 * T129 + t) * G3200 + gglob];
            gb[wv][dl][2] = a2 + xW[(size_t)(2 * T129 + t) * G3200 + gglob];
            gb[wv][dl][3] = a3 + xW[(size_t)(3 * T129 + t) * G3200 + gglob];
        }
        __syncthreads();
        if (tid < 16) {
            int d = tid & 3, bb = tid >> 2;
            float gi = gb[0][d][bb], gf = gb[1][d][bb], gg = gb[2][d][bb], go = gb[3][d][bb];
            float si = 1.f / (1.f + __expf(-gi));
            float sf = 1.f / (1.f + __expf(-gf));
            float so = 1.f / (1.f + __expf(-go));
            cst = sf * cst + si * tanhf(gg);
            float hv = so * tanhf(cst);
            __hip_atomic_store(&lstm[(size_t)((bb * T129 + t) * 1600) + dir * 800 + d0 + d], hv,
                               __ATOMIC_RELAXED, __HIP_MEMORY_SCOPE_AGENT);
        }
        if (step < 128) {
            __syncthreads();   // drains vmcnt: h stores are at the coherent point
            if (tid == 0) {
                __threadfence();
                __hip_atomic_fetch_add(&cnt[dir * 129 + step], 1, __ATOMIC_RELEASE, __HIP_MEMORY_SCOPE_AGENT);
                long long iters = 0;
                while (__hip_atomic_load(&cnt[dir * 129 + step], __ATOMIC_ACQUIRE, __HIP_MEMORY_SCOPE_AGENT) < 200) {
                    if (++iters > 200000000LL) break;   // safety valve vs deadlock
                    __builtin_amdgcn_s_sleep(8);
                }
            }
            __syncthreads();
        }
    }
}

// ---------------------------------------------------------------------------
// GAT attention coefficients: a_s[n,h] = sum_d h1[n,h*100+d]*asrc[h,d]; same a_d.
__global__ __launch_bounds__(256) void k_gat_coef(const float* __restrict__ h1,
                                                  const float* __restrict__ asrc, const float* __restrict__ adst,
                                                  float* __restrict__ a_s, float* __restrict__ a_d)
{
    int t = blockIdx.x * 256 + threadIdx.x;   // 512*8
    if (t >= 512 * 8) return;
    int h = t & 7, n = t >> 3;
    const float* hp = h1 + (size_t)n * H800 + h * 100;
    float s1 = 0.f, s2 = 0.f;
    for (int d = 0; d < 100; d++) {
        float hv = hp[d];
        s1 += hv * asrc[h * 100 + d];
        s2 += hv * adst[h * 100 + d];
    }
    a_s[t] = s1;
    a_d[t] = s2;
}

// Per (b,h): segment max + sum of exp over incident edges (incl self-loops).
__global__ __launch_bounds__(128) void k_gat_softmax(const int* __restrict__ esrc, const int* __restrict__ edst,
                                                     const float* __restrict__ a_s, const float* __restrict__ a_d,
                                                     float* __restrict__ mbuf, float* __restrict__ dbuf)
{
    __shared__ int se[384], de[384];
    __shared__ float asl[128], adl[128];
    int bh = blockIdx.x;
    int b = bh >> 3, h = bh & 7;
    int t = threadIdx.x;
    for (int e = t; e < 384; e += 128) {
        if (e < E256) { se[e] = esrc[b * E256 + e]; de[e] = edst[b * E256 + e]; }
        else          { se[e] = e - E256;           de[e] = e - E256; }
    }
    asl[t] = a_s[(b * S128 + t) * 8 + h];
    adl[t] = a_d[(b * S128 + t) * 8 + h];
    __syncthreads();
    float myad = adl[t];
    float m = -3.4e38f;
    for (int e = 0; e < 384; e++) {
        if (de[e] == t) {
            float sc = asl[se[e]] + myad;
            sc = (sc > 0.f) ? sc : 0.2f * sc;
            m = fmaxf(m, sc);
        }
    }
    float den = 0.f;
    for (int e = 0; e < 384; e++) {
        if (de[e] == t) {
            float sc = asl[se[e]] + myad;
            sc = (sc > 0.f) ? sc : 0.2f * sc;
            den += __expf(sc - m);
        }
    }
    mbuf[(b * S128 + t) * 8 + h] = m;
    dbuf[(b * S128 + t) * 8 + h] = den;
}

// Aggregate: out[n] = res[n] + relu( sum_e alpha*h1[src] + bias ). RESMODE 1: res is xg-view.
template<int RESMODE>
__global__ __launch_bounds__(512) void k_gat_agg(const int* __restrict__ esrc, const int* __restrict__ edst,
                                                 const float* __restrict__ a_s, const float* __restrict__ a_d,
                                                 const float* __restrict__ mbuf, const float* __restrict__ dbuf,
                                                 const float* __restrict__ h1, const float* __restrict__ gbias,
                                                 const float* __restrict__ res, float* __restrict__ out)
{
    __shared__ int se[384], de[384];
    __shared__ float asl[128], adl[128], ml[128], dl_[128];
    int bh = blockIdx.x;
    int b = bh >> 3, h = bh & 7;
    int t = threadIdx.x;
    if (t < 384) {
        if (t < E256) { se[t] = esrc[b * E256 + t]; de[t] = edst[b * E256 + t]; }
        else          { se[t] = t - E256;           de[t] = t - E256; }
    }
    if (t < 128) {
        asl[t] = a_s[(b * S128 + t) * 8 + h];
        adl[t] = a_d[(b * S128 + t) * 8 + h];
        ml[t]  = mbuf[(b * S128 + t) * 8 + h];
        dl_[t] = dbuf[(b * S128 + t) * 8 + h];
    }
    __syncthreads();
    int dst = t >> 2, ch = t & 3;
    int dd0 = ch * 25;
    float acc[25] = {};
    float myad = adl[dst], mym = ml[dst];
    for (int e = 0; e < 384; e++) {
        if (de[e] == dst) {
            int s = se[e];
            float sc = asl[s] + myad;
            sc = (sc > 0.f) ? sc : 0.2f * sc;
            float w = __expf(sc - mym);
            const float* hp = h1 + (size_t)(b * S128 + s) * H800 + h * 100 + dd0;
            #pragma unroll
            for (int q = 0; q < 25; q++) acc[q] += w * hp[q];
        }
    }
    float inv = 1.f / dl_[dst];
    int n = b * S128 + dst;
    size_t rrow = (RESMODE == 1) ? (size_t)(n + b + 1) * H800 : (size_t)n * H800;
    #pragma unroll
    for (int q = 0; q < 25; q++) {
        int col = h * 100 + dd0 + q;
        float v = acc[q] * inv + gbias[col];
        out[(size_t)n * H800 + col] = res[rrow + col] + fmaxf(v, 0.f);
    }
}

// ---------------------------------------------------------------------------
// Trig head on the diagonal only: 512 rows. One wave per (b,i).
__global__ __launch_bounds__(64) void k_trig(const float* __restrict__ u, const float* __restrict__ v,
                                             const float* __restrict__ W, const float* __restrict__ bias,
                                             const int* __restrict__ labels, float* __restrict__ d_out)
{
    __shared__ float s[800];
    __shared__ float lg[66];
    int bi = blockIdx.x;          // b*128+i
    int i = bi & 127;
    int l = threadIdx.x;
    const float* ur = u + (size_t)bi * H800;
    const float* vr = v + (size_t)bi * H800;
    for (int k = l; k < 800; k += 64) s[k] = gelu_f(ur[k] + vr[k]);
    __syncthreads();
    float a0 = 0.f, a1 = 0.f;
    bool has2 = (l < 2);
    for (int k = 0; k < 800; k++) {
        float sv = s[k];
        a0 += sv * W[k * NE + l];
        if (has2) a1 += sv * W[k * NE + 64 + l];
    }
    lg[l] = a0 + bias[l];
    if (has2) lg[64 + l] = a1 + bias[64 + l];
    __syncthreads();
    if (l == 0) {
        float m = lg[0];
        for (int c = 1; c < NE; c++) m = fmaxf(m, lg[c]);
        float se = 0.f, sl = 0.f, bv = lg[0];
        int am = 0;
        for (int c = 0; c < NE; c++) {
            se += __expf(lg[c] - m);
            sl += lg[c];
            if (lg[c] > bv) { bv = lg[c]; am = c; }
        }
        float lse = m + __logf(se);
        int tgt = labels[(size_t)bi * S128 + i];       // start_labels[b,i,i]
        float ce = (0.1f / NE) * (NE * lse - sl) + 0.9f * (lse - lg[tgt]);
        atomicAdd(d_out, ce * (1.f / 128.f));
        int r = bi * S128 + i;
        d_out[1 + r] = (float)am;
        d_out[1 + 65536 + r] = (float)am;
    }
}

// ---------------------------------------------------------------------------
// rs/re logits for one batch: rows local r = i*128+j (16384), cols 122 (stride 128).
// A built on the fly: gelu(u[b,i,k] + v[b,j,k]).
__global__ __launch_bounds__(256) void k_logits(const float* __restrict__ ub, const float* __restrict__ vb,
                                                const float* __restrict__ W, const float* __restrict__ bias,
                                                float* __restrict__ L)
{
    __shared__ float As[16][68];
    __shared__ float Bs[16][68];
    int rt = blockIdx.x;            // 0..255: (i)*2 + jhalf
    int il = rt >> 1;               // i 0..127
    int j0 = (rt & 1) * 64;
    int c0 = blockIdx.y * 64;
    const float* urow = ub + (size_t)il * H800;
    int tid = threadIdx.x;
    int tm = tid & 15, tn = tid >> 4;
    float acc[4][4] = {};
    for (int k0 = 0; k0 < 800; k0 += 16) {
        {
            int kk = tid & 15, rrb = tid >> 4;
            float uk = urow[k0 + kk];
            #pragma unroll
            for (int q = 0; q < 4; q++) {
                int rr = rrb + q * 16;
                float xv = uk + vb[(size_t)(j0 + rr) * H800 + k0 + kk];
                As[kk][rr] = gelu_f(xv);
            }
        }
        {
            int cc = (tid & 15) * 4, kk2 = tid >> 4;
            #pragma unroll
            for (int q = 0; q < 4; q++) {
                int c = c0 + cc + q;
                Bs[kk2][cc + q] = (c < NR) ? W[(size_t)(k0 + kk2) * NR + c] : 0.f;
            }
        }
        __syncthreads();
        #pragma unroll
        for (int kk = 0; kk < 16; kk++) {
            float4 a = *(const float4*)&As[kk][tm * 4];
            float4 bb = *(const float4*)&Bs[kk][tn * 4];
            float av[4] = {a.x, a.y, a.z, a.w};
            float bv[4] = {bb.x, bb.y, bb.z, bb.w};
            #pragma unroll
            for (int xx = 0; xx < 4; xx++)
                #pragma unroll
                for (int yy = 0; yy < 4; yy++)
                    acc[xx][yy] += av[xx] * bv[yy];
        }
        __syncthreads();
    }
    #pragma unroll
    for (int xx = 0; xx < 4; xx++) {
        int j = j0 + tm * 4 + xx;
        int r = il * S128 + j;
        #pragma unroll
        for (int yy = 0; yy < 4; yy++) {
            int c = c0 + tn * 4 + yy;
            if (c < NR) L[(size_t)r * 128 + c] = acc[xx][yy] + bias[c];
        }
    }
}

// CE loss + symmetric argmax over one batch's 122-class logits. One wave per row.
__global__ __launch_bounds__(256) void k_loss_arg(const float* __restrict__ L, const int* __restrict__ labels,
                                                  float* __restrict__ resout, float* __restrict__ lossptr)
{
    __shared__ float wsum[4];
    int wv = threadIdx.x >> 6, l = threadIdx.x & 63;
    int r = blockIdx.x * 4 + wv;          // local row in [0,16384)
    int i = r >> 7, j = r & 127;
    float ce = 0.f;
    if (i != j) {
        const float* row = L + (size_t)r * 128;
        int p = (j << 7) | i;
        const float* prow = L + (size_t)p * 128;
        float x1 = row[l];
        bool v2 = (l < NR - 64);
        float x2 = v2 ? row[l + 64] : -3.4e38f;
        float m = fmaxf(x1, x2);
        #pragma unroll
        for (int s = 32; s; s >>= 1) m = fmaxf(m, __shfl_xor(m, s, 64));
        float se = __expf(x1 - m) + (v2 ? __expf(x2 - m) : 0.f);
        float sl = x1 + (v2 ? x2 : 0.f);
        #pragma unroll
        for (int s = 32; s; s >>= 1) { se += __shfl_xor(se, s, 64); sl += __shfl_xor(sl, s, 64); }
        float lse = m + __logf(se);
        int tgt = labels[r];
        float lt = row[tgt];
        ce = (0.1f / NR) * (NR * lse - sl) + 0.9f * (lse - lt);
        // argmax of row + row^T (first-max tie rule)
        float y1 = x1 + prow[l];
        float y2 = v2 ? (x2 + prow[l + 64]) : -3.4e38f;
        float bv; int bidx;
        if (y2 > y1) { bv = y2; bidx = l + 64; } else { bv = y1; bidx = l; }
        #pragma unroll
        for (int s = 32; s; s >>= 1) {
            float ov = __shfl_xor(bv, s, 64);
            int oi = __shfl_xor(bidx, s, 64);
            if (ov > bv || (ov == bv && oi < bidx)) { bv = ov; bidx = oi; }
        }
        if (l == 0) resout[r] = (float)bidx;
    }
    if (l == 0) wsum[wv] = ce;
    __syncthreads();
    if (threadIdx.x == 0) {
        float s = (wsum[0] + wsum[1] + wsum[2] + wsum[3]) * (1.f / 16256.f);
        atomicAdd(lossptr, s);
    }
}

// ---------------------------------------------------------------------------
extern "C" void kernel_launch(void* const* d_in, const int* in_sizes, int n_in,
                              void* d_out, int out_size, void* d_ws, size_t ws_size,
                              hipStream_t stream)
{
    (void)in_sizes; (void)n_in; (void)out_size; (void)ws_size;
    const float* bert  = (const float*)d_in[0];
    const int*   pids  = (const int*)d_in[1];
    const int*   esrc  = (const int*)d_in[2];
    const int*   edst  = (const int*)d_in[3];
    const int*   slab  = (const int*)d_in[4];
    const int*   elab  = (const int*)d_in[5];
    const float* ptab  = (const float*)d_in[6];
    const float* Wih_f = (const float*)d_in[7];
    const float* Whh_f = (const float*)d_in[8];
    const float* bl_f  = (const float*)d_in[9];
    const float* Wih_b = (const float*)d_in[10];
    const float* Whh_b = (const float*)d_in[11];
    const float* bl_b  = (const float*)d_in[12];
    const float* fcW   = (const float*)d_in[13];
    const float* fcb   = (const float*)d_in[14];
    const float* tW    = (const float*)d_in[15];
    const float* tb    = (const float*)d_in[16];
    const float* gatW  = (const float*)d_in[17];
    const float* asrc  = (const float*)d_in[18];
    const float* adst  = (const float*)d_in[19];
    const float* gbias = (const float*)d_in[20];
    const float* trigW = (const float*)d_in[21];
    const float* trigb = (const float*)d_in[22];
    const float* rsW   = (const float*)d_in[23];
    const float* rsb   = (const float*)d_in[24];
    const float* reW   = (const float*)d_in[25];
    const float* reb   = (const float*)d_in[26];
    float* out = (float*)d_out;

    float* ws = (float*)d_ws;
    size_t off = 0;
    auto alloc = [&](size_t n) { float* p = ws + off; off += (n + 255) & ~(size_t)255; return p; };
    float* x    = alloc(516 * 800);
    float* xWf  = alloc((size_t)516 * 3200);
    float* xWb  = alloc((size_t)516 * 3200);
    float* lstm = alloc((size_t)516 * 1600);
    float* xg   = alloc(516 * 800);
    float* h1   = alloc(512 * 800);
    float* g1   = alloc(512 * 800);
    float* g2   = alloc(512 * 800);
    float* uu   = alloc(512 * 800);
    float* vv   = alloc(512 * 800);
    float* as_  = alloc(4096);
    float* ad_  = alloc(4096);
    float* mb   = alloc(4096);
    float* db   = alloc(4096);
    float* Lbuf = alloc((size_t)16384 * 128);
    int*   cnt  = (int*)alloc(2 * 129);

    hipMemsetAsync(d_out, 0, 4, stream);                 // loss accumulator
    hipMemsetAsync(cnt, 0, 2 * 129 * sizeof(int), stream);

    k_embed<<<(B4 * T129 * H800 + 255) / 256, 256, 0, stream>>>(bert, pids, ptab, x);

    // gate-input precompute: xW = x @ Wih^T + bl  (bias folded here)
    k_gemm<0, 1, 0><<<dim3(9, 50), 256, 0, stream>>>(x, Wih_f, bl_f, nullptr, xWf, 516, 3200, 800);
    k_gemm<0, 1, 0><<<dim3(9, 50), 256, 0, stream>>>(x, Wih_b, bl_b, nullptr, xWb, 516, 3200, 800);

    k_lstm<<<400, 256, 0, stream>>>(xWf, xWb, Whh_f, Whh_b, lstm, cnt);

    // xg = x + relu(lstm @ fcW + fcb)
    k_gemm<0, 0, 1><<<dim3(9, 13), 256, 0, stream>>>(lstm, fcW, fcb, x, xg, 516, 800, 1600);

    // GAT layer 1 (input = xg[:,1:,:] view via AMODE/RESMODE 1)
    k_gemm<1, 0, 0><<<dim3(8, 13), 256, 0, stream>>>(xg, gatW, nullptr, nullptr, h1, 512, 800, 800);
    k_gat_coef<<<16, 256, 0, stream>>>(h1, asrc, adst, as_, ad_);
    k_gat_softmax<<<32, 128, 0, stream>>>(esrc, edst, as_, ad_, mb, db);
    k_gat_agg<1><<<32, 512, 0, stream>>>(esrc, edst, as_, ad_, mb, db, h1, gbias, xg, g1);
    // GAT layer 2
    k_gemm<0, 0, 0><<<dim3(8, 13), 256, 0, stream>>>(g1, gatW, nullptr, nullptr, h1, 512, 800, 800);
    k_gat_coef<<<16, 256, 0, stream>>>(h1, asrc, adst, as_, ad_);
    k_gat_softmax<<<32, 128, 0, stream>>>(esrc, edst, as_, ad_, mb, db);
    k_gat_agg<0><<<32, 512, 0, stream>>>(esrc, edst, as_, ad_, mb, db, h1, gbias, g1, g2);

    // table split: u = g2@tW[:800] + tb ; v = g2@tW[800:]
    k_gemm<0, 0, 0><<<dim3(8, 13), 256, 0, stream>>>(g2, tW, tb, nullptr, uu, 512, 800, 800);
    k_gemm<0, 0, 0><<<dim3(8, 13), 256, 0, stream>>>(g2, tW + (size_t)800 * 800, nullptr, nullptr, vv, 512, 800, 800);

    // trig head: diagonal only (l1 + results diag)
    k_trig<<<512, 64, 0, stream>>>(uu, vv, trigW, trigb, slab, out);

    // rs head (l2 + results1 off-diag), per-batch chunks to bound ws
    for (int b = 0; b < B4; b++) {
        k_logits<<<dim3(256, 2), 256, 0, stream>>>(uu + (size_t)b * 128 * 800, vv + (size_t)b * 128 * 800,
                                                   rsW, rsb, Lbuf);
        k_loss_arg<<<4096, 256, 0, stream>>>(Lbuf, slab + (size_t)b * 16384, out + 1 + (size_t)b * 16384, out);
    }
    // re head (l3 + results2 off-diag)
    for (int b = 0; b < B4; b++) {
        k_logits<<<dim3(256, 2), 256, 0, stream>>>(uu + (size_t)b * 128 * 800, vv + (size_t)b * 128 * 800,
                                                   reW, reb, Lbuf);
        k_loss_arg<<<4096, 256, 0, stream>>>(Lbuf, elab + (size_t)b * 16384, out + 1 + 65536 + (size_t)b * 16384, out);
    }
}

// Round 2
// 6443.807 us; speedup vs baseline: 1.0889x; 1.0889x over previous
//
#include <hip/hip_runtime.h>
#include <hip/hip_bf16.h>

// Problem dims
#define B4 4
#define S128 128
#define T129 129
#define H800 800
#define G3200 3200
#define E256 256
#define NE 66
#define NR 122

// ---------------------------------------------------------------------------
// gelu (jax approximate=True): 0.5*x*(1+tanh(sqrt(2/pi)*(x+0.044715 x^3)))
__device__ __forceinline__ float gelu_f(float x) {
    float t = 0.7978845608028654f * (x + 0.044715f * x * x * x);
    float e = __expf(2.f * t);           // overflow -> inf -> th=1 ; underflow -> 0 -> th=-1
    float th = 1.f - 2.f / (e + 1.f);
    return 0.5f * x * (1.f + th);
}

// ---------------------------------------------------------------------------
// K_embed: x[b,t,0:768]=bert, x[b,t,768:800]=pos_table[pos_ids[b,t-1]] (0 for t=0)
__global__ void k_embed(const float* __restrict__ bert, const int* __restrict__ pos_ids,
                        const float* __restrict__ ptab, float* __restrict__ x)
{
    int idx = blockIdx.x * 256 + threadIdx.x;
    if (idx >= B4 * T129 * H800) return;
    int c = idx % H800;
    int bt = idx / H800;
    int t = bt % T129, b = bt / T129;
    float v;
    if (c < 768) v = bert[(size_t)bt * 768 + c];
    else         v = (t == 0) ? 0.f : ptab[pos_ids[b * S128 + t - 1] * 32 + (c - 768)];
    x[idx] = v;
}

// ---------------------------------------------------------------------------
// Generic fp32 tiled GEMM. C[M,N] = A(M,K) * B  (+bias) with optional epilogue.
// AMODE: 0 direct row, 1 xg-view (row -> row + row/128 + 1)  [x[:,1:,:] view]
// BTRANS: 0: B is [K,N]; 1: B is [N,K] (A @ B^T)
// EPI: 0: C = acc (+bias); 1: C = res + relu(acc+bias)
template<int AMODE, int BTRANS, int EPI>
__global__ __launch_bounds__(256) void k_gemm(const float* __restrict__ A, const float* __restrict__ Bm,
                                              const float* __restrict__ bias, const float* __restrict__ res,
                                              float* __restrict__ C, int M, int N, int K)
{
    __shared__ float As[16][68];
    __shared__ float Bs[16][68];
    int m0 = blockIdx.x * 64, n0 = blockIdx.y * 64;
    int tid = threadIdx.x;
    int tm = tid & 15, tn = tid >> 4;
    float acc[4][4] = {};
    for (int k0 = 0; k0 < K; k0 += 16) {
        // A tile: As[kk][mm]
        {
            int kk = tid & 15, mmb = tid >> 4;
            #pragma unroll
            for (int q = 0; q < 4; q++) {
                int mm = mmb + q * 16;
                int m = m0 + mm;
                float v = 0.f;
                if (m < M) {
                    int row = (AMODE == 1) ? (m + (m >> 7) + 1) : m;
                    v = A[(size_t)row * K + k0 + kk];
                }
                As[kk][mm] = v;
            }
        }
        // B tile: Bs[kk][nn]
        if (BTRANS == 0) {
            int nn = (tid & 15) * 4, kk2 = tid >> 4;
            int n = n0 + nn;
            float t0, t1, t2, t3;
            if (n + 3 < N) {
                const float4 bv = *(const float4*)&Bm[(size_t)(k0 + kk2) * N + n];
                t0 = bv.x; t1 = bv.y; t2 = bv.z; t3 = bv.w;
            } else {
                t0 = (n + 0 < N) ? Bm[(size_t)(k0 + kk2) * N + n + 0] : 0.f;
                t1 = (n + 1 < N) ? Bm[(size_t)(k0 + kk2) * N + n + 1] : 0.f;
                t2 = (n + 2 < N) ? Bm[(size_t)(k0 + kk2) * N + n + 2] : 0.f;
                t3 = (n + 3 < N) ? Bm[(size_t)(k0 + kk2) * N + n + 3] : 0.f;
            }
            Bs[kk2][nn + 0] = t0; Bs[kk2][nn + 1] = t1; Bs[kk2][nn + 2] = t2; Bs[kk2][nn + 3] = t3;
        } else {
            int kk = tid & 15, nnb = tid >> 4;
            #pragma unroll
            for (int q = 0; q < 4; q++) {
                int nn = nnb + q * 16;
                int n = n0 + nn;
                Bs[kk][nn] = (n < N) ? Bm[(size_t)n * K + k0 + kk] : 0.f;
            }
        }
        __syncthreads();
        #pragma unroll
        for (int kk = 0; kk < 16; kk++) {
            float4 a = *(const float4*)&As[kk][tm * 4];
            float4 bb = *(const float4*)&Bs[kk][tn * 4];
            float av[4] = {a.x, a.y, a.z, a.w};
            float bv[4] = {bb.x, bb.y, bb.z, bb.w};
            #pragma unroll
            for (int xx = 0; xx < 4; xx++)
                #pragma unroll
                for (int yy = 0; yy < 4; yy++)
                    acc[xx][yy] += av[xx] * bv[yy];
        }
        __syncthreads();
    }
    #pragma unroll
    for (int xx = 0; xx < 4; xx++) {
        int m = m0 + tm * 4 + xx;
        if (m >= M) continue;
        #pragma unroll
        for (int yy = 0; yy < 4; yy++) {
            int n = n0 + tn * 4 + yy;
            if (n >= N) continue;
            float v = acc[xx][yy];
            if (bias) v += bias[n];
            if (EPI == 1) v = res[(size_t)m * N + n] + fmaxf(v, 0.f);
            C[(size_t)m * N + n] = v;
        }
    }
}

// ---------------------------------------------------------------------------
// Persistent BiLSTM recurrence. Grid: 400 WGs x 256 thr. WGs [0,200) fwd, [200,400) bwd.
// Each WG owns 4 h-dims (all 4 gates, all 4 batches); Whh rows staged in LDS.
// h exchanged through lstm_out via agent-scope atomics.
// Barrier v2: per-WG arrival FLAG (distinct address, plain release store — no RMW
// serialization), wave-0 wide poll of all 200 flags. Flags monotone = step+1.
__global__ __launch_bounds__(256) void k_lstm(const float* __restrict__ xWf, const float* __restrict__ xWb,
                                              const float* __restrict__ Whhf, const float* __restrict__ Whhb,
                                              float* __restrict__ lstm, int* __restrict__ flags)
{
    __shared__ float wl[16][802];   // 16 gate rows x 800 (pad 802)
    __shared__ float hb[4][800];    // current h, 4 batches
    __shared__ float gb[4][4][4];   // [gate][dim][batch]
    int wg = blockIdx.x;
    int dir = (wg >= 200) ? 1 : 0;
    int wgd = dir ? (wg - 200) : wg;
    const float* Whh = dir ? Whhb : Whhf;
    const float* xW  = dir ? xWb  : xWf;
    int d0 = wgd * 4;
    int tid = threadIdx.x;

    // one-time stage of the 16 Whh rows: row rr = gate(rr>>2)*800 + d0 + (rr&3)
    for (int rr = 0; rr < 16; rr++) {
        int g = (rr >> 2) * 800 + d0 + (rr & 3);
        for (int k = tid; k < 800; k += 256) wl[rr][k] = Whh[(size_t)g * 800 + k];
    }
    for (int i = tid; i < 3200; i += 256) (&hb[0][0])[i] = 0.f;
    __syncthreads();

    int wv = tid >> 6, l = tid & 63;
    int dl = l & 3;           // dim-local
    int slice = l >> 2;       // k-slice 0..15 (50 k each)
    int k0s = slice * 50;
    int gglob = wv * 800 + d0 + dl;   // this wave computes gate 'wv'
    float cst = 0.f;                  // c state (threads tid<16 only)

    for (int step = 0; step < 129; step++) {
        int t = dir ? (128 - step) : step;
        // prefetch gate-input (x@Wih^T + b) early to hide IC latency under the dot
        float xq0 = 0.f, xq1 = 0.f, xq2 = 0.f, xq3 = 0.f;
        if (slice == 0) {
            xq0 = xW[(size_t)(0 * T129 + t) * G3200 + gglob];
            xq1 = xW[(size_t)(1 * T129 + t) * G3200 + gglob];
            xq2 = xW[(size_t)(2 * T129 + t) * G3200 + gglob];
            xq3 = xW[(size_t)(3 * T129 + t) * G3200 + gglob];
        }
        if (step > 0) {
            int tprev = dir ? (t + 1) : (t - 1);
            for (int i = tid; i < 3200; i += 256) {
                int bb = i / 800, dd = i - bb * 800;
                hb[bb][dd] = __hip_atomic_load(
                    &lstm[(size_t)((bb * T129 + tprev) * 1600) + dir * 800 + dd],
                    __ATOMIC_RELAXED, __HIP_MEMORY_SCOPE_AGENT);
            }
        }
        __syncthreads();
        // partial dot: gate row (wv, dl) x h[b], k in [k0s, k0s+50)
        float a0 = 0.f, a1 = 0.f, a2 = 0.f, a3 = 0.f;
        const float* wrow = &wl[(wv << 2) | dl][0];
        #pragma unroll 5
        for (int kk = k0s; kk < k0s + 50; kk += 2) {
            float w0 = wrow[kk], w1 = wrow[kk + 1];
            a0 += w0 * hb[0][kk] + w1 * hb[0][kk + 1];
            a1 += w0 * hb[1][kk] + w1 * hb[1][kk + 1];
            a2 += w0 * hb[2][kk] + w1 * hb[2][kk + 1];
            a3 += w0 * hb[3][kk] + w1 * hb[3][kk + 1];
        }
        // reduce over the 16 k-slices (lanes differing in bits 2..5)
        #pragma unroll
        for (int s = 4; s <= 32; s <<= 1) {
            a0 += __shfl_xor(a0, s, 64);
            a1 += __shfl_xor(a1, s, 64);
            a2 += __shfl_xor(a2, s, 64);
            a3 += __shfl_xor(a3, s, 64);
        }
        if (slice == 0) {
            gb[wv][dl][0] = a0 + xq0;
            gb[wv][dl][1] = a1 + xq1;
            gb[wv][dl][2] = a2 + xq2;
            gb[wv][dl][3] = a3 + xq3;
        }
        __syncthreads();
        if (tid < 16) {
            int d = tid & 3, bb = tid >> 2;
            float gi = gb[0][d][bb], gf = gb[1][d][bb], gg = gb[2][d][bb], go = gb[3][d][bb];
            float si = 1.f / (1.f + __expf(-gi));
            float sf = 1.f / (1.f + __expf(-gf));
            float so = 1.f / (1.f + __expf(-go));
            cst = sf * cst + si * tanhf(gg);
            float hv = so * tanhf(cst);
            __hip_atomic_store(&lstm[(size_t)((bb * T129 + t) * 1600) + dir * 800 + d0 + d], hv,
                               __ATOMIC_RELAXED, __HIP_MEMORY_SCOPE_AGENT);
        }
        if (step < 128) {
            __syncthreads();   // drains vmcnt: h stores acknowledged
            if (tid == 0) {
                __threadfence();
                __hip_atomic_store(&flags[dir * 200 + wgd], step + 1,
                                   __ATOMIC_RELEASE, __HIP_MEMORY_SCOPE_AGENT);
            }
            if (tid < 64) {     // wave 0 polls all 200 flags of this dir
                int base = dir * 200 + tid * 4;
                bool mine = (tid < 50);
                long long iters = 0;
                for (;;) {
                    int mn = step + 1;
                    if (mine) {
                        int f0 = __hip_atomic_load(&flags[base + 0], __ATOMIC_RELAXED, __HIP_MEMORY_SCOPE_AGENT);
                        int f1 = __hip_atomic_load(&flags[base + 1], __ATOMIC_RELAXED, __HIP_MEMORY_SCOPE_AGENT);
                        int f2 = __hip_atomic_load(&flags[base + 2], __ATOMIC_RELAXED, __HIP_MEMORY_SCOPE_AGENT);
                        int f3 = __hip_atomic_load(&flags[base + 3], __ATOMIC_RELAXED, __HIP_MEMORY_SCOPE_AGENT);
                        mn = min(min(f0, f1), min(f2, f3));
                    }
                    if (__all(mn >= step + 1)) break;
                    if (++iters > 100000000LL) break;   // safety valve vs deadlock
                    __builtin_amdgcn_s_sleep(1);
                }
                __threadfence();   // acquire: order flag observation before h loads
            }
            __syncthreads();
        }
    }
}

// ---------------------------------------------------------------------------
// GAT attention coefficients: a_s[n,h] = sum_d h1[n,h*100+d]*asrc[h,d]; same a_d.
__global__ __launch_bounds__(256) void k_gat_coef(const float* __restrict__ h1,
                                                  const float* __restrict__ asrc, const float* __restrict__ adst,
                                                  float* __restrict__ a_s, float* __restrict__ a_d)
{
    int t = blockIdx.x * 256 + threadIdx.x;   // 512*8
    if (t >= 512 * 8) return;
    int h = t & 7, n = t >> 3;
    const float* hp = h1 + (size_t)n * H800 + h * 100;
    float s1 = 0.f, s2 = 0.f;
    for (int d = 0; d < 100; d++) {
        float hv = hp[d];
        s1 += hv * asrc[h * 100 + d];
        s2 += hv * adst[h * 100 + d];
    }
    a_s[t] = s1;
    a_d[t] = s2;
}

// Per (b,h): segment max + sum of exp over incident edges (incl self-loops).
__global__ __launch_bounds__(128) void k_gat_softmax(const int* __restrict__ esrc, const int* __restrict__ edst,
                                                     const float* __restrict__ a_s, const float* __restrict__ a_d,
                                                     float* __restrict__ mbuf, float* __restrict__ dbuf)
{
    __shared__ int se[384], de[384];
    __shared__ float asl[128], adl[128];
    int bh = blockIdx.x;
    int b = bh >> 3, h = bh & 7;
    int t = threadIdx.x;
    for (int e = t; e < 384; e += 128) {
        if (e < E256) { se[e] = esrc[b * E256 + e]; de[e] = edst[b * E256 + e]; }
        else          { se[e] = e - E256;           de[e] = e - E256; }
    }
    asl[t] = a_s[(b * S128 + t) * 8 + h];
    adl[t] = a_d[(b * S128 + t) * 8 + h];
    __syncthreads();
    float myad = adl[t];
    float m = -3.4e38f;
    for (int e = 0; e < 384; e++) {
        if (de[e] == t) {
            float sc = asl[se[e]] + myad;
            sc = (sc > 0.f) ? sc : 0.2f * sc;
            m = fmaxf(m, sc);
        }
    }
    float den = 0.f;
    for (int e = 0; e < 384; e++) {
        if (de[e] == t) {
            float sc = asl[se[e]] + myad;
            sc = (sc > 0.f) ? sc : 0.2f * sc;
            den += __expf(sc - m);
        }
    }
    mbuf[(b * S128 + t) * 8 + h] = m;
    dbuf[(b * S128 + t) * 8 + h] = den;
}

// Aggregate: out[n] = res[n] + relu( sum_e alpha*h1[src] + bias ). RESMODE 1: res is xg-view.
template<int RESMODE>
__global__ __launch_bounds__(512) void k_gat_agg(const int* __restrict__ esrc, const int* __restrict__ edst,
                                                 const float* __restrict__ a_s, const float* __restrict__ a_d,
                                                 const float* __restrict__ mbuf, const float* __restrict__ dbuf,
                                                 const float* __restrict__ h1, const float* __restrict__ gbias,
                                                 const float* __restrict__ res, float* __restrict__ out)
{
    __shared__ int se[384], de[384];
    __shared__ float asl[128], adl[128], ml[128], dl_[128];
    int bh = blockIdx.x;
    int b = bh >> 3, h = bh & 7;
    int t = threadIdx.x;
    if (t < 384) {
        if (t < E256) { se[t] = esrc[b * E256 + t]; de[t] = edst[b * E256 + t]; }
        else          { se[t] = t - E256;           de[t] = t - E256; }
    }
    if (t < 128) {
        asl[t] = a_s[(b * S128 + t) * 8 + h];
        adl[t] = a_d[(b * S128 + t) * 8 + h];
        ml[t]  = mbuf[(b * S128 + t) * 8 + h];
        dl_[t] = dbuf[(b * S128 + t) * 8 + h];
    }
    __syncthreads();
    int dst = t >> 2, ch = t & 3;
    int dd0 = ch * 25;
    float acc[25] = {};
    float myad = adl[dst], mym = ml[dst];
    for (int e = 0; e < 384; e++) {
        if (de[e] == dst) {
            int s = se[e];
            float sc = asl[s] + myad;
            sc = (sc > 0.f) ? sc : 0.2f * sc;
            float w = __expf(sc - mym);
            const float* hp = h1 + (size_t)(b * S128 + s) * H800 + h * 100 + dd0;
            #pragma unroll
            for (int q = 0; q < 25; q++) acc[q] += w * hp[q];
        }
    }
    float inv = 1.f / dl_[dst];
    int n = b * S128 + dst;
    size_t rrow = (RESMODE == 1) ? (size_t)(n + b + 1) * H800 : (size_t)n * H800;
    #pragma unroll
    for (int q = 0; q < 25; q++) {
        int col = h * 100 + dd0 + q;
        float v = acc[q] * inv + gbias[col];
        out[(size_t)n * H800 + col] = res[rrow + col] + fmaxf(v, 0.f);
    }
}

// ---------------------------------------------------------------------------
// Trig head on the diagonal only: 512 rows. One wave per (b,i).
__global__ __launch_bounds__(64) void k_trig(const float* __restrict__ u, const float* __restrict__ v,
                                             const float* __restrict__ W, const float* __restrict__ bias,
                                             const int* __restrict__ labels, float* __restrict__ d_out)
{
    __shared__ float s[800];
    __shared__ float lg[66];
    int bi = blockIdx.x;          // b*128+i
    int i = bi & 127;
    int l = threadIdx.x;
    const float* ur = u + (size_t)bi * H800;
    const float* vr = v + (size_t)bi * H800;
    for (int k = l; k < 800; k += 64) s[k] = gelu_f(ur[k] + vr[k]);
    __syncthreads();
    float a0 = 0.f, a1 = 0.f;
    bool has2 = (l < 2);
    for (int k = 0; k < 800; k++) {
        float sv = s[k];
        a0 += sv * W[k * NE + l];
        if (has2) a1 += sv * W[k * NE + 64 + l];
    }
    lg[l] = a0 + bias[l];
    if (has2) lg[64 + l] = a1 + bias[64 + l];
    __syncthreads();
    if (l == 0) {
        float m = lg[0];
        for (int c = 1; c < NE; c++) m = fmaxf(m, lg[c]);
        float se = 0.f, sl = 0.f, bv = lg[0];
        int am = 0;
        for (int c = 0; c < NE; c++) {
            se += __expf(lg[c] - m);
            sl += lg[c];
            if (lg[c] > bv) { bv = lg[c]; am = c; }
        }
        float lse = m + __logf(se);
        int tgt = labels[(size_t)bi * S128 + i];       // start_labels[b,i,i]
        float ce = (0.1f / NE) * (NE * lse - sl) + 0.9f * (lse - lg[tgt]);
        atomicAdd(d_out, ce * (1.f / 128.f));
        int r = bi * S128 + i;
        d_out[1 + r] = (float)am;
        d_out[1 + 65536 + r] = (float)am;
    }
}

// ---------------------------------------------------------------------------
// Fused rs+re logits for one batch: rows r = i*128+j (16384), cols 0..255
// (col<128 -> rs head col c, col>=128 -> re head col c-128; valid c<122).
// A built on the fly: gelu(u[b,i,k] + v[b,j,k]) — built ONCE for both heads.
__global__ __launch_bounds__(256) void k_logits2(const float* __restrict__ ub, const float* __restrict__ vb,
                                                 const float* __restrict__ rsW, const float* __restrict__ rsb,
                                                 const float* __restrict__ reW, const float* __restrict__ reb,
                                                 float* __restrict__ L)
{
    __shared__ float As[16][68];
    __shared__ float Bs[16][256];
    int il = blockIdx.x >> 1;               // i 0..127
    int j0 = (blockIdx.x & 1) * 64;
    const float* urow = ub + (size_t)il * H800;
    int tid = threadIdx.x;
    int tm = tid & 15, tn = tid >> 4;       // rows tm*4..+3, cols tn*16..+15
    float acc[4][16] = {};
    // B column for this thread (persistent across k0)
    int ct = tid;
    int hc = (ct < 128) ? ct : (ct - 128);
    const float* Wp = (ct < 128) ? rsW : reW;
    bool cok = hc < NR;
    for (int k0 = 0; k0 < 800; k0 += 16) {
        {
            int kk = tid & 15, rrb = tid >> 4;
            float uk = urow[k0 + kk];
            #pragma unroll
            for (int q = 0; q < 4; q++) {
                int rr = rrb + q * 16;
                float xv = uk + vb[(size_t)(j0 + rr) * H800 + k0 + kk];
                As[kk][rr] = gelu_f(xv);
            }
        }
        #pragma unroll
        for (int kk2 = 0; kk2 < 16; kk2++)
            Bs[kk2][ct] = cok ? Wp[(size_t)(k0 + kk2) * NR + hc] : 0.f;
        __syncthreads();
        #pragma unroll
        for (int kk = 0; kk < 16; kk++) {
            float4 a = *(const float4*)&As[kk][tm * 4];
            float av[4] = {a.x, a.y, a.z, a.w};
            float bv[16];
            #pragma unroll
            for (int q = 0; q < 4; q++) {
                float4 bb = *(const float4*)&Bs[kk][tn * 16 + q * 4];
                bv[q * 4 + 0] = bb.x; bv[q * 4 + 1] = bb.y; bv[q * 4 + 2] = bb.z; bv[q * 4 + 3] = bb.w;
            }
            #pragma unroll
            for (int xx = 0; xx < 4; xx++)
                #pragma unroll
                for (int yy = 0; yy < 16; yy++)
                    acc[xx][yy] += av[xx] * bv[yy];
        }
        __syncthreads();
    }
    #pragma unroll
    for (int xx = 0; xx < 4; xx++) {
        int r = il * S128 + j0 + tm * 4 + xx;
        #pragma unroll
        for (int yy = 0; yy < 16; yy++) {
            int cc = tn * 16 + yy;
            int head = cc >> 7, c = cc & 127;
            if (c < NR)
                L[(size_t)r * 256 + cc] = acc[xx][yy] + (head ? reb[c] : rsb[c]);
        }
    }
}

// CE loss + symmetric argmax over one batch's 122-class logits (stride-256 buffer,
// head selects column half). One wave per row.
__global__ __launch_bounds__(256) void k_loss_arg(const float* __restrict__ L, int head,
                                                  const int* __restrict__ labels,
                                                  float* __restrict__ resout, float* __restrict__ lossptr)
{
    __shared__ float wsum[4];
    int wv = threadIdx.x >> 6, l = threadIdx.x & 63;
    int r = blockIdx.x * 4 + wv;          // local row in [0,16384)
    int i = r >> 7, j = r & 127;
    float ce = 0.f;
    if (i != j) {
        const float* row = L + (size_t)r * 256 + head * 128;
        int p = (j << 7) | i;
        const float* prow = L + (size_t)p * 256 + head * 128;
        float x1 = row[l];
        bool v2 = (l < NR - 64);
        float x2 = v2 ? row[l + 64] : -3.4e38f;
        float m = fmaxf(x1, x2);
        #pragma unroll
        for (int s = 32; s; s >>= 1) m = fmaxf(m, __shfl_xor(m, s, 64));
        float se = __expf(x1 - m) + (v2 ? __expf(x2 - m) : 0.f);
        float sl = x1 + (v2 ? x2 : 0.f);
        #pragma unroll
        for (int s = 32; s; s >>= 1) { se += __shfl_xor(se, s, 64); sl += __shfl_xor(sl, s, 64); }
        float lse = m + __logf(se);
        int tgt = labels[r];
        float lt = row[tgt];
        ce = (0.1f / NR) * (NR * lse - sl) + 0.9f * (lse - lt);
        // argmax of row + row^T (first-max tie rule)
        float y1 = x1 + prow[l];
        float y2 = v2 ? (x2 + prow[l + 64]) : -3.4e38f;
        float bv; int bidx;
        if (y2 > y1) { bv = y2; bidx = l + 64; } else { bv = y1; bidx = l; }
        #pragma unroll
        for (int s = 32; s; s >>= 1) {
            float ov = __shfl_xor(bv, s, 64);
            int oi = __shfl_xor(bidx, s, 64);
            if (ov > bv || (ov == bv && oi < bidx)) { bv = ov; bidx = oi; }
        }
        if (l == 0) resout[r] = (float)bidx;
    }
    if (l == 0) wsum[wv] = ce;
    __syncthreads();
    if (threadIdx.x == 0) {
        float s = (wsum[0] + wsum[1] + wsum[2] + wsum[3]) * (1.f / 16256.f);
        atomicAdd(lossptr, s);
    }
}

// ---------------------------------------------------------------------------
extern "C" void kernel_launch(void* const* d_in, const int* in_sizes, int n_in,
                              void* d_out, int out_size, void* d_ws, size_t ws_size,
                              hipStream_t stream)
{
    (void)in_sizes; (void)n_in; (void)out_size; (void)ws_size;
    const float* bert  = (const float*)d_in[0];
    const int*   pids  = (const int*)d_in[1];
    const int*   esrc  = (const int*)d_in[2];
    const int*   edst  = (const int*)d_in[3];
    const int*   slab  = (const int*)d_in[4];
    const int*   elab  = (const int*)d_in[5];
    const float* ptab  = (const float*)d_in[6];
    const float* Wih_f = (const float*)d_in[7];
    const float* Whh_f = (const float*)d_in[8];
    const float* bl_f  = (const float*)d_in[9];
    const float* Wih_b = (const float*)d_in[10];
    const float* Whh_b = (const float*)d_in[11];
    const float* bl_b  = (const float*)d_in[12];
    const float* fcW   = (const float*)d_in[13];
    const float* fcb   = (const float*)d_in[14];
    const float* tW    = (const float*)d_in[15];
    const float* tb    = (const float*)d_in[16];
    const float* gatW  = (const float*)d_in[17];
    const float* asrc  = (const float*)d_in[18];
    const float* adst  = (const float*)d_in[19];
    const float* gbias = (const float*)d_in[20];
    const float* trigW = (const float*)d_in[21];
    const float* trigb = (const float*)d_in[22];
    const float* rsW   = (const float*)d_in[23];
    const float* rsb   = (const float*)d_in[24];
    const float* reW   = (const float*)d_in[25];
    const float* reb   = (const float*)d_in[26];
    float* out = (float*)d_out;

    float* ws = (float*)d_ws;
    size_t off = 0;
    auto alloc = [&](size_t n) { float* p = ws + off; off += (n + 255) & ~(size_t)255; return p; };
    float* x    = alloc(516 * 800);
    float* xWf  = alloc((size_t)516 * 3200);
    float* xWb  = alloc((size_t)516 * 3200);
    float* lstm = alloc((size_t)516 * 1600);
    float* xg   = alloc(516 * 800);
    float* h1   = alloc(512 * 800);
    float* g1   = alloc(512 * 800);
    float* g2   = alloc(512 * 800);
    float* uu   = alloc(512 * 800);
    float* vv   = alloc(512 * 800);
    float* as_  = alloc(4096);
    float* ad_  = alloc(4096);
    float* mb   = alloc(4096);
    float* db   = alloc(4096);
    float* Lbuf = alloc((size_t)16384 * 256);
    int*   flags = (int*)alloc(512);

    hipMemsetAsync(d_out, 0, 4, stream);                 // loss accumulator
    hipMemsetAsync(flags, 0, 400 * sizeof(int), stream);

    k_embed<<<(B4 * T129 * H800 + 255) / 256, 256, 0, stream>>>(bert, pids, ptab, x);

    // gate-input precompute: xW = x @ Wih^T + bl  (bias folded here)
    k_gemm<0, 1, 0><<<dim3(9, 50), 256, 0, stream>>>(x, Wih_f, bl_f, nullptr, xWf, 516, 3200, 800);
    k_gemm<0, 1, 0><<<dim3(9, 50), 256, 0, stream>>>(x, Wih_b, bl_b, nullptr, xWb, 516, 3200, 800);

    k_lstm<<<400, 256, 0, stream>>>(xWf, xWb, Whh_f, Whh_b, lstm, flags);

    // xg = x + relu(lstm @ fcW + fcb)
    k_gemm<0, 0, 1><<<dim3(9, 13), 256, 0, stream>>>(lstm, fcW, fcb, x, xg, 516, 800, 1600);

    // GAT layer 1 (input = xg[:,1:,:] view via AMODE/RESMODE 1)
    k_gemm<1, 0, 0><<<dim3(8, 13), 256, 0, stream>>>(xg, gatW, nullptr, nullptr, h1, 512, 800, 800);
    k_gat_coef<<<16, 256, 0, stream>>>(h1, asrc, adst, as_, ad_);
    k_gat_softmax<<<32, 128, 0, stream>>>(esrc, edst, as_, ad_, mb, db);
    k_gat_agg<1><<<32, 512, 0, stream>>>(esrc, edst, as_, ad_, mb, db, h1, gbias, xg, g1);
    // GAT layer 2
    k_gemm<0, 0, 0><<<dim3(8, 13), 256, 0, stream>>>(g1, gatW, nullptr, nullptr, h1, 512, 800, 800);
    k_gat_coef<<<16, 256, 0, stream>>>(h1, asrc, adst, as_, ad_);
    k_gat_softmax<<<32, 128, 0, stream>>>(esrc, edst, as_, ad_, mb, db);
    k_gat_agg<0><<<32, 512, 0, stream>>>(esrc, edst, as_, ad_, mb, db, h1, gbias, g1, g2);

    // table split: u = g2@tW[:800] + tb ; v = g2@tW[800:]
    k_gemm<0, 0, 0><<<dim3(8, 13), 256, 0, stream>>>(g2, tW, tb, nullptr, uu, 512, 800, 800);
    k_gemm<0, 0, 0><<<dim3(8, 13), 256, 0, stream>>>(g2, tW + (size_t)800 * 800, nullptr, nullptr, vv, 512, 800, 800);

    // trig head: diagonal only (l1 + results diag)
    k_trig<<<512, 64, 0, stream>>>(uu, vv, trigW, trigb, slab, out);

    // fused rs+re heads per batch (l2, l3, off-diag results)
    for (int b = 0; b < B4; b++) {
        k_logits2<<<256, 256, 0, stream>>>(uu + (size_t)b * 128 * 800, vv + (size_t)b * 128 * 800,
                                           rsW, rsb, reW, reb, Lbuf);
        k_loss_arg<<<4096, 256, 0, stream>>>(Lbuf, 0, slab + (size_t)b * 16384, out + 1 + (size_t)b * 16384, out);
        k_loss_arg<<<4096, 256, 0, stream>>>(Lbuf, 1, elab + (size_t)b * 16384, out + 1 + 65536 + (size_t)b * 16384, out);
    }
}

// Round 5
// 4542.003 us; speedup vs baseline: 1.5448x; 1.4187x over previous
//
#include <hip/hip_runtime.h>
#include <hip/hip_bf16.h>

// Problem dims
#define B4 4
#define S128 128
#define T129 129
#define H800 800
#define G3200 3200
#define E256 256
#define NE 66
#define NR 122
#define DPW 8      // LSTM dims per WG
#define NWGD 100   // LSTM WGs per direction

// ---------------------------------------------------------------------------
// gelu (jax approximate=True): 0.5*x*(1+tanh(sqrt(2/pi)*(x+0.044715 x^3)))
__device__ __forceinline__ float gelu_f(float x) {
    float t = 0.7978845608028654f * (x + 0.044715f * x * x * x);
    float e = __expf(2.f * t);           // overflow -> inf -> th=1 ; underflow -> 0 -> th=-1
    float th = 1.f - 2.f / (e + 1.f);
    return 0.5f * x * (1.f + th);
}

// ---------------------------------------------------------------------------
// K_embed: x[b,t,0:768]=bert, x[b,t,768:800]=pos_table[pos_ids[b,t-1]] (0 for t=0)
__global__ void k_embed(const float* __restrict__ bert, const int* __restrict__ pos_ids,
                        const float* __restrict__ ptab, float* __restrict__ x)
{
    int idx = blockIdx.x * 256 + threadIdx.x;
    if (idx >= B4 * T129 * H800) return;
    int c = idx % H800;
    int bt = idx / H800;
    int t = bt % T129, b = bt / T129;
    float v;
    if (c < 768) v = bert[(size_t)bt * 768 + c];
    else         v = (t == 0) ? 0.f : ptab[pos_ids[b * S128 + t - 1] * 32 + (c - 768)];
    x[idx] = v;
}

// ---------------------------------------------------------------------------
// Generic fp32 tiled GEMM. C[M,N] = A(M,K) * B  (+bias) with optional epilogue.
// AMODE: 0 direct row, 1 xg-view (row -> row + row/128 + 1)  [x[:,1:,:] view]
// BTRANS: 0: B is [K,N]; 1: B is [N,K] (A @ B^T)
// EPI: 0: C = acc (+bias); 1: C = res + relu(acc+bias)
template<int AMODE, int BTRANS, int EPI>
__global__ __launch_bounds__(256) void k_gemm(const float* __restrict__ A, const float* __restrict__ Bm,
                                              const float* __restrict__ bias, const float* __restrict__ res,
                                              float* __restrict__ C, int M, int N, int K)
{
    __shared__ float As[16][68];
    __shared__ float Bs[16][68];
    int m0 = blockIdx.x * 64, n0 = blockIdx.y * 64;
    int tid = threadIdx.x;
    int tm = tid & 15, tn = tid >> 4;
    float acc[4][4] = {};
    for (int k0 = 0; k0 < K; k0 += 16) {
        // A tile: As[kk][mm]
        {
            int kk = tid & 15, mmb = tid >> 4;
            #pragma unroll
            for (int q = 0; q < 4; q++) {
                int mm = mmb + q * 16;
                int m = m0 + mm;
                float v = 0.f;
                if (m < M) {
                    int row = (AMODE == 1) ? (m + (m >> 7) + 1) : m;
                    v = A[(size_t)row * K + k0 + kk];
                }
                As[kk][mm] = v;
            }
        }
        // B tile: Bs[kk][nn]
        if (BTRANS == 0) {
            int nn = (tid & 15) * 4, kk2 = tid >> 4;
            int n = n0 + nn;
            float t0, t1, t2, t3;
            if (n + 3 < N) {
                const float4 bv = *(const float4*)&Bm[(size_t)(k0 + kk2) * N + n];
                t0 = bv.x; t1 = bv.y; t2 = bv.z; t3 = bv.w;
            } else {
                t0 = (n + 0 < N) ? Bm[(size_t)(k0 + kk2) * N + n + 0] : 0.f;
                t1 = (n + 1 < N) ? Bm[(size_t)(k0 + kk2) * N + n + 1] : 0.f;
                t2 = (n + 2 < N) ? Bm[(size_t)(k0 + kk2) * N + n + 2] : 0.f;
                t3 = (n + 3 < N) ? Bm[(size_t)(k0 + kk2) * N + n + 3] : 0.f;
            }
            Bs[kk2][nn + 0] = t0; Bs[kk2][nn + 1] = t1; Bs[kk2][nn + 2] = t2; Bs[kk2][nn + 3] = t3;
        } else {
            int kk = tid & 15, nnb = tid >> 4;
            #pragma unroll
            for (int q = 0; q < 4; q++) {
                int nn = nnb + q * 16;
                int n = n0 + nn;
                Bs[kk][nn] = (n < N) ? Bm[(size_t)n * K + k0 + kk] : 0.f;
            }
        }
        __syncthreads();
        #pragma unroll
        for (int kk = 0; kk < 16; kk++) {
            float4 a = *(const float4*)&As[kk][tm * 4];
            float4 bb = *(const float4*)&Bs[kk][tn * 4];
            float av[4] = {a.x, a.y, a.z, a.w};
            float bv[4] = {bb.x, bb.y, bb.z, bb.w};
            #pragma unroll
            for (int xx = 0; xx < 4; xx++)
                #pragma unroll
                for (int yy = 0; yy < 4; yy++)
                    acc[xx][yy] += av[xx] * bv[yy];
        }
        __syncthreads();
    }
    #pragma unroll
    for (int xx = 0; xx < 4; xx++) {
        int m = m0 + tm * 4 + xx;
        if (m >= M) continue;
        #pragma unroll
        for (int yy = 0; yy < 4; yy++) {
            int n = n0 + tn * 4 + yy;
            if (n >= N) continue;
            float v = acc[xx][yy];
            if (bias) v += bias[n];
            if (EPI == 1) v = res[(size_t)m * N + n] + fmaxf(v, 0.f);
            C[(size_t)m * N + n] = v;
        }
    }
}

// ---------------------------------------------------------------------------
// Persistent BiLSTM v5 = r2's PROVEN exchange protocol + v3's register-weight
// compute partition. Grid: 200 WGs x 256 thr; WGs [0,100) fwd, [100,200) bwd.
// Each WG owns 8 h-dims; Whh slice in REGISTERS (100 floats/thread).
// h exchanged through the lstm output buffer itself (fresh region per t, single
// writer per element) via per-element relaxed AGENT atomics — exactly as r2.
// Release: __syncthreads -> tid0 {threadfence; RELEASE flag}. Acquire: wave-0
// poll (s_sleep(1)) -> threadfence -> __syncthreads. Poll at END of step.
__global__ __launch_bounds__(256) void k_lstm(const float* __restrict__ xWf, const float* __restrict__ xWb,
                                              const float* __restrict__ Whhf, const float* __restrict__ Whhb,
                                              float* __restrict__ lstm, int* __restrict__ flags)
{
    __shared__ float hb[4][800];        // h_{t-1}, 4 batches
    __shared__ float gsum[8][32][4];    // [k-slice][gate*8+dim][batch]
    int wg = blockIdx.x;
    int dir = wg >= NWGD ? 1 : 0;
    int wgd = dir ? wg - NWGD : wg;
    const float* Whh = dir ? Whhb : Whhf;
    const float* xW  = dir ? xWb  : xWf;
    int tid = threadIdx.x;
    int r = tid & 31;                   // row: gate g = r>>3, dim d = r&7
    int s = tid >> 5;                   // k-slice 0..7 (100 k each)
    int g = r >> 3, d = r & 7;
    int grow = g * 800 + wgd * DPW + d; // row in [0,3200)

    // one-time: weight slice into registers
    float wreg[100];
    {
        const float* wp = Whh + (size_t)grow * 800 + s * 100;
        #pragma unroll
        for (int q = 0; q < 100; q++) wreg[q] = wp[q];
    }
    for (int i = tid; i < 3200; i += 256) (&hb[0][0])[i] = 0.f;
    __syncthreads();

    float cst = 0.f;                    // cell state (threads tid<32)
    int fbase = dir * NWGD;

    for (int step = 0; step < 129; step++) {
        int t = dir ? (128 - step) : step;
        // prefetch gate inputs (x@Wih^T + b); read-only, safe before any wait
        float xq0 = 0.f, xq1 = 0.f, xq2 = 0.f, xq3 = 0.f;
        if (s == 0) {
            const float* xp = xW + (size_t)t * G3200 + grow;
            xq0 = xp[0];
            xq1 = xp[(size_t)T129 * G3200];
            xq2 = xp[2 * (size_t)T129 * G3200];
            xq3 = xp[3 * (size_t)T129 * G3200];
        }
        if (step > 0) {
            int tprev = dir ? (t + 1) : (t - 1);
            for (int i = tid; i < 3200; i += 256) {
                int bb = i / 800, dd = i - bb * 800;
                hb[bb][dd] = __hip_atomic_load(
                    &lstm[(size_t)((bb * T129 + tprev) * 1600) + dir * 800 + dd],
                    __ATOMIC_RELAXED, __HIP_MEMORY_SCOPE_AGENT);
            }
        }
        __syncthreads();
        // dot: own 100-k slice x 4 batches, weights in registers, h from LDS
        float a0, a1, a2, a3;
        if (s == 0) { a0 = xq0; a1 = xq1; a2 = xq2; a3 = xq3; }
        else        { a0 = a1 = a2 = a3 = 0.f; }
        {
            int k0 = s * 100;
            #pragma unroll
            for (int q = 0; q < 100; q += 4) {
                float4 h0 = *(const float4*)&hb[0][k0 + q];
                float4 h1 = *(const float4*)&hb[1][k0 + q];
                float4 h2 = *(const float4*)&hb[2][k0 + q];
                float4 h3 = *(const float4*)&hb[3][k0 + q];
                float w0 = wreg[q], w1 = wreg[q + 1], w2 = wreg[q + 2], w3 = wreg[q + 3];
                a0 += w0 * h0.x + w1 * h0.y + w2 * h0.z + w3 * h0.w;
                a1 += w0 * h1.x + w1 * h1.y + w2 * h1.z + w3 * h1.w;
                a2 += w0 * h2.x + w1 * h2.y + w2 * h2.z + w3 * h2.w;
                a3 += w0 * h3.x + w1 * h3.y + w2 * h3.z + w3 * h3.w;
            }
        }
        *(float4*)&gsum[s][r][0] = make_float4(a0, a1, a2, a3);
        __syncthreads();
        if (tid < 32) {
            int d2 = tid & 7, b2 = tid >> 3;
            float gi = 0.f, gf = 0.f, gg = 0.f, go = 0.f;
            #pragma unroll
            for (int ss = 0; ss < 8; ss++) {
                gi += gsum[ss][d2][b2];
                gf += gsum[ss][8 + d2][b2];
                gg += gsum[ss][16 + d2][b2];
                go += gsum[ss][24 + d2][b2];
            }
            float si = 1.f / (1.f + __expf(-gi));
            float sf = 1.f / (1.f + __expf(-gf));
            float so = 1.f / (1.f + __expf(-go));
            cst = sf * cst + si * tanhf(gg);
            float hv = so * tanhf(cst);
            __hip_atomic_store(&lstm[(size_t)((b2 * T129 + t) * 1600) + dir * 800 + wgd * DPW + d2], hv,
                               __ATOMIC_RELAXED, __HIP_MEMORY_SCOPE_AGENT);
        }
        if (step < 128) {
            __syncthreads();   // drains vmcnt: h stores are at the coherent point
            if (tid == 0) {
                __threadfence();
                __hip_atomic_store(&flags[fbase + wgd], step + 1,
                                   __ATOMIC_RELEASE, __HIP_MEMORY_SCOPE_AGENT);
            }
            if (tid < 64) {     // wave 0 polls this dir's 100 flags (25 lanes x 4)
                bool mine = (tid < 25);
                int base = fbase + tid * 4;
                long long iters = 0;
                for (;;) {
                    int mn = step + 1;
                    if (mine) {
                        int f0 = __hip_atomic_load(&flags[base + 0], __ATOMIC_RELAXED, __HIP_MEMORY_SCOPE_AGENT);
                        int f1 = __hip_atomic_load(&flags[base + 1], __ATOMIC_RELAXED, __HIP_MEMORY_SCOPE_AGENT);
                        int f2 = __hip_atomic_load(&flags[base + 2], __ATOMIC_RELAXED, __HIP_MEMORY_SCOPE_AGENT);
                        int f3 = __hip_atomic_load(&flags[base + 3], __ATOMIC_RELAXED, __HIP_MEMORY_SCOPE_AGENT);
                        mn = min(min(f0, f1), min(f2, f3));
                    }
                    if (__all(mn >= step + 1)) break;
                    if (++iters > 100000000LL) break;   // safety valve vs deadlock
                    __builtin_amdgcn_s_sleep(1);
                }
                __threadfence();   // acquire: order flag observation before h loads
            }
            __syncthreads();
        }
    }
}

// ---------------------------------------------------------------------------
// GAT attention coefficients: a_s[n,h] = sum_d h1[n,h*100+d]*asrc[h,d]; same a_d.
__global__ __launch_bounds__(256) void k_gat_coef(const float* __restrict__ h1,
                                                  const float* __restrict__ asrc, const float* __restrict__ adst,
                                                  float* __restrict__ a_s, float* __restrict__ a_d)
{
    int t = blockIdx.x * 256 + threadIdx.x;   // 512*8
    if (t >= 512 * 8) return;
    int h = t & 7, n = t >> 3;
    const float* hp = h1 + (size_t)n * H800 + h * 100;
    float s1 = 0.f, s2 = 0.f;
    for (int d = 0; d < 100; d++) {
        float hv = hp[d];
        s1 += hv * asrc[h * 100 + d];
        s2 += hv * adst[h * 100 + d];
    }
    a_s[t] = s1;
    a_d[t] = s2;
}

// Per (b,h): segment max + sum of exp over incident edges (incl self-loops).
__global__ __launch_bounds__(128) void k_gat_softmax(const int* __restrict__ esrc, const int* __restrict__ edst,
                                                     const float* __restrict__ a_s, const float* __restrict__ a_d,
                                                     float* __restrict__ mbuf, float* __restrict__ dbuf)
{
    __shared__ int se[384], de[384];
    __shared__ float asl[128], adl[128];
    int bh = blockIdx.x;
    int b = bh >> 3, h = bh & 7;
    int t = threadIdx.x;
    for (int e = t; e < 384; e += 128) {
        if (e < E256) { se[e] = esrc[b * E256 + e]; de[e] = edst[b * E256 + e]; }
        else          { se[e] = e - E256;           de[e] = e - E256; }
    }
    asl[t] = a_s[(b * S128 + t) * 8 + h];
    adl[t] = a_d[(b * S128 + t) * 8 + h];
    __syncthreads();
    float myad = adl[t];
    float m = -3.4e38f;
    for (int e = 0; e < 384; e++) {
        if (de[e] == t) {
            float sc = asl[se[e]] + myad;
            sc = (sc > 0.f) ? sc : 0.2f * sc;
            m = fmaxf(m, sc);
        }
    }
    float den = 0.f;
    for (int e = 0; e < 384; e++) {
        if (de[e] == t) {
            float sc = asl[se[e]] + myad;
            sc = (sc > 0.f) ? sc : 0.2f * sc;
            den += __expf(sc - m);
        }
    }
    mbuf[(b * S128 + t) * 8 + h] = m;
    dbuf[(b * S128 + t) * 8 + h] = den;
}

// Aggregate: out[n] = res[n] + relu( sum_e alpha*h1[src] + bias ). RESMODE 1: res is xg-view.
template<int RESMODE>
__global__ __launch_bounds__(512) void k_gat_agg(const int* __restrict__ esrc, const int* __restrict__ edst,
                                                 const float* __restrict__ a_s, const float* __restrict__ a_d,
                                                 const float* __restrict__ mbuf, const float* __restrict__ dbuf,
                                                 const float* __restrict__ h1, const float* __restrict__ gbias,
                                                 const float* __restrict__ res, float* __restrict__ out)
{
    __shared__ int se[384], de[384];
    __shared__ float asl[128], adl[128], ml[128], dl_[128];
    int bh = blockIdx.x;
    int b = bh >> 3, h = bh & 7;
    int t = threadIdx.x;
    if (t < 384) {
        if (t < E256) { se[t] = esrc[b * E256 + t]; de[t] = edst[b * E256 + t]; }
        else          { se[t] = t - E256;           de[t] = t - E256; }
    }
    if (t < 128) {
        asl[t] = a_s[(b * S128 + t) * 8 + h];
        adl[t] = a_d[(b * S128 + t) * 8 + h];
        ml[t]  = mbuf[(b * S128 + t) * 8 + h];
        dl_[t] = dbuf[(b * S128 + t) * 8 + h];
    }
    __syncthreads();
    int dst = t >> 2, ch = t & 3;
    int dd0 = ch * 25;
    float acc[25] = {};
    float myad = adl[dst], mym = ml[dst];
    for (int e = 0; e < 384; e++) {
        if (de[e] == dst) {
            int s = se[e];
            float sc = asl[s] + myad;
            sc = (sc > 0.f) ? sc : 0.2f * sc;
            float w = __expf(sc - mym);
            const float* hp = h1 + (size_t)(b * S128 + s) * H800 + h * 100 + dd0;
            #pragma unroll
            for (int q = 0; q < 25; q++) acc[q] += w * hp[q];
        }
    }
    float inv = 1.f / dl_[dst];
    int n = b * S128 + dst;
    size_t rrow = (RESMODE == 1) ? (size_t)(n + b + 1) * H800 : (size_t)n * H800;
    #pragma unroll
    for (int q = 0; q < 25; q++) {
        int col = h * 100 + dd0 + q;
        float v = acc[q] * inv + gbias[col];
        out[(size_t)n * H800 + col] = res[rrow + col] + fmaxf(v, 0.f);
    }
}

// ---------------------------------------------------------------------------
// Trig head on the diagonal only: 512 rows. One wave per (b,i).
__global__ __launch_bounds__(64) void k_trig(const float* __restrict__ u, const float* __restrict__ v,
                                             const float* __restrict__ W, const float* __restrict__ bias,
                                             const int* __restrict__ labels, float* __restrict__ d_out)
{
    __shared__ float s[800];
    __shared__ float lg[66];
    int bi = blockIdx.x;          // b*128+i
    int i = bi & 127;
    int l = threadIdx.x;
    const float* ur = u + (size_t)bi * H800;
    const float* vr = v + (size_t)bi * H800;
    for (int k = l; k < 800; k += 64) s[k] = gelu_f(ur[k] + vr[k]);
    __syncthreads();
    float a0 = 0.f, a1 = 0.f;
    bool has2 = (l < 2);
    for (int k = 0; k < 800; k++) {
        float sv = s[k];
        a0 += sv * W[k * NE + l];
        if (has2) a1 += sv * W[k * NE + 64 + l];
    }
    lg[l] = a0 + bias[l];
    if (has2) lg[64 + l] = a1 + bias[64 + l];
    __syncthreads();
    if (l == 0) {
        float m = lg[0];
        for (int c = 1; c < NE; c++) m = fmaxf(m, lg[c]);
        float se = 0.f, sl = 0.f, bv = lg[0];
        int am = 0;
        for (int c = 0; c < NE; c++) {
            se += __expf(lg[c] - m);
            sl += lg[c];
            if (lg[c] > bv) { bv = lg[c]; am = c; }
        }
        float lse = m + __logf(se);
        int tgt = labels[(size_t)bi * S128 + i];       // start_labels[b,i,i]
        float ce = (0.1f / NE) * (NE * lse - sl) + 0.9f * (lse - lg[tgt]);
        atomicAdd(d_out, ce * (1.f / 128.f));
        int r = bi * S128 + i;
        d_out[1 + r] = (float)am;
        d_out[1 + 65536 + r] = (float)am;
    }
}

// ---------------------------------------------------------------------------
// Fused rs+re logits for one batch: rows r = i*128+j (16384), cols 0..255
// (col<128 -> rs head col c, col>=128 -> re head col c-128; valid c<122).
// A built on the fly: gelu(u[b,i,k] + v[b,j,k]) — built ONCE for both heads.
__global__ __launch_bounds__(256) void k_logits2(const float* __restrict__ ub, const float* __restrict__ vb,
                                                 const float* __restrict__ rsW, const float* __restrict__ rsb,
                                                 const float* __restrict__ reW, const float* __restrict__ reb,
                                                 float* __restrict__ L)
{
    __shared__ float As[16][68];
    __shared__ float Bs[16][256];
    int il = blockIdx.x >> 1;               // i 0..127
    int j0 = (blockIdx.x & 1) * 64;
    const float* urow = ub + (size_t)il * H800;
    int tid = threadIdx.x;
    int tm = tid & 15, tn = tid >> 4;       // rows tm*4..+3, cols tn*16..+15
    float acc[4][16] = {};
    // B column for this thread (persistent across k0)
    int ct = tid;
    int hc = (ct < 128) ? ct : (ct - 128);
    const float* Wp = (ct < 128) ? rsW : reW;
    bool cok = hc < NR;
    for (int k0 = 0; k0 < 800; k0 += 16) {
        {
            int kk = tid & 15, rrb = tid >> 4;
            float uk = urow[k0 + kk];
            #pragma unroll
            for (int q = 0; q < 4; q++) {
                int rr = rrb + q * 16;
                float xv = uk + vb[(size_t)(j0 + rr) * H800 + k0 + kk];
                As[kk][rr] = gelu_f(xv);
            }
        }
        #pragma unroll
        for (int kk2 = 0; kk2 < 16; kk2++)
            Bs[kk2][ct] = cok ? Wp[(size_t)(k0 + kk2) * NR + hc] : 0.f;
        __syncthreads();
        #pragma unroll
        for (int kk = 0; kk < 16; kk++) {
            float4 a = *(const float4*)&As[kk][tm * 4];
            float av[4] = {a.x, a.y, a.z, a.w};
            float bv[16];
            #pragma unroll
            for (int q = 0; q < 4; q++) {
                float4 bb = *(const float4*)&Bs[kk][tn * 16 + q * 4];
                bv[q * 4 + 0] = bb.x; bv[q * 4 + 1] = bb.y; bv[q * 4 + 2] = bb.z; bv[q * 4 + 3] = bb.w;
            }
            #pragma unroll
            for (int xx = 0; xx < 4; xx++)
                #pragma unroll
                for (int yy = 0; yy < 16; yy++)
                    acc[xx][yy] += av[xx] * bv[yy];
        }
        __syncthreads();
    }
    #pragma unroll
    for (int xx = 0; xx < 4; xx++) {
        int r = il * S128 + j0 + tm * 4 + xx;
        #pragma unroll
        for (int yy = 0; yy < 16; yy++) {
            int cc = tn * 16 + yy;
            int head = cc >> 7, c = cc & 127;
            if (c < NR)
                L[(size_t)r * 256 + cc] = acc[xx][yy] + (head ? reb[c] : rsb[c]);
        }
    }
}

// CE loss + symmetric argmax over one batch's 122-class logits (stride-256 buffer,
// head selects column half). One wave per row.
__global__ __launch_bounds__(256) void k_loss_arg(const float* __restrict__ L, int head,
                                                  const int* __restrict__ labels,
                                                  float* __restrict__ resout, float* __restrict__ lossptr)
{
    __shared__ float wsum[4];
    int wv = threadIdx.x >> 6, l = threadIdx.x & 63;
    int r = blockIdx.x * 4 + wv;          // local row in [0,16384)
    int i = r >> 7, j = r & 127;
    float ce = 0.f;
    if (i != j) {
        const float* row = L + (size_t)r * 256 + head * 128;
        int p = (j << 7) | i;
        const float* prow = L + (size_t)p * 256 + head * 128;
        float x1 = row[l];
        bool v2 = (l < NR - 64);
        float x2 = v2 ? row[l + 64] : -3.4e38f;
        float m = fmaxf(x1, x2);
        #pragma unroll
        for (int s = 32; s; s >>= 1) m = fmaxf(m, __shfl_xor(m, s, 64));
        float se = __expf(x1 - m) + (v2 ? __expf(x2 - m) : 0.f);
        float sl = x1 + (v2 ? x2 : 0.f);
        #pragma unroll
        for (int s = 32; s; s >>= 1) { se += __shfl_xor(se, s, 64); sl += __shfl_xor(sl, s, 64); }
        float lse = m + __logf(se);
        int tgt = labels[r];
        float lt = row[tgt];
        ce = (0.1f / NR) * (NR * lse - sl) + 0.9f * (lse - lt);
        // argmax of row + row^T (first-max tie rule)
        float y1 = x1 + prow[l];
        float y2 = v2 ? (x2 + prow[l + 64]) : -3.4e38f;
        float bv; int bidx;
        if (y2 > y1) { bv = y2; bidx = l + 64; } else { bv = y1; bidx = l; }
        #pragma unroll
        for (int s = 32; s; s >>= 1) {
            float ov = __shfl_xor(bv, s, 64);
            int oi = __shfl_xor(bidx, s, 64);
            if (ov > bv || (ov == bv && oi < bidx)) { bv = ov; bidx = oi; }
        }
        if (l == 0) resout[r] = (float)bidx;
    }
    if (l == 0) wsum[wv] = ce;
    __syncthreads();
    if (threadIdx.x == 0) {
        float s = (wsum[0] + wsum[1] + wsum[2] + wsum[3]) * (1.f / 16256.f);
        atomicAdd(lossptr, s);
    }
}

// ---------------------------------------------------------------------------
extern "C" void kernel_launch(void* const* d_in, const int* in_sizes, int n_in,
                              void* d_out, int out_size, void* d_ws, size_t ws_size,
                              hipStream_t stream)
{
    (void)in_sizes; (void)n_in; (void)out_size; (void)ws_size;
    const float* bert  = (const float*)d_in[0];
    const int*   pids  = (const int*)d_in[1];
    const int*   esrc  = (const int*)d_in[2];
    const int*   edst  = (const int*)d_in[3];
    const int*   slab  = (const int*)d_in[4];
    const int*   elab  = (const int*)d_in[5];
    const float* ptab  = (const float*)d_in[6];
    const float* Wih_f = (const float*)d_in[7];
    const float* Whh_f = (const float*)d_in[8];
    const float* bl_f  = (const float*)d_in[9];
    const float* Wih_b = (const float*)d_in[10];
    const float* Whh_b = (const float*)d_in[11];
    const float* bl_b  = (const float*)d_in[12];
    const float* fcW   = (const float*)d_in[13];
    const float* fcb   = (const float*)d_in[14];
    const float* tW    = (const float*)d_in[15];
    const float* tb    = (const float*)d_in[16];
    const float* gatW  = (const float*)d_in[17];
    const float* asrc  = (const float*)d_in[18];
    const float* adst  = (const float*)d_in[19];
    const float* gbias = (const float*)d_in[20];
    const float* trigW = (const float*)d_in[21];
    const float* trigb = (const float*)d_in[22];
    const float* rsW   = (const float*)d_in[23];
    const float* rsb   = (const float*)d_in[24];
    const float* reW   = (const float*)d_in[25];
    const float* reb   = (const float*)d_in[26];
    float* out = (float*)d_out;

    float* ws = (float*)d_ws;
    size_t off = 0;
    auto alloc = [&](size_t n) { float* p = ws + off; off += (n + 255) & ~(size_t)255; return p; };
    float* x    = alloc(516 * 800);
    float* xWf  = alloc((size_t)516 * 3200);
    float* xWb  = alloc((size_t)516 * 3200);
    float* lstm = alloc((size_t)516 * 1600);
    float* xg   = alloc(516 * 800);
    float* h1   = alloc(512 * 800);
    float* g1   = alloc(512 * 800);
    float* g2   = alloc(512 * 800);
    float* uu   = alloc(512 * 800);
    float* vv   = alloc(512 * 800);
    float* as_  = alloc(4096);
    float* ad_  = alloc(4096);
    float* mb   = alloc(4096);
    float* db   = alloc(4096);
    float* Lbuf = alloc((size_t)16384 * 256);
    int*   flags = (int*)alloc(512);

    hipMemsetAsync(d_out, 0, 4, stream);                 // loss accumulator
    hipMemsetAsync(flags, 0, 2 * NWGD * sizeof(int), stream);

    k_embed<<<(B4 * T129 * H800 + 255) / 256, 256, 0, stream>>>(bert, pids, ptab, x);

    // gate-input precompute: xW = x @ Wih^T + bl  (bias folded here)
    k_gemm<0, 1, 0><<<dim3(9, 50), 256, 0, stream>>>(x, Wih_f, bl_f, nullptr, xWf, 516, 3200, 800);
    k_gemm<0, 1, 0><<<dim3(9, 50), 256, 0, stream>>>(x, Wih_b, bl_b, nullptr, xWb, 516, 3200, 800);

    k_lstm<<<2 * NWGD, 256, 0, stream>>>(xWf, xWb, Whh_f, Whh_b, lstm, flags);

    // xg = x + relu(lstm @ fcW + fcb)
    k_gemm<0, 0, 1><<<dim3(9, 13), 256, 0, stream>>>(lstm, fcW, fcb, x, xg, 516, 800, 1600);

    // GAT layer 1 (input = xg[:,1:,:] view via AMODE/RESMODE 1)
    k_gemm<1, 0, 0><<<dim3(8, 13), 256, 0, stream>>>(xg, gatW, nullptr, nullptr, h1, 512, 800, 800);
    k_gat_coef<<<16, 256, 0, stream>>>(h1, asrc, adst, as_, ad_);
    k_gat_softmax<<<32, 128, 0, stream>>>(esrc, edst, as_, ad_, mb, db);
    k_gat_agg<1><<<32, 512, 0, stream>>>(esrc, edst, as_, ad_, mb, db, h1, gbias, xg, g1);
    // GAT layer 2
    k_gemm<0, 0, 0><<<dim3(8, 13), 256, 0, stream>>>(g1, gatW, nullptr, nullptr, h1, 512, 800, 800);
    k_gat_coef<<<16, 256, 0, stream>>>(h1, asrc, adst, as_, ad_);
    k_gat_softmax<<<32, 128, 0, stream>>>(esrc, edst, as_, ad_, mb, db);
    k_gat_agg<0><<<32, 512, 0, stream>>>(esrc, edst, as_, ad_, mb, db, h1, gbias, g1, g2);

    // table split: u = g2@tW[:800] + tb ; v = g2@tW[800:]
    k_gemm<0, 0, 0><<<dim3(8, 13), 256, 0, stream>>>(g2, tW, tb, nullptr, uu, 512, 800, 800);
    k_gemm<0, 0, 0><<<dim3(8, 13), 256, 0, stream>>>(g2, tW + (size_t)800 * 800, nullptr, nullptr, vv, 512, 800, 800);

    // trig head: diagonal only (l1 + results diag)
    k_trig<<<512, 64, 0, stream>>>(uu, vv, trigW, trigb, slab, out);

    // fused rs+re heads per batch (l2, l3, off-diag results)
    for (int b = 0; b < B4; b++) {
        k_logits2<<<256, 256, 0, stream>>>(uu + (size_t)b * 128 * 800, vv + (size_t)b * 128 * 800,
                                           rsW, rsb, reW, reb, Lbuf);
        k_loss_arg<<<4096, 256, 0, stream>>>(Lbuf, 0, slab + (size_t)b * 16384, out + 1 + (size_t)b * 16384, out);
        k_loss_arg<<<4096, 256, 0, stream>>>(Lbuf, 1, elab + (size_t)b * 16384, out + 1 + 65536 + (size_t)b * 16384, out);
    }
}

// Round 6
// 3730.740 us; speedup vs baseline: 1.8807x; 1.2175x over previous
//
#include <hip/hip_runtime.h>
#include <hip/hip_bf16.h>

// Problem dims
#define B4 4
#define S128 128
#define T129 129
#define H800 800
#define G3200 3200
#define E256 256
#define NE 66
#define NR 122
#define DPW 8      // LSTM dims per WG
#define NWGD 100   // LSTM WGs per direction

typedef float f32x4 __attribute__((ext_vector_type(4)));

// ---------------------------------------------------------------------------
// gelu (jax approximate=True): 0.5*x*(1+tanh(sqrt(2/pi)*(x+0.044715 x^3)))
__device__ __forceinline__ float gelu_f(float x) {
    float t = 0.7978845608028654f * (x + 0.044715f * x * x * x);
    float e = __expf(2.f * t);           // overflow -> inf -> th=1 ; underflow -> 0 -> th=-1
    float th = 1.f - 2.f / (e + 1.f);
    return 0.5f * x * (1.f + th);
}

// ---------------------------------------------------------------------------
// K_embed: x[b,t,0:768]=bert, x[b,t,768:800]=pos_table[pos_ids[b,t-1]] (0 for t=0)
__global__ void k_embed(const float* __restrict__ bert, const int* __restrict__ pos_ids,
                        const float* __restrict__ ptab, float* __restrict__ x)
{
    int idx = blockIdx.x * 256 + threadIdx.x;
    if (idx >= B4 * T129 * H800) return;
    int c = idx % H800;
    int bt = idx / H800;
    int t = bt % T129, b = bt / T129;
    float v;
    if (c < 768) v = bert[(size_t)bt * 768 + c];
    else         v = (t == 0) ? 0.f : ptab[pos_ids[b * S128 + t - 1] * 32 + (c - 768)];
    x[idx] = v;
}

// ---------------------------------------------------------------------------
// Generic fp32 tiled GEMM. C[M,N] = A(M,K) * B  (+bias) with optional epilogue.
// AMODE: 0 direct row, 1 xg-view (row -> row + row/128 + 1)  [x[:,1:,:] view]
// BTRANS: 0: B is [K,N]; 1: B is [N,K] (A @ B^T)
// EPI: 0: C = acc (+bias); 1: C = res + relu(acc+bias)
template<int AMODE, int BTRANS, int EPI>
__global__ __launch_bounds__(256) void k_gemm(const float* __restrict__ A, const float* __restrict__ Bm,
                                              const float* __restrict__ bias, const float* __restrict__ res,
                                              float* __restrict__ C, int M, int N, int K)
{
    __shared__ float As[16][68];
    __shared__ float Bs[16][68];
    int m0 = blockIdx.x * 64, n0 = blockIdx.y * 64;
    int tid = threadIdx.x;
    int tm = tid & 15, tn = tid >> 4;
    float acc[4][4] = {};
    for (int k0 = 0; k0 < K; k0 += 16) {
        // A tile: As[kk][mm]
        {
            int kk = tid & 15, mmb = tid >> 4;
            #pragma unroll
            for (int q = 0; q < 4; q++) {
                int mm = mmb + q * 16;
                int m = m0 + mm;
                float v = 0.f;
                if (m < M) {
                    int row = (AMODE == 1) ? (m + (m >> 7) + 1) : m;
                    v = A[(size_t)row * K + k0 + kk];
                }
                As[kk][mm] = v;
            }
        }
        // B tile: Bs[kk][nn]
        if (BTRANS == 0) {
            int nn = (tid & 15) * 4, kk2 = tid >> 4;
            int n = n0 + nn;
            float t0, t1, t2, t3;
            if (n + 3 < N) {
                const float4 bv = *(const float4*)&Bm[(size_t)(k0 + kk2) * N + n];
                t0 = bv.x; t1 = bv.y; t2 = bv.z; t3 = bv.w;
            } else {
                t0 = (n + 0 < N) ? Bm[(size_t)(k0 + kk2) * N + n + 0] : 0.f;
                t1 = (n + 1 < N) ? Bm[(size_t)(k0 + kk2) * N + n + 1] : 0.f;
                t2 = (n + 2 < N) ? Bm[(size_t)(k0 + kk2) * N + n + 2] : 0.f;
                t3 = (n + 3 < N) ? Bm[(size_t)(k0 + kk2) * N + n + 3] : 0.f;
            }
            Bs[kk2][nn + 0] = t0; Bs[kk2][nn + 1] = t1; Bs[kk2][nn + 2] = t2; Bs[kk2][nn + 3] = t3;
        } else {
            int kk = tid & 15, nnb = tid >> 4;
            #pragma unroll
            for (int q = 0; q < 4; q++) {
                int nn = nnb + q * 16;
                int n = n0 + nn;
                Bs[kk][nn] = (n < N) ? Bm[(size_t)n * K + k0 + kk] : 0.f;
            }
        }
        __syncthreads();
        #pragma unroll
        for (int kk = 0; kk < 16; kk++) {
            float4 a = *(const float4*)&As[kk][tm * 4];
            float4 bb = *(const float4*)&Bs[kk][tn * 4];
            float av[4] = {a.x, a.y, a.z, a.w};
            float bv[4] = {bb.x, bb.y, bb.z, bb.w};
            #pragma unroll
            for (int xx = 0; xx < 4; xx++)
                #pragma unroll
                for (int yy = 0; yy < 4; yy++)
                    acc[xx][yy] += av[xx] * bv[yy];
        }
        __syncthreads();
    }
    #pragma unroll
    for (int xx = 0; xx < 4; xx++) {
        int m = m0 + tm * 4 + xx;
        if (m >= M) continue;
        #pragma unroll
        for (int yy = 0; yy < 4; yy++) {
            int n = n0 + tn * 4 + yy;
            if (n >= N) continue;
            float v = acc[xx][yy];
            if (bias) v += bias[n];
            if (EPI == 1) v = res[(size_t)m * N + n] + fmaxf(v, 0.f);
            C[(size_t)m * N + n] = v;
        }
    }
}

// ---------------------------------------------------------------------------
// Persistent BiLSTM v6 = r5's PROVEN exchange buffer/protocol, mechanics
// vectorized. Grid: 200 WGs x 256 thr; WGs [0,100) fwd, [100,200) bwd.
// Each WG owns 8 h-dims; Whh slice in REGISTERS (100 floats/thread).
// h exchanged through the lstm output buffer (fresh region per t, single writer
// per element) via dwordx4 sc0 sc1 (device-coherent point, bypasses L1/L2 — the
// vectorized equivalent of r5's per-element agent atomics). Release: wave-0
// s_waitcnt vmcnt(0) -> relaxed flag store. Acquire: ALL waves hot-poll flags
// (keeps clocks up, doubles as barrier) -> __syncthreads -> sc0sc1 loads.
__global__ __launch_bounds__(256) void k_lstm(const float* __restrict__ xWf, const float* __restrict__ xWb,
                                              const float* __restrict__ Whhf, const float* __restrict__ Whhb,
                                              float* __restrict__ lstm, int* __restrict__ flags)
{
    __shared__ float hb[4][800];        // h_{t-1}, 4 batches
    __shared__ float gsum[8][32][4];    // [k-slice][gate*8+dim][batch]
    int wg = blockIdx.x;
    int dir = wg >= NWGD ? 1 : 0;
    int wgd = dir ? wg - NWGD : wg;
    const float* Whh = dir ? Whhb : Whhf;
    const float* xW  = dir ? xWb  : xWf;
    int tid = threadIdx.x;
    int r = tid & 31;                   // row: gate g = r>>3, dim d = r&7
    int s = tid >> 5;                   // k-slice 0..7 (100 k each)
    int g = r >> 3, d = r & 7;
    int grow = g * 800 + wgd * DPW + d; // row in [0,3200)
    int lane = tid & 63;
    int wv = tid >> 6;

    // one-time: weight slice into registers
    float wreg[100];
    {
        const float* wp = Whh + (size_t)grow * 800 + s * 100;
        #pragma unroll
        for (int q = 0; q < 100; q++) wreg[q] = wp[q];
    }
    for (int i = tid; i < 3200; i += 256) (&hb[0][0])[i] = 0.f;
    __syncthreads();

    float cst = 0.f;                    // cell state (threads tid<32)
    int fbase = dir * NWGD;

    for (int step = 0; step < 129; step++) {
        int t = dir ? (128 - step) : step;
        // prefetch gate inputs (x@Wih^T + b); read-only, safe before any wait
        float xq0 = 0.f, xq1 = 0.f, xq2 = 0.f, xq3 = 0.f;
        if (s == 0) {
            const float* xp = xW + (size_t)t * G3200 + grow;
            xq0 = xp[0];
            xq1 = xp[(size_t)T129 * G3200];
            xq2 = xp[2 * (size_t)T129 * G3200];
            xq3 = xp[3 * (size_t)T129 * G3200];
        }
        if (step > 0) {
            // hot poll by ALL waves (each wave verifies all 100 flags of this dir)
            {
                bool mine = (lane < 25);
                int base = fbase + lane * 4;
                long long iters = 0;
                for (;;) {
                    int mn = step;
                    if (mine) {
                        int f0 = __hip_atomic_load(&flags[base + 0], __ATOMIC_RELAXED, __HIP_MEMORY_SCOPE_AGENT);
                        int f1 = __hip_atomic_load(&flags[base + 1], __ATOMIC_RELAXED, __HIP_MEMORY_SCOPE_AGENT);
                        int f2 = __hip_atomic_load(&flags[base + 2], __ATOMIC_RELAXED, __HIP_MEMORY_SCOPE_AGENT);
                        int f3 = __hip_atomic_load(&flags[base + 3], __ATOMIC_RELAXED, __HIP_MEMORY_SCOPE_AGENT);
                        mn = min(min(f0, f1), min(f2, f3));
                    }
                    if (__all(mn >= step)) break;
                    if (++iters > 50000000LL) break;    // safety valve vs deadlock
                }
            }
            __syncthreads();
            int tprev = dir ? (t + 1) : (t - 1);
            // device-coherent vectorized load of h_{t-1}: 200 thr x 4 float4
            if (tid < 200) {
                const f32x4* p0 = (const f32x4*)(lstm + (size_t)((0 * T129 + tprev) * 1600) + dir * 800) + tid;
                const f32x4* p1 = (const f32x4*)(lstm + (size_t)((1 * T129 + tprev) * 1600) + dir * 800) + tid;
                const f32x4* p2 = (const f32x4*)(lstm + (size_t)((2 * T129 + tprev) * 1600) + dir * 800) + tid;
                const f32x4* p3 = (const f32x4*)(lstm + (size_t)((3 * T129 + tprev) * 1600) + dir * 800) + tid;
                f32x4 v0, v1, v2, v3;
                asm volatile(
                    "global_load_dwordx4 %0, %4, off sc0 sc1\n\t"
                    "global_load_dwordx4 %1, %5, off sc0 sc1\n\t"
                    "global_load_dwordx4 %2, %6, off sc0 sc1\n\t"
                    "global_load_dwordx4 %3, %7, off sc0 sc1\n\t"
                    "s_waitcnt vmcnt(0)"
                    : "=&v"(v0), "=&v"(v1), "=&v"(v2), "=&v"(v3)
                    : "v"(p0), "v"(p1), "v"(p2), "v"(p3)
                    : "memory");
                f32x4* dst = (f32x4*)&hb[0][0];
                dst[tid] = v0; dst[tid + 200] = v1; dst[tid + 400] = v2; dst[tid + 600] = v3;
            }
            __syncthreads();
        }
        // dot: own 100-k slice x 4 batches, weights in registers, h from LDS
        float a0, a1, a2, a3;
        if (s == 0) { a0 = xq0; a1 = xq1; a2 = xq2; a3 = xq3; }
        else        { a0 = a1 = a2 = a3 = 0.f; }
        {
            int k0 = s * 100;
            #pragma unroll
            for (int q = 0; q < 100; q += 4) {
                float4 h0 = *(const float4*)&hb[0][k0 + q];
                float4 h1 = *(const float4*)&hb[1][k0 + q];
                float4 h2 = *(const float4*)&hb[2][k0 + q];
                float4 h3 = *(const float4*)&hb[3][k0 + q];
                float w0 = wreg[q], w1 = wreg[q + 1], w2 = wreg[q + 2], w3 = wreg[q + 3];
                a0 += w0 * h0.x + w1 * h0.y + w2 * h0.z + w3 * h0.w;
                a1 += w0 * h1.x + w1 * h1.y + w2 * h1.z + w3 * h1.w;
                a2 += w0 * h2.x + w1 * h2.y + w2 * h2.z + w3 * h2.w;
                a3 += w0 * h3.x + w1 * h3.y + w2 * h3.z + w3 * h3.w;
            }
        }
        *(float4*)&gsum[s][r][0] = make_float4(a0, a1, a2, a3);
        __syncthreads();
        // wave 0: reduce, activate, publish h (others fall through to next poll)
        float hv = 0.f;
        if (tid < 32) {
            int d2 = tid & 7, b2 = tid >> 3;
            float gi = 0.f, gf = 0.f, gg = 0.f, go = 0.f;
            #pragma unroll
            for (int ss = 0; ss < 8; ss++) {
                gi += gsum[ss][d2][b2];
                gf += gsum[ss][8 + d2][b2];
                gg += gsum[ss][16 + d2][b2];
                go += gsum[ss][24 + d2][b2];
            }
            float si = 1.f / (1.f + __expf(-gi));
            float sf = 1.f / (1.f + __expf(-gf));
            float so = 1.f / (1.f + __expf(-go));
            cst = sf * cst + si * tanhf(gg);
            hv = so * tanhf(cst);       // lane tid holds h for (b=tid>>3, d=tid&7)
        }
        if (wv == 0) {
            // gather 4 consecutive hv's into lanes 0..7 and store as dwordx4
            int src = (lane & 7) * 4;
            f32x4 o;
            o.x = __shfl(hv, src + 0, 64);
            o.y = __shfl(hv, src + 1, 64);
            o.z = __shfl(hv, src + 2, 64);
            o.w = __shfl(hv, src + 3, 64);
            if (lane < 8) {
                int bb = lane >> 1, half = lane & 1;
                float* ap = lstm + (size_t)((bb * T129 + t) * 1600) + dir * 800 + wgd * DPW + half * 4;
                asm volatile("global_store_dwordx4 %0, %1, off sc0 sc1"
                             :: "v"((f32x4*)ap), "v"(o) : "memory");
            }
            // release: drain wave-0's data stores before flag escapes
            asm volatile("s_waitcnt vmcnt(0)" ::: "memory");
            if (tid == 0 && step < 128)
                __hip_atomic_store(&flags[fbase + wgd], step + 1,
                                   __ATOMIC_RELAXED, __HIP_MEMORY_SCOPE_AGENT);
        }
    }
}

// ---------------------------------------------------------------------------
// GAT attention coefficients: a_s[n,h] = sum_d h1[n,h*100+d]*asrc[h,d]; same a_d.
__global__ __launch_bounds__(256) void k_gat_coef(const float* __restrict__ h1,
                                                  const float* __restrict__ asrc, const float* __restrict__ adst,
                                                  float* __restrict__ a_s, float* __restrict__ a_d)
{
    int t = blockIdx.x * 256 + threadIdx.x;   // 512*8
    if (t >= 512 * 8) return;
    int h = t & 7, n = t >> 3;
    const float* hp = h1 + (size_t)n * H800 + h * 100;
    float s1 = 0.f, s2 = 0.f;
    for (int d = 0; d < 100; d++) {
        float hv = hp[d];
        s1 += hv * asrc[h * 100 + d];
        s2 += hv * adst[h * 100 + d];
    }
    a_s[t] = s1;
    a_d[t] = s2;
}

// Per (b,h): segment max + sum of exp over incident edges (incl self-loops).
__global__ __launch_bounds__(128) void k_gat_softmax(const int* __restrict__ esrc, const int* __restrict__ edst,
                                                     const float* __restrict__ a_s, const float* __restrict__ a_d,
                                                     float* __restrict__ mbuf, float* __restrict__ dbuf)
{
    __shared__ int se[384], de[384];
    __shared__ float asl[128], adl[128];
    int bh = blockIdx.x;
    int b = bh >> 3, h = bh & 7;
    int t = threadIdx.x;
    for (int e = t; e < 384; e += 128) {
        if (e < E256) { se[e] = esrc[b * E256 + e]; de[e] = edst[b * E256 + e]; }
        else          { se[e] = e - E256;           de[e] = e - E256; }
    }
    asl[t] = a_s[(b * S128 + t) * 8 + h];
    adl[t] = a_d[(b * S128 + t) * 8 + h];
    __syncthreads();
    float myad = adl[t];
    float m = -3.4e38f;
    for (int e = 0; e < 384; e++) {
        if (de[e] == t) {
            float sc = asl[se[e]] + myad;
            sc = (sc > 0.f) ? sc : 0.2f * sc;
            m = fmaxf(m, sc);
        }
    }
    float den = 0.f;
    for (int e = 0; e < 384; e++) {
        if (de[e] == t) {
            float sc = asl[se[e]] + myad;
            sc = (sc > 0.f) ? sc : 0.2f * sc;
            den += __expf(sc - m);
        }
    }
    mbuf[(b * S128 + t) * 8 + h] = m;
    dbuf[(b * S128 + t) * 8 + h] = den;
}

// Aggregate: out[n] = res[n] + relu( sum_e alpha*h1[src] + bias ). RESMODE 1: res is xg-view.
template<int RESMODE>
__global__ __launch_bounds__(512) void k_gat_agg(const int* __restrict__ esrc, const int* __restrict__ edst,
                                                 const float* __restrict__ a_s, const float* __restrict__ a_d,
                                                 const float* __restrict__ mbuf, const float* __restrict__ dbuf,
                                                 const float* __restrict__ h1, const float* __restrict__ gbias,
                                                 const float* __restrict__ res, float* __restrict__ out)
{
    __shared__ int se[384], de[384];
    __shared__ float asl[128], adl[128], ml[128], dl_[128];
    int bh = blockIdx.x;
    int b = bh >> 3, h = bh & 7;
    int t = threadIdx.x;
    if (t < 384) {
        if (t < E256) { se[t] = esrc[b * E256 + t]; de[t] = edst[b * E256 + t]; }
        else          { se[t] = t - E256;           de[t] = t - E256; }
    }
    if (t < 128) {
        asl[t] = a_s[(b * S128 + t) * 8 + h];
        adl[t] = a_d[(b * S128 + t) * 8 + h];
        ml[t]  = mbuf[(b * S128 + t) * 8 + h];
        dl_[t] = dbuf[(b * S128 + t) * 8 + h];
    }
    __syncthreads();
    int dst = t >> 2, ch = t & 3;
    int dd0 = ch * 25;
    float acc[25] = {};
    float myad = adl[dst], mym = ml[dst];
    for (int e = 0; e < 384; e++) {
        if (de[e] == dst) {
            int s = se[e];
            float sc = asl[s] + myad;
            sc = (sc > 0.f) ? sc : 0.2f * sc;
            float w = __expf(sc - mym);
            const float* hp = h1 + (size_t)(b * S128 + s) * H800 + h * 100 + dd0;
            #pragma unroll
            for (int q = 0; q < 25; q++) acc[q] += w * hp[q];
        }
    }
    float inv = 1.f / dl_[dst];
    int n = b * S128 + dst;
    size_t rrow = (RESMODE == 1) ? (size_t)(n + b + 1) * H800 : (size_t)n * H800;
    #pragma unroll
    for (int q = 0; q < 25; q++) {
        int col = h * 100 + dd0 + q;
        float v = acc[q] * inv + gbias[col];
        out[(size_t)n * H800 + col] = res[rrow + col] + fmaxf(v, 0.f);
    }
}

// ---------------------------------------------------------------------------
// Trig head on the diagonal only: 512 rows. One wave per (b,i).
__global__ __launch_bounds__(64) void k_trig(const float* __restrict__ u, const float* __restrict__ v,
                                             const float* __restrict__ W, const float* __restrict__ bias,
                                             const int* __restrict__ labels, float* __restrict__ d_out)
{
    __shared__ float s[800];
    __shared__ float lg[66];
    int bi = blockIdx.x;          // b*128+i
    int i = bi & 127;
    int l = threadIdx.x;
    const float* ur = u + (size_t)bi * H800;
    const float* vr = v + (size_t)bi * H800;
    for (int k = l; k < 800; k += 64) s[k] = gelu_f(ur[k] + vr[k]);
    __syncthreads();
    float a0 = 0.f, a1 = 0.f;
    bool has2 = (l < 2);
    for (int k = 0; k < 800; k++) {
        float sv = s[k];
        a0 += sv * W[k * NE + l];
        if (has2) a1 += sv * W[k * NE + 64 + l];
    }
    lg[l] = a0 + bias[l];
    if (has2) lg[64 + l] = a1 + bias[64 + l];
    __syncthreads();
    if (l == 0) {
        float m = lg[0];
        for (int c = 1; c < NE; c++) m = fmaxf(m, lg[c]);
        float se = 0.f, sl = 0.f, bv = lg[0];
        int am = 0;
        for (int c = 0; c < NE; c++) {
            se += __expf(lg[c] - m);
            sl += lg[c];
            if (lg[c] > bv) { bv = lg[c]; am = c; }
        }
        float lse = m + __logf(se);
        int tgt = labels[(size_t)bi * S128 + i];       // start_labels[b,i,i]
        float ce = (0.1f / NE) * (NE * lse - sl) + 0.9f * (lse - lg[tgt]);
        atomicAdd(d_out, ce * (1.f / 128.f));
        int r = bi * S128 + i;
        d_out[1 + r] = (float)am;
        d_out[1 + 65536 + r] = (float)am;
    }
}

// ---------------------------------------------------------------------------
// Fused rs+re logits for one batch: rows r = i*128+j (16384), cols 0..255
// (col<128 -> rs head col c, col>=128 -> re head col c-128; valid c<122).
// A built on the fly: gelu(u[b,i,k] + v[b,j,k]) — built ONCE for both heads.
__global__ __launch_bounds__(256) void k_logits2(const float* __restrict__ ub, const float* __restrict__ vb,
                                                 const float* __restrict__ rsW, const float* __restrict__ rsb,
                                                 const float* __restrict__ reW, const float* __restrict__ reb,
                                                 float* __restrict__ L)
{
    __shared__ float As[16][68];
    __shared__ float Bs[16][256];
    int il = blockIdx.x >> 1;               // i 0..127
    int j0 = (blockIdx.x & 1) * 64;
    const float* urow = ub + (size_t)il * H800;
    int tid = threadIdx.x;
    int tm = tid & 15, tn = tid >> 4;       // rows tm*4..+3, cols tn*16..+15
    float acc[4][16] = {};
    // B column for this thread (persistent across k0)
    int ct = tid;
    int hc = (ct < 128) ? ct : (ct - 128);
    const float* Wp = (ct < 128) ? rsW : reW;
    bool cok = hc < NR;
    for (int k0 = 0; k0 < 800; k0 += 16) {
        {
            int kk = tid & 15, rrb = tid >> 4;
            float uk = urow[k0 + kk];
            #pragma unroll
            for (int q = 0; q < 4; q++) {
                int rr = rrb + q * 16;
                float xv = uk + vb[(size_t)(j0 + rr) * H800 + k0 + kk];
                As[kk][rr] = gelu_f(xv);
            }
        }
        #pragma unroll
        for (int kk2 = 0; kk2 < 16; kk2++)
            Bs[kk2][ct] = cok ? Wp[(size_t)(k0 + kk2) * NR + hc] : 0.f;
        __syncthreads();
        #pragma unroll
        for (int kk = 0; kk < 16; kk++) {
            float4 a = *(const float4*)&As[kk][tm * 4];
            float av[4] = {a.x, a.y, a.z, a.w};
            float bv[16];
            #pragma unroll
            for (int q = 0; q < 4; q++) {
                float4 bb = *(const float4*)&Bs[kk][tn * 16 + q * 4];
                bv[q * 4 + 0] = bb.x; bv[q * 4 + 1] = bb.y; bv[q * 4 + 2] = bb.z; bv[q * 4 + 3] = bb.w;
            }
            #pragma unroll
            for (int xx = 0; xx < 4; xx++)
                #pragma unroll
                for (int yy = 0; yy < 16; yy++)
                    acc[xx][yy] += av[xx] * bv[yy];
        }
        __syncthreads();
    }
    #pragma unroll
    for (int xx = 0; xx < 4; xx++) {
        int r = il * S128 + j0 + tm * 4 + xx;
        #pragma unroll
        for (int yy = 0; yy < 16; yy++) {
            int cc = tn * 16 + yy;
            int head = cc >> 7, c = cc & 127;
            if (c < NR)
                L[(size_t)r * 256 + cc] = acc[xx][yy] + (head ? reb[c] : rsb[c]);
        }
    }
}

// CE loss + symmetric argmax over one batch's 122-class logits (stride-256 buffer,
// head selects column half). One wave per row.
__global__ __launch_bounds__(256) void k_loss_arg(const float* __restrict__ L, int head,
                                                  const int* __restrict__ labels,
                                                  float* __restrict__ resout, float* __restrict__ lossptr)
{
    __shared__ float wsum[4];
    int wv = threadIdx.x >> 6, l = threadIdx.x & 63;
    int r = blockIdx.x * 4 + wv;          // local row in [0,16384)
    int i = r >> 7, j = r & 127;
    float ce = 0.f;
    if (i != j) {
        const float* row = L + (size_t)r * 256 + head * 128;
        int p = (j << 7) | i;
        const float* prow = L + (size_t)p * 256 + head * 128;
        float x1 = row[l];
        bool v2 = (l < NR - 64);
        float x2 = v2 ? row[l + 64] : -3.4e38f;
        float m = fmaxf(x1, x2);
        #pragma unroll
        for (int s = 32; s; s >>= 1) m = fmaxf(m, __shfl_xor(m, s, 64));
        float se = __expf(x1 - m) + (v2 ? __expf(x2 - m) : 0.f);
        float sl = x1 + (v2 ? x2 : 0.f);
        #pragma unroll
        for (int s = 32; s; s >>= 1) { se += __shfl_xor(se, s, 64); sl += __shfl_xor(sl, s, 64); }
        float lse = m + __logf(se);
        int tgt = labels[r];
        float lt = row[tgt];
        ce = (0.1f / NR) * (NR * lse - sl) + 0.9f * (lse - lt);
        // argmax of row + row^T (first-max tie rule)
        float y1 = x1 + prow[l];
        float y2 = v2 ? (x2 + prow[l + 64]) : -3.4e38f;
        float bv; int bidx;
        if (y2 > y1) { bv = y2; bidx = l + 64; } else { bv = y1; bidx = l; }
        #pragma unroll
        for (int s = 32; s; s >>= 1) {
            float ov = __shfl_xor(bv, s, 64);
            int oi = __shfl_xor(bidx, s, 64);
            if (ov > bv || (ov == bv && oi < bidx)) { bv = ov; bidx = oi; }
        }
        if (l == 0) resout[r] = (float)bidx;
    }
    if (l == 0) wsum[wv] = ce;
    __syncthreads();
    if (threadIdx.x == 0) {
        float s = (wsum[0] + wsum[1] + wsum[2] + wsum[3]) * (1.f / 16256.f);
        atomicAdd(lossptr, s);
    }
}

// ---------------------------------------------------------------------------
extern "C" void kernel_launch(void* const* d_in, const int* in_sizes, int n_in,
                              void* d_out, int out_size, void* d_ws, size_t ws_size,
                              hipStream_t stream)
{
    (void)in_sizes; (void)n_in; (void)out_size; (void)ws_size;
    const float* bert  = (const float*)d_in[0];
    const int*   pids  = (const int*)d_in[1];
    const int*   esrc  = (const int*)d_in[2];
    const int*   edst  = (const int*)d_in[3];
    const int*   slab  = (const int*)d_in[4];
    const int*   elab  = (const int*)d_in[5];
    const float* ptab  = (const float*)d_in[6];
    const float* Wih_f = (const float*)d_in[7];
    const float* Whh_f = (const float*)d_in[8];
    const float* bl_f  = (const float*)d_in[9];
    const float* Wih_b = (const float*)d_in[10];
    const float* Whh_b = (const float*)d_in[11];
    const float* bl_b  = (const float*)d_in[12];
    const float* fcW   = (const float*)d_in[13];
    const float* fcb   = (const float*)d_in[14];
    const float* tW    = (const float*)d_in[15];
    const float* tb    = (const float*)d_in[16];
    const float* gatW  = (const float*)d_in[17];
    const float* asrc  = (const float*)d_in[18];
    const float* adst  = (const float*)d_in[19];
    const float* gbias = (const float*)d_in[20];
    const float* trigW = (const float*)d_in[21];
    const float* trigb = (const float*)d_in[22];
    const float* rsW   = (const float*)d_in[23];
    const float* rsb   = (const float*)d_in[24];
    const float* reW   = (const float*)d_in[25];
    const float* reb   = (const float*)d_in[26];
    float* out = (float*)d_out;

    float* ws = (float*)d_ws;
    size_t off = 0;
    auto alloc = [&](size_t n) { float* p = ws + off; off += (n + 255) & ~(size_t)255; return p; };
    float* x    = alloc(516 * 800);
    float* xWf  = alloc((size_t)516 * 3200);
    float* xWb  = alloc((size_t)516 * 3200);
    float* lstm = alloc((size_t)516 * 1600);
    float* xg   = alloc(516 * 800);
    float* h1   = alloc(512 * 800);
    float* g1   = alloc(512 * 800);
    float* g2   = alloc(512 * 800);
    float* uu   = alloc(512 * 800);
    float* vv   = alloc(512 * 800);
    float* as_  = alloc(4096);
    float* ad_  = alloc(4096);
    float* mb   = alloc(4096);
    float* db   = alloc(4096);
    float* Lbuf = alloc((size_t)16384 * 256);
    int*   flags = (int*)alloc(512);

    hipMemsetAsync(d_out, 0, 4, stream);                 // loss accumulator
    hipMemsetAsync(flags, 0, 2 * NWGD * sizeof(int), stream);

    k_embed<<<(B4 * T129 * H800 + 255) / 256, 256, 0, stream>>>(bert, pids, ptab, x);

    // gate-input precompute: xW = x @ Wih^T + bl  (bias folded here)
    k_gemm<0, 1, 0><<<dim3(9, 50), 256, 0, stream>>>(x, Wih_f, bl_f, nullptr, xWf, 516, 3200, 800);
    k_gemm<0, 1, 0><<<dim3(9, 50), 256, 0, stream>>>(x, Wih_b, bl_b, nullptr, xWb, 516, 3200, 800);

    k_lstm<<<2 * NWGD, 256, 0, stream>>>(xWf, xWb, Whh_f, Whh_b, lstm, flags);

    // xg = x + relu(lstm @ fcW + fcb)
    k_gemm<0, 0, 1><<<dim3(9, 13), 256, 0, stream>>>(lstm, fcW, fcb, x, xg, 516, 800, 1600);

    // GAT layer 1 (input = xg[:,1:,:] view via AMODE/RESMODE 1)
    k_gemm<1, 0, 0><<<dim3(8, 13), 256, 0, stream>>>(xg, gatW, nullptr, nullptr, h1, 512, 800, 800);
    k_gat_coef<<<16, 256, 0, stream>>>(h1, asrc, adst, as_, ad_);
    k_gat_softmax<<<32, 128, 0, stream>>>(esrc, edst, as_, ad_, mb, db);
    k_gat_agg<1><<<32, 512, 0, stream>>>(esrc, edst, as_, ad_, mb, db, h1, gbias, xg, g1);
    // GAT layer 2
    k_gemm<0, 0, 0><<<dim3(8, 13), 256, 0, stream>>>(g1, gatW, nullptr, nullptr, h1, 512, 800, 800);
    k_gat_coef<<<16, 256, 0, stream>>>(h1, asrc, adst, as_, ad_);
    k_gat_softmax<<<32, 128, 0, stream>>>(esrc, edst, as_, ad_, mb, db);
    k_gat_agg<0><<<32, 512, 0, stream>>>(esrc, edst, as_, ad_, mb, db, h1, gbias, g1, g2);

    // table split: u = g2@tW[:800] + tb ; v = g2@tW[800:]
    k_gemm<0, 0, 0><<<dim3(8, 13), 256, 0, stream>>>(g2, tW, tb, nullptr, uu, 512, 800, 800);
    k_gemm<0, 0, 0><<<dim3(8, 13), 256, 0, stream>>>(g2, tW + (size_t)800 * 800, nullptr, nullptr, vv, 512, 800, 800);

    // trig head: diagonal only (l1 + results diag)
    k_trig<<<512, 64, 0, stream>>>(uu, vv, trigW, trigb, slab, out);

    // fused rs+re heads per batch (l2, l3, off-diag results)
    for (int b = 0; b < B4; b++) {
        k_logits2<<<256, 256, 0, stream>>>(uu + (size_t)b * 128 * 800, vv + (size_t)b * 128 * 800,
                                           rsW, rsb, reW, reb, Lbuf);
        k_loss_arg<<<4096, 256, 0, stream>>>(Lbuf, 0, slab + (size_t)b * 16384, out + 1 + (size_t)b * 16384, out);
        k_loss_arg<<<4096, 256, 0, stream>>>(Lbuf, 1, elab + (size_t)b * 16384, out + 1 + 65536 + (size_t)b * 16384, out);
    }
}

// Round 7
// 3505.111 us; speedup vs baseline: 2.0018x; 1.0644x over previous
//
#include <hip/hip_runtime.h>
#include <hip/hip_bf16.h>

// Problem dims
#define B4 4
#define S128 128
#define T129 129
#define H800 800
#define G3200 3200
#define E256 256
#define NE 66
#define NR 122
#define DPW 8      // LSTM dims per WG
#define NWGD 100   // LSTM WGs per direction

typedef float f32x4 __attribute__((ext_vector_type(4)));

// ---------------------------------------------------------------------------
// gelu (jax approximate=True): 0.5*x*(1+tanh(sqrt(2/pi)*(x+0.044715 x^3)))
__device__ __forceinline__ float gelu_f(float x) {
    float t = 0.7978845608028654f * (x + 0.044715f * x * x * x);
    float e = __expf(2.f * t);           // overflow -> inf -> th=1 ; underflow -> 0 -> th=-1
    float th = 1.f - 2.f / (e + 1.f);
    return 0.5f * x * (1.f + th);
}

// ---------------------------------------------------------------------------
// K_embed: x[b,t,0:768]=bert, x[b,t,768:800]=pos_table[pos_ids[b,t-1]] (0 for t=0)
__global__ void k_embed(const float* __restrict__ bert, const int* __restrict__ pos_ids,
                        const float* __restrict__ ptab, float* __restrict__ x)
{
    int idx = blockIdx.x * 256 + threadIdx.x;
    if (idx >= B4 * T129 * H800) return;
    int c = idx % H800;
    int bt = idx / H800;
    int t = bt % T129, b = bt / T129;
    float v;
    if (c < 768) v = bert[(size_t)bt * 768 + c];
    else         v = (t == 0) ? 0.f : ptab[pos_ids[b * S128 + t - 1] * 32 + (c - 768)];
    x[idx] = v;
}

// ---------------------------------------------------------------------------
// Generic fp32 tiled GEMM. C[M,N] = A(M,K) * B  (+bias) with optional epilogue.
// AMODE: 0 direct row, 1 xg-view (row -> row + row/128 + 1)  [x[:,1:,:] view]
// BTRANS: 0: B is [K,N]; 1: B is [N,K] (A @ B^T)
// EPI: 0: C = acc (+bias); 1: C = res + relu(acc+bias)
template<int AMODE, int BTRANS, int EPI>
__global__ __launch_bounds__(256) void k_gemm(const float* __restrict__ A, const float* __restrict__ Bm,
                                              const float* __restrict__ bias, const float* __restrict__ res,
                                              float* __restrict__ C, int M, int N, int K)
{
    __shared__ float As[16][68];
    __shared__ float Bs[16][68];
    int m0 = blockIdx.x * 64, n0 = blockIdx.y * 64;
    int tid = threadIdx.x;
    int tm = tid & 15, tn = tid >> 4;
    float acc[4][4] = {};
    for (int k0 = 0; k0 < K; k0 += 16) {
        // A tile: As[kk][mm]
        {
            int kk = tid & 15, mmb = tid >> 4;
            #pragma unroll
            for (int q = 0; q < 4; q++) {
                int mm = mmb + q * 16;
                int m = m0 + mm;
                float v = 0.f;
                if (m < M) {
                    int row = (AMODE == 1) ? (m + (m >> 7) + 1) : m;
                    v = A[(size_t)row * K + k0 + kk];
                }
                As[kk][mm] = v;
            }
        }
        // B tile: Bs[kk][nn]
        if (BTRANS == 0) {
            int nn = (tid & 15) * 4, kk2 = tid >> 4;
            int n = n0 + nn;
            float t0, t1, t2, t3;
            if (n + 3 < N) {
                const float4 bv = *(const float4*)&Bm[(size_t)(k0 + kk2) * N + n];
                t0 = bv.x; t1 = bv.y; t2 = bv.z; t3 = bv.w;
            } else {
                t0 = (n + 0 < N) ? Bm[(size_t)(k0 + kk2) * N + n + 0] : 0.f;
                t1 = (n + 1 < N) ? Bm[(size_t)(k0 + kk2) * N + n + 1] : 0.f;
                t2 = (n + 2 < N) ? Bm[(size_t)(k0 + kk2) * N + n + 2] : 0.f;
                t3 = (n + 3 < N) ? Bm[(size_t)(k0 + kk2) * N + n + 3] : 0.f;
            }
            Bs[kk2][nn + 0] = t0; Bs[kk2][nn + 1] = t1; Bs[kk2][nn + 2] = t2; Bs[kk2][nn + 3] = t3;
        } else {
            int kk = tid & 15, nnb = tid >> 4;
            #pragma unroll
            for (int q = 0; q < 4; q++) {
                int nn = nnb + q * 16;
                int n = n0 + nn;
                Bs[kk][nn] = (n < N) ? Bm[(size_t)n * K + k0 + kk] : 0.f;
            }
        }
        __syncthreads();
        #pragma unroll
        for (int kk = 0; kk < 16; kk++) {
            float4 a = *(const float4*)&As[kk][tm * 4];
            float4 bb = *(const float4*)&Bs[kk][tn * 4];
            float av[4] = {a.x, a.y, a.z, a.w};
            float bv[4] = {bb.x, bb.y, bb.z, bb.w};
            #pragma unroll
            for (int xx = 0; xx < 4; xx++)
                #pragma unroll
                for (int yy = 0; yy < 4; yy++)
                    acc[xx][yy] += av[xx] * bv[yy];
        }
        __syncthreads();
    }
    #pragma unroll
    for (int xx = 0; xx < 4; xx++) {
        int m = m0 + tm * 4 + xx;
        if (m >= M) continue;
        #pragma unroll
        for (int yy = 0; yy < 4; yy++) {
            int n = n0 + tn * 4 + yy;
            if (n >= N) continue;
            float v = acc[xx][yy];
            if (bias) v += bias[n];
            if (EPI == 1) v = res[(size_t)m * N + n] + fmaxf(v, 0.f);
            C[(size_t)m * N + n] = v;
        }
    }
}

// ---------------------------------------------------------------------------
// Persistent BiLSTM v7 = v6 minus the redundant post-poll barrier.
// Grid: 200 WGs x 256 thr; WGs [0,100) fwd, [100,200) bwd. 8 h-dims/WG.
// Whh slice in REGISTERS. h exchange through lstm buffer (fresh region per t)
// via dwordx4 sc0 sc1; release = wave0 s_waitcnt vmcnt(0) -> relaxed flag;
// acquire = ALL-wave hot poll (own flag in poll set => own wave0 done =>
// no barrier needed before overwriting hb with the loads).
__global__ __launch_bounds__(256) void k_lstm(const float* __restrict__ xWf, const float* __restrict__ xWb,
                                              const float* __restrict__ Whhf, const float* __restrict__ Whhb,
                                              float* __restrict__ lstm, int* __restrict__ flags)
{
    __shared__ float hb[4][800];        // h_{t-1}, 4 batches
    __shared__ float gsum[8][32][4];    // [k-slice][gate*8+dim][batch]
    int wg = blockIdx.x;
    int dir = wg >= NWGD ? 1 : 0;
    int wgd = dir ? wg - NWGD : wg;
    const float* Whh = dir ? Whhb : Whhf;
    const float* xW  = dir ? xWb  : xWf;
    int tid = threadIdx.x;
    int r = tid & 31;                   // row: gate g = r>>3, dim d = r&7
    int s = tid >> 5;                   // k-slice 0..7 (100 k each)
    int g = r >> 3, d = r & 7;
    int grow = g * 800 + wgd * DPW + d; // row in [0,3200)
    int lane = tid & 63;
    int wv = tid >> 6;

    // one-time: weight slice into registers
    float wreg[100];
    {
        const float* wp = Whh + (size_t)grow * 800 + s * 100;
        #pragma unroll
        for (int q = 0; q < 100; q++) wreg[q] = wp[q];
    }
    for (int i = tid; i < 3200; i += 256) (&hb[0][0])[i] = 0.f;
    __syncthreads();

    float cst = 0.f;                    // cell state (threads tid<32)
    int fbase = dir * NWGD;

    for (int step = 0; step < 129; step++) {
        int t = dir ? (128 - step) : step;
        // prefetch gate inputs (x@Wih^T + b); read-only, safe before any wait
        float xq0 = 0.f, xq1 = 0.f, xq2 = 0.f, xq3 = 0.f;
        if (s == 0) {
            const float* xp = xW + (size_t)t * G3200 + grow;
            xq0 = xp[0];
            xq1 = xp[(size_t)T129 * G3200];
            xq2 = xp[2 * (size_t)T129 * G3200];
            xq3 = xp[3 * (size_t)T129 * G3200];
        }
        if (step > 0) {
            // hot poll by ALL waves (each wave verifies all 100 flags of this dir)
            {
                bool mine = (lane < 25);
                int base = fbase + lane * 4;
                long long iters = 0;
                for (;;) {
                    int mn = step;
                    if (mine) {
                        int f0 = __hip_atomic_load(&flags[base + 0], __ATOMIC_RELAXED, __HIP_MEMORY_SCOPE_AGENT);
                        int f1 = __hip_atomic_load(&flags[base + 1], __ATOMIC_RELAXED, __HIP_MEMORY_SCOPE_AGENT);
                        int f2 = __hip_atomic_load(&flags[base + 2], __ATOMIC_RELAXED, __HIP_MEMORY_SCOPE_AGENT);
                        int f3 = __hip_atomic_load(&flags[base + 3], __ATOMIC_RELAXED, __HIP_MEMORY_SCOPE_AGENT);
                        mn = min(min(f0, f1), min(f2, f3));
                    }
                    if (__all(mn >= step)) break;
                    if (++iters > 50000000LL) break;    // safety valve vs deadlock
                }
            }
            // no barrier needed: own flag >= step implies own wave0 finished
            // reading gsum and publishing h; hb overwrite is safe.
            int tprev = dir ? (t + 1) : (t - 1);
            // device-coherent vectorized load of h_{t-1}: 200 thr x 4 float4
            if (tid < 200) {
                const f32x4* p0 = (const f32x4*)(lstm + (size_t)((0 * T129 + tprev) * 1600) + dir * 800) + tid;
                const f32x4* p1 = (const f32x4*)(lstm + (size_t)((1 * T129 + tprev) * 1600) + dir * 800) + tid;
                const f32x4* p2 = (const f32x4*)(lstm + (size_t)((2 * T129 + tprev) * 1600) + dir * 800) + tid;
                const f32x4* p3 = (const f32x4*)(lstm + (size_t)((3 * T129 + tprev) * 1600) + dir * 800) + tid;
                f32x4 v0, v1, v2, v3;
                asm volatile(
                    "global_load_dwordx4 %0, %4, off sc0 sc1\n\t"
                    "global_load_dwordx4 %1, %5, off sc0 sc1\n\t"
                    "global_load_dwordx4 %2, %6, off sc0 sc1\n\t"
                    "global_load_dwordx4 %3, %7, off sc0 sc1\n\t"
                    "s_waitcnt vmcnt(0)"
                    : "=&v"(v0), "=&v"(v1), "=&v"(v2), "=&v"(v3)
                    : "v"(p0), "v"(p1), "v"(p2), "v"(p3)
                    : "memory");
                f32x4* dst = (f32x4*)&hb[0][0];
                dst[tid] = v0; dst[tid + 200] = v1; dst[tid + 400] = v2; dst[tid + 600] = v3;
            }
            __syncthreads();
        }
        // dot: own 100-k slice x 4 batches, weights in registers, h from LDS
        float a0, a1, a2, a3;
        if (s == 0) { a0 = xq0; a1 = xq1; a2 = xq2; a3 = xq3; }
        else        { a0 = a1 = a2 = a3 = 0.f; }
        {
            int k0 = s * 100;
            #pragma unroll
            for (int q = 0; q < 100; q += 4) {
                float4 h0 = *(const float4*)&hb[0][k0 + q];
                float4 h1 = *(const float4*)&hb[1][k0 + q];
                float4 h2 = *(const float4*)&hb[2][k0 + q];
                float4 h3 = *(const float4*)&hb[3][k0 + q];
                float w0 = wreg[q], w1 = wreg[q + 1], w2 = wreg[q + 2], w3 = wreg[q + 3];
                a0 += w0 * h0.x + w1 * h0.y + w2 * h0.z + w3 * h0.w;
                a1 += w0 * h1.x + w1 * h1.y + w2 * h1.z + w3 * h1.w;
                a2 += w0 * h2.x + w1 * h2.y + w2 * h2.z + w3 * h2.w;
                a3 += w0 * h3.x + w1 * h3.y + w2 * h3.z + w3 * h3.w;
            }
        }
        *(float4*)&gsum[s][r][0] = make_float4(a0, a1, a2, a3);
        __syncthreads();
        // wave 0: reduce, activate, publish h (others fall through to next poll)
        float hv = 0.f;
        if (tid < 32) {
            int d2 = tid & 7, b2 = tid >> 3;
            float gi = 0.f, gf = 0.f, gg = 0.f, go = 0.f;
            #pragma unroll
            for (int ss = 0; ss < 8; ss++) {
                gi += gsum[ss][d2][b2];
                gf += gsum[ss][8 + d2][b2];
                gg += gsum[ss][16 + d2][b2];
                go += gsum[ss][24 + d2][b2];
            }
            float si = 1.f / (1.f + __expf(-gi));
            float sf = 1.f / (1.f + __expf(-gf));
            float so = 1.f / (1.f + __expf(-go));
            cst = sf * cst + si * tanhf(gg);
            hv = so * tanhf(cst);       // lane tid holds h for (b=tid>>3, d=tid&7)
        }
        if (wv == 0) {
            // gather 4 consecutive hv's into lanes 0..7 and store as dwordx4
            int src = (lane & 7) * 4;
            f32x4 o;
            o.x = __shfl(hv, src + 0, 64);
            o.y = __shfl(hv, src + 1, 64);
            o.z = __shfl(hv, src + 2, 64);
            o.w = __shfl(hv, src + 3, 64);
            if (lane < 8) {
                int bb = lane >> 1, half = lane & 1;
                float* ap = lstm + (size_t)((bb * T129 + t) * 1600) + dir * 800 + wgd * DPW + half * 4;
                asm volatile("global_store_dwordx4 %0, %1, off sc0 sc1"
                             :: "v"((f32x4*)ap), "v"(o) : "memory");
            }
            // release: drain wave-0's data stores before flag escapes
            asm volatile("s_waitcnt vmcnt(0)" ::: "memory");
            if (tid == 0 && step < 128)
                __hip_atomic_store(&flags[fbase + wgd], step + 1,
                                   __ATOMIC_RELAXED, __HIP_MEMORY_SCOPE_AGENT);
        }
    }
}

// ---------------------------------------------------------------------------
// Fused GAT layer (coef + softmax + aggregate), one block per (b,h).
// Everything for a (b,h) pair is block-local: 512 thr = 128 nodes x 4 chunks.
// RESMODE 1: res is xg-view (row -> n + b + 1).
template<int RESMODE>
__global__ __launch_bounds__(512) void k_gat_fused(const int* __restrict__ esrc, const int* __restrict__ edst,
                                                   const float* __restrict__ h1,
                                                   const float* __restrict__ asrc, const float* __restrict__ adst,
                                                   const float* __restrict__ gbias,
                                                   const float* __restrict__ res, float* __restrict__ out)
{
    __shared__ int se[384], de[384];
    __shared__ float asl[128], adl[128], ml[128], dl_[128];
    int bh = blockIdx.x;
    int b = bh >> 3, h = bh & 7;
    int t = threadIdx.x;
    if (t < 384) {
        if (t < E256) { se[t] = esrc[b * E256 + t]; de[t] = edst[b * E256 + t]; }
        else          { se[t] = t - E256;           de[t] = t - E256; }
    }
    int node = t >> 2, ch = t & 3;
    int dd0 = ch * 25;
    {   // attention coefficients: 4 lanes per node, 25-d partials, shuffle-reduce
        const float* hp = h1 + (size_t)(b * S128 + node) * H800 + h * 100 + dd0;
        const float* ap = asrc + h * 100 + dd0;
        const float* dp = adst + h * 100 + dd0;
        float s1 = 0.f, s2 = 0.f;
        #pragma unroll
        for (int q = 0; q < 25; q++) { float hv = hp[q]; s1 += hv * ap[q]; s2 += hv * dp[q]; }
        s1 += __shfl_xor(s1, 1, 64); s1 += __shfl_xor(s1, 2, 64);
        s2 += __shfl_xor(s2, 1, 64); s2 += __shfl_xor(s2, 2, 64);
        if (ch == 0) { asl[node] = s1; adl[node] = s2; }
    }
    __syncthreads();
    if (t < 128) {   // segment max + denom per dst node
        float myad = adl[t];
        float m = -3.4e38f;
        for (int e = 0; e < 384; e++)
            if (de[e] == t) {
                float sc = asl[se[e]] + myad;
                sc = (sc > 0.f) ? sc : 0.2f * sc;
                m = fmaxf(m, sc);
            }
        float den = 0.f;
        for (int e = 0; e < 384; e++)
            if (de[e] == t) {
                float sc = asl[se[e]] + myad;
                sc = (sc > 0.f) ? sc : 0.2f * sc;
                den += __expf(sc - m);
            }
        ml[t] = m; dl_[t] = den;
    }
    __syncthreads();
    // aggregate
    float acc[25] = {};
    float myad = adl[node], mym = ml[node];
    for (int e = 0; e < 384; e++) {
        if (de[e] == node) {
            int s = se[e];
            float sc = asl[s] + myad;
            sc = (sc > 0.f) ? sc : 0.2f * sc;
            float w = __expf(sc - mym);
            const float* hp = h1 + (size_t)(b * S128 + s) * H800 + h * 100 + dd0;
            #pragma unroll
            for (int q = 0; q < 25; q++) acc[q] += w * hp[q];
        }
    }
    float inv = 1.f / dl_[node];
    int n = b * S128 + node;
    size_t rrow = (RESMODE == 1) ? (size_t)(n + b + 1) * H800 : (size_t)n * H800;
    #pragma unroll
    for (int q = 0; q < 25; q++) {
        int col = h * 100 + dd0 + q;
        float v = acc[q] * inv + gbias[col];
        out[(size_t)n * H800 + col] = res[rrow + col] + fmaxf(v, 0.f);
    }
}

// ---------------------------------------------------------------------------
// Trig head on the diagonal only: 512 rows. One wave per (b,i).
__global__ __launch_bounds__(64) void k_trig(const float* __restrict__ u, const float* __restrict__ v,
                                             const float* __restrict__ W, const float* __restrict__ bias,
                                             const int* __restrict__ labels, float* __restrict__ d_out)
{
    __shared__ float s[800];
    __shared__ float lg[66];
    int bi = blockIdx.x;          // b*128+i
    int i = bi & 127;
    int l = threadIdx.x;
    const float* ur = u + (size_t)bi * H800;
    const float* vr = v + (size_t)bi * H800;
    for (int k = l; k < 800; k += 64) s[k] = gelu_f(ur[k] + vr[k]);
    __syncthreads();
    float a0 = 0.f, a1 = 0.f;
    bool has2 = (l < 2);
    for (int k = 0; k < 800; k++) {
        float sv = s[k];
        a0 += sv * W[k * NE + l];
        if (has2) a1 += sv * W[k * NE + 64 + l];
    }
    lg[l] = a0 + bias[l];
    if (has2) lg[64 + l] = a1 + bias[64 + l];
    __syncthreads();
    if (l == 0) {
        float m = lg[0];
        for (int c = 1; c < NE; c++) m = fmaxf(m, lg[c]);
        float se = 0.f, sl = 0.f, bv = lg[0];
        int am = 0;
        for (int c = 0; c < NE; c++) {
            se += __expf(lg[c] - m);
            sl += lg[c];
            if (lg[c] > bv) { bv = lg[c]; am = c; }
        }
        float lse = m + __logf(se);
        int tgt = labels[(size_t)bi * S128 + i];       // start_labels[b,i,i]
        float ce = (0.1f / NE) * (NE * lse - sl) + 0.9f * (lse - lg[tgt]);
        atomicAdd(d_out, ce * (1.f / 128.f));
        int r = bi * S128 + i;
        d_out[1 + r] = (float)am;
        d_out[1 + 65536 + r] = (float)am;
    }
}

// ---------------------------------------------------------------------------
// Fused rs+re logits for one batch: rows r = i*128+j (16384), cols 0..255
// (col<128 -> rs col c, col>=128 -> re col c-128; valid c<122).
// A built on the fly: gelu(u[b,i,k] + v[b,j,k]) — ONCE for both heads.
// v2: acc[8][8] thread tile (tm=tid&7 x8 rows, tn=tid>>3 x8 cols):
// 4 ds_read_b128 per 64 FMAs (was 5) + vectorized epilogue stores.
__global__ __launch_bounds__(256) void k_logits2(const float* __restrict__ ub, const float* __restrict__ vb,
                                                 const float* __restrict__ rsW, const float* __restrict__ rsb,
                                                 const float* __restrict__ reW, const float* __restrict__ reb,
                                                 float* __restrict__ L)
{
    __shared__ float As[16][68];
    __shared__ float Bs[16][256];
    int il = blockIdx.x >> 1;               // i 0..127
    int j0 = (blockIdx.x & 1) * 64;
    const float* urow = ub + (size_t)il * H800;
    int tid = threadIdx.x;
    int tm = tid & 7, tn = tid >> 3;        // rows tm*8..+7, cols tn*8..+7
    float acc[8][8] = {};
    // B column for this thread's staging (one col per thread, persistent)
    int ct = tid;
    int hc = (ct < 128) ? ct : (ct - 128);
    const float* Wp = (ct < 128) ? rsW : reW;
    bool cok = hc < NR;
    for (int k0 = 0; k0 < 800; k0 += 16) {
        {
            int kk = tid & 15, rrb = tid >> 4;
            float uk = urow[k0 + kk];
            #pragma unroll
            for (int q = 0; q < 4; q++) {
                int rr = rrb + q * 16;
                float xv = uk + vb[(size_t)(j0 + rr) * H800 + k0 + kk];
                As[kk][rr] = gelu_f(xv);
            }
        }
        #pragma unroll
        for (int kk2 = 0; kk2 < 16; kk2++)
            Bs[kk2][ct] = cok ? Wp[(size_t)(k0 + kk2) * NR + hc] : 0.f;
        __syncthreads();
        #pragma unroll
        for (int kk = 0; kk < 16; kk++) {
            float4 a0 = *(const float4*)&As[kk][tm * 8];
            float4 a1 = *(const float4*)&As[kk][tm * 8 + 4];
            float4 b0 = *(const float4*)&Bs[kk][tn * 8];
            float4 b1 = *(const float4*)&Bs[kk][tn * 8 + 4];
            float av[8] = {a0.x, a0.y, a0.z, a0.w, a1.x, a1.y, a1.z, a1.w};
            float bv[8] = {b0.x, b0.y, b0.z, b0.w, b1.x, b1.y, b1.z, b1.w};
            #pragma unroll
            for (int xx = 0; xx < 8; xx++)
                #pragma unroll
                for (int yy = 0; yy < 8; yy++)
                    acc[xx][yy] += av[xx] * bv[yy];
        }
        __syncthreads();
    }
    // epilogue: this thread's 8 cols never straddle heads (8 | 128)
    int head = tn >> 4;                      // tn*8 >= 128 ?
    const float* bp = head ? reb : rsb;
    #pragma unroll
    for (int xx = 0; xx < 8; xx++) {
        int r = il * S128 + j0 + tm * 8 + xx;
        float* Lr = L + (size_t)r * 256 + tn * 8;
        #pragma unroll
        for (int hf = 0; hf < 2; hf++) {
            int c = (tn * 8 + hf * 4) & 127;
            if (c + 3 < NR) {
                float4 o = make_float4(acc[xx][hf*4+0] + bp[c+0], acc[xx][hf*4+1] + bp[c+1],
                                       acc[xx][hf*4+2] + bp[c+2], acc[xx][hf*4+3] + bp[c+3]);
                *(float4*)(Lr + hf * 4) = o;
            } else {
                #pragma unroll
                for (int q = 0; q < 4; q++)
                    if (c + q < NR) Lr[hf * 4 + q] = acc[xx][hf*4+q] + bp[c+q];
            }
        }
    }
}

// CE loss + symmetric argmax for BOTH heads of one batch (stride-256 buffer).
// One wave per row; row read once, both softmax/argmax computed.
__global__ __launch_bounds__(256) void k_loss2(const float* __restrict__ L,
                                               const int* __restrict__ lab0, const int* __restrict__ lab1,
                                               float* __restrict__ res0, float* __restrict__ res1,
                                               float* __restrict__ lossptr)
{
    __shared__ float wsum[4];
    int wv = threadIdx.x >> 6, l = threadIdx.x & 63;
    int r = blockIdx.x * 4 + wv;          // local row in [0,16384)
    int i = r >> 7, j = r & 127;
    float ces = 0.f;
    if (i != j) {
        const float* row  = L + (size_t)r * 256;
        const float* prow = L + (size_t)((j << 7) | i) * 256;
        bool v2 = (l < NR - 64);
        #pragma unroll
        for (int hd = 0; hd < 2; hd++) {
            const float* rw = row + hd * 128;
            const float* pw = prow + hd * 128;
            float x1 = rw[l];
            float x2 = v2 ? rw[l + 64] : -3.4e38f;
            float m = fmaxf(x1, x2);
            #pragma unroll
            for (int s = 32; s; s >>= 1) m = fmaxf(m, __shfl_xor(m, s, 64));
            float se = __expf(x1 - m) + (v2 ? __expf(x2 - m) : 0.f);
            float sl = x1 + (v2 ? x2 : 0.f);
            #pragma unroll
            for (int s = 32; s; s >>= 1) { se += __shfl_xor(se, s, 64); sl += __shfl_xor(sl, s, 64); }
            float lse = m + __logf(se);
            int tgt = (hd ? lab1 : lab0)[r];
            float lt = rw[tgt];
            ces += (0.1f / NR) * (NR * lse - sl) + 0.9f * (lse - lt);
            // argmax of row + row^T (first-max tie rule)
            float y1 = x1 + pw[l];
            float y2 = v2 ? (x2 + pw[l + 64]) : -3.4e38f;
            float bv; int bidx;
            if (y2 > y1) { bv = y2; bidx = l + 64; } else { bv = y1; bidx = l; }
            #pragma unroll
            for (int s = 32; s; s >>= 1) {
                float ov = __shfl_xor(bv, s, 64);
                int oi = __shfl_xor(bidx, s, 64);
                if (ov > bv || (ov == bv && oi < bidx)) { bv = ov; bidx = oi; }
            }
            if (l == 0) (hd ? res1 : res0)[r] = (float)bidx;
        }
    }
    if (l == 0) wsum[wv] = ces;
    __syncthreads();
    if (threadIdx.x == 0) {
        float s = (wsum[0] + wsum[1] + wsum[2] + wsum[3]) * (1.f / 16256.f);
        atomicAdd(lossptr, s);
    }
}

// ---------------------------------------------------------------------------
extern "C" void kernel_launch(void* const* d_in, const int* in_sizes, int n_in,
                              void* d_out, int out_size, void* d_ws, size_t ws_size,
                              hipStream_t stream)
{
    (void)in_sizes; (void)n_in; (void)out_size; (void)ws_size;
    const float* bert  = (const float*)d_in[0];
    const int*   pids  = (const int*)d_in[1];
    const int*   esrc  = (const int*)d_in[2];
    const int*   edst  = (const int*)d_in[3];
    const int*   slab  = (const int*)d_in[4];
    const int*   elab  = (const int*)d_in[5];
    const float* ptab  = (const float*)d_in[6];
    const float* Wih_f = (const float*)d_in[7];
    const float* Whh_f = (const float*)d_in[8];
    const float* bl_f  = (const float*)d_in[9];
    const float* Wih_b = (const float*)d_in[10];
    const float* Whh_b = (const float*)d_in[11];
    const float* bl_b  = (const float*)d_in[12];
    const float* fcW   = (const float*)d_in[13];
    const float* fcb   = (const float*)d_in[14];
    const float* tW    = (const float*)d_in[15];
    const float* tb    = (const float*)d_in[16];
    const float* gatW  = (const float*)d_in[17];
    const float* asrc  = (const float*)d_in[18];
    const float* adst  = (const float*)d_in[19];
    const float* gbias = (const float*)d_in[20];
    const float* trigW = (const float*)d_in[21];
    const float* trigb = (const float*)d_in[22];
    const float* rsW   = (const float*)d_in[23];
    const float* rsb   = (const float*)d_in[24];
    const float* reW   = (const float*)d_in[25];
    const float* reb   = (const float*)d_in[26];
    float* out = (float*)d_out;

    float* ws = (float*)d_ws;
    size_t off = 0;
    auto alloc = [&](size_t n) { float* p = ws + off; off += (n + 255) & ~(size_t)255; return p; };
    float* x    = alloc(516 * 800);
    float* xWf  = alloc((size_t)516 * 3200);
    float* xWb  = alloc((size_t)516 * 3200);
    float* lstm = alloc((size_t)516 * 1600);
    float* xg   = alloc(516 * 800);
    float* h1   = alloc(512 * 800);
    float* g1   = alloc(512 * 800);
    float* g2   = alloc(512 * 800);
    float* uu   = alloc(512 * 800);
    float* vv   = alloc(512 * 800);
    float* Lbuf = alloc((size_t)16384 * 256);
    int*   flags = (int*)alloc(512);

    hipMemsetAsync(d_out, 0, 4, stream);                 // loss accumulator
    hipMemsetAsync(flags, 0, 2 * NWGD * sizeof(int), stream);

    k_embed<<<(B4 * T129 * H800 + 255) / 256, 256, 0, stream>>>(bert, pids, ptab, x);

    // gate-input precompute: xW = x @ Wih^T + bl  (bias folded here)
    k_gemm<0, 1, 0><<<dim3(9, 50), 256, 0, stream>>>(x, Wih_f, bl_f, nullptr, xWf, 516, 3200, 800);
    k_gemm<0, 1, 0><<<dim3(9, 50), 256, 0, stream>>>(x, Wih_b, bl_b, nullptr, xWb, 516, 3200, 800);

    k_lstm<<<2 * NWGD, 256, 0, stream>>>(xWf, xWb, Whh_f, Whh_b, lstm, flags);

    // xg = x + relu(lstm @ fcW + fcb)
    k_gemm<0, 0, 1><<<dim3(9, 13), 256, 0, stream>>>(lstm, fcW, fcb, x, xg, 516, 800, 1600);

    // GAT layer 1 (input = xg[:,1:,:] view via AMODE/RESMODE 1)
    k_gemm<1, 0, 0><<<dim3(8, 13), 256, 0, stream>>>(xg, gatW, nullptr, nullptr, h1, 512, 800, 800);
    k_gat_fused<1><<<32, 512, 0, stream>>>(esrc, edst, h1, asrc, adst, gbias, xg, g1);
    // GAT layer 2
    k_gemm<0, 0, 0><<<dim3(8, 13), 256, 0, stream>>>(g1, gatW, nullptr, nullptr, h1, 512, 800, 800);
    k_gat_fused<0><<<32, 512, 0, stream>>>(esrc, edst, h1, asrc, adst, gbias, g1, g2);

    // table split: u = g2@tW[:800] + tb ; v = g2@tW[800:]
    k_gemm<0, 0, 0><<<dim3(8, 13), 256, 0, stream>>>(g2, tW, tb, nullptr, uu, 512, 800, 800);
    k_gemm<0, 0, 0><<<dim3(8, 13), 256, 0, stream>>>(g2, tW + (size_t)800 * 800, nullptr, nullptr, vv, 512, 800, 800);

    // trig head: diagonal only (l1 + results diag)
    k_trig<<<512, 64, 0, stream>>>(uu, vv, trigW, trigb, slab, out);

    // fused rs+re heads per batch (l2, l3, off-diag results)
    for (int b = 0; b < B4; b++) {
        k_logits2<<<256, 256, 0, stream>>>(uu + (size_t)b * 128 * 800, vv + (size_t)b * 128 * 800,
                                           rsW, rsb, reW, reb, Lbuf);
        k_loss2<<<4096, 256, 0, stream>>>(Lbuf, slab + (size_t)b * 16384, elab + (size_t)b * 16384,
                                          out + 1 + (size_t)b * 16384, out + 1 + 65536 + (size_t)b * 16384, out);
    }
}

// Round 8
// 2751.552 us; speedup vs baseline: 2.5500x; 1.2739x over previous
//
#include <hip/hip_runtime.h>
#include <hip/hip_bf16.h>

// Problem dims
#define B4 4
#define S128 128
#define T129 129
#define H800 800
#define E256 256
#define NE 66
#define NR 122
#define DPW 8      // LSTM dims per WG
#define NWGD 100   // LSTM WGs per direction

typedef float f32x4 __attribute__((ext_vector_type(4)));

// staggered LDS index for h: phys = k + (k>>5)*4  (breaks 32-float bank aliasing)
#define HB_PHYS(k) ((k) + (((k) >> 5) << 2))
#define HB_ROW 900

// ---------------------------------------------------------------------------
__device__ __forceinline__ float gelu_f(float x) {
    float t = 0.7978845608028654f * (x + 0.044715f * x * x * x);
    float e = __expf(2.f * t);
    float th = 1.f - 2.f / (e + 1.f);
    return 0.5f * x * (1.f + th);
}

// ---------------------------------------------------------------------------
__global__ void k_embed(const float* __restrict__ bert, const int* __restrict__ pos_ids,
                        const float* __restrict__ ptab, float* __restrict__ x)
{
    int idx = blockIdx.x * 256 + threadIdx.x;
    if (idx >= B4 * T129 * H800) return;
    int c = idx % H800;
    int bt = idx / H800;
    int t = bt % T129, b = bt / T129;
    float v;
    if (c < 768) v = bert[(size_t)bt * 768 + c];
    else         v = (t == 0) ? 0.f : ptab[pos_ids[b * S128 + t - 1] * 32 + (c - 768)];
    x[idx] = v;
}

// ---------------------------------------------------------------------------
// Generic fp32 tiled GEMM (as r7). AMODE 1: xg-view row. BTRANS 1: A@B^T.
// EPI 1: C = res + relu(acc+bias).
template<int AMODE, int BTRANS, int EPI>
__global__ __launch_bounds__(256) void k_gemm(const float* __restrict__ A, const float* __restrict__ Bm,
                                              const float* __restrict__ bias, const float* __restrict__ res,
                                              float* __restrict__ C, int M, int N, int K)
{
    __shared__ float As[16][68];
    __shared__ float Bs[16][68];
    int m0 = blockIdx.x * 64, n0 = blockIdx.y * 64;
    int tid = threadIdx.x;
    int tm = tid & 15, tn = tid >> 4;
    float acc[4][4] = {};
    for (int k0 = 0; k0 < K; k0 += 16) {
        {
            int kk = tid & 15, mmb = tid >> 4;
            #pragma unroll
            for (int q = 0; q < 4; q++) {
                int mm = mmb + q * 16;
                int m = m0 + mm;
                float v = 0.f;
                if (m < M) {
                    int row = (AMODE == 1) ? (m + (m >> 7) + 1) : m;
                    v = A[(size_t)row * K + k0 + kk];
                }
                As[kk][mm] = v;
            }
        }
        if (BTRANS == 0) {
            int nn = (tid & 15) * 4, kk2 = tid >> 4;
            int n = n0 + nn;
            float t0, t1, t2, t3;
            if (n + 3 < N) {
                const float4 bv = *(const float4*)&Bm[(size_t)(k0 + kk2) * N + n];
                t0 = bv.x; t1 = bv.y; t2 = bv.z; t3 = bv.w;
            } else {
                t0 = (n + 0 < N) ? Bm[(size_t)(k0 + kk2) * N + n + 0] : 0.f;
                t1 = (n + 1 < N) ? Bm[(size_t)(k0 + kk2) * N + n + 1] : 0.f;
                t2 = (n + 2 < N) ? Bm[(size_t)(k0 + kk2) * N + n + 2] : 0.f;
                t3 = (n + 3 < N) ? Bm[(size_t)(k0 + kk2) * N + n + 3] : 0.f;
            }
            Bs[kk2][nn + 0] = t0; Bs[kk2][nn + 1] = t1; Bs[kk2][nn + 2] = t2; Bs[kk2][nn + 3] = t3;
        } else {
            int kk = tid & 15, nnb = tid >> 4;
            #pragma unroll
            for (int q = 0; q < 4; q++) {
                int nn = nnb + q * 16;
                int n = n0 + nn;
                Bs[kk][nn] = (n < N) ? Bm[(size_t)n * K + k0 + kk] : 0.f;
            }
        }
        __syncthreads();
        #pragma unroll
        for (int kk = 0; kk < 16; kk++) {
            float4 a = *(const float4*)&As[kk][tm * 4];
            float4 bb = *(const float4*)&Bs[kk][tn * 4];
            float av[4] = {a.x, a.y, a.z, a.w};
            float bv[4] = {bb.x, bb.y, bb.z, bb.w};
            #pragma unroll
            for (int xx = 0; xx < 4; xx++)
                #pragma unroll
                for (int yy = 0; yy < 4; yy++)
                    acc[xx][yy] += av[xx] * bv[yy];
        }
        __syncthreads();
    }
    #pragma unroll
    for (int xx = 0; xx < 4; xx++) {
        int m = m0 + tm * 4 + xx;
        if (m >= M) continue;
        #pragma unroll
        for (int yy = 0; yy < 4; yy++) {
            int n = n0 + tn * 4 + yy;
            if (n >= N) continue;
            float v = acc[xx][yy];
            if (bias) v += bias[n];
            if (EPI == 1) v = res[(size_t)m * N + n] + fmaxf(v, 0.f);
            C[(size_t)m * N + n] = v;
        }
    }
}

// ---------------------------------------------------------------------------
// Merged Wih GEMM: C[516][6400] = x @ [Wih_f | Wih_b]^T + [bl_f | bl_b].
// Column blocks are uniform in half (64 | 3200).
__global__ __launch_bounds__(256) void k_gemm_wih(const float* __restrict__ A,
                                                  const float* __restrict__ Wf, const float* __restrict__ Wb,
                                                  const float* __restrict__ bf, const float* __restrict__ bb_,
                                                  float* __restrict__ C)
{
    __shared__ float As[16][68];
    __shared__ float Bs[16][68];
    const int M = 516, K = 800, N = 6400;
    int m0 = blockIdx.x * 64, n0 = blockIdx.y * 64;
    const float* W  = (n0 < 3200) ? Wf : Wb;
    const float* bi = (n0 < 3200) ? bf : bb_;
    int nb = (n0 < 3200) ? n0 : (n0 - 3200);
    int tid = threadIdx.x;
    int tm = tid & 15, tn = tid >> 4;
    float acc[4][4] = {};
    for (int k0 = 0; k0 < K; k0 += 16) {
        {
            int kk = tid & 15, mmb = tid >> 4;
            #pragma unroll
            for (int q = 0; q < 4; q++) {
                int mm = mmb + q * 16;
                int m = m0 + mm;
                As[kk][mm] = (m < M) ? A[(size_t)m * K + k0 + kk] : 0.f;
            }
        }
        {
            int kk = tid & 15, nnb = tid >> 4;
            #pragma unroll
            for (int q = 0; q < 4; q++) {
                int nn = nnb + q * 16;
                Bs[kk][nn] = W[(size_t)(nb + nn) * K + k0 + kk];
            }
        }
        __syncthreads();
        #pragma unroll
        for (int kk = 0; kk < 16; kk++) {
            float4 a = *(const float4*)&As[kk][tm * 4];
            float4 bb = *(const float4*)&Bs[kk][tn * 4];
            float av[4] = {a.x, a.y, a.z, a.w};
            float bv[4] = {bb.x, bb.y, bb.z, bb.w};
            #pragma unroll
            for (int xx = 0; xx < 4; xx++)
                #pragma unroll
                for (int yy = 0; yy < 4; yy++)
                    acc[xx][yy] += av[xx] * bv[yy];
        }
        __syncthreads();
    }
    #pragma unroll
    for (int xx = 0; xx < 4; xx++) {
        int m = m0 + tm * 4 + xx;
        if (m >= M) continue;
        #pragma unroll
        for (int yy = 0; yy < 4; yy++) {
            int n = n0 + tn * 4 + yy;
            C[(size_t)m * N + n] = acc[xx][yy] + bi[nb + (n - n0) + 0];
        }
    }
}

// ---------------------------------------------------------------------------
// Merged table GEMM: uv[512][1600]; col n<800: g2@tW[:800] + tb; else g2@tW[800:].
__global__ __launch_bounds__(256) void k_gemm_uv(const float* __restrict__ A, const float* __restrict__ tW,
                                                 const float* __restrict__ tb, float* __restrict__ C)
{
    __shared__ float As[16][68];
    __shared__ float Bs[16][68];
    const int M = 512, K = 800, N = 1600;
    int m0 = blockIdx.x * 64, n0 = blockIdx.y * 64;
    int tid = threadIdx.x;
    int tm = tid & 15, tn = tid >> 4;
    float acc[4][4] = {};
    for (int k0 = 0; k0 < K; k0 += 16) {
        {
            int kk = tid & 15, mmb = tid >> 4;
            #pragma unroll
            for (int q = 0; q < 4; q++) {
                int mm = mmb + q * 16;
                As[kk][mm] = A[(size_t)(m0 + mm) * K + k0 + kk];
            }
        }
        {
            int nn = (tid & 15) * 4, kk2 = tid >> 4;
            #pragma unroll
            for (int q = 0; q < 4; q++) {
                int n = n0 + nn + q;
                Bs[kk2][nn + q] = (n < 800) ? tW[(size_t)(k0 + kk2) * 800 + n]
                                            : tW[(size_t)(800 + k0 + kk2) * 800 + (n - 800)];
            }
        }
        __syncthreads();
        #pragma unroll
        for (int kk = 0; kk < 16; kk++) {
            float4 a = *(const float4*)&As[kk][tm * 4];
            float4 bb = *(const float4*)&Bs[kk][tn * 4];
            float av[4] = {a.x, a.y, a.z, a.w};
            float bv[4] = {bb.x, bb.y, bb.z, bb.w};
            #pragma unroll
            for (int xx = 0; xx < 4; xx++)
                #pragma unroll
                for (int yy = 0; yy < 4; yy++)
                    acc[xx][yy] += av[xx] * bv[yy];
        }
        __syncthreads();
    }
    #pragma unroll
    for (int xx = 0; xx < 4; xx++) {
        int m = m0 + tm * 4 + xx;
        #pragma unroll
        for (int yy = 0; yy < 4; yy++) {
            int n = n0 + tn * 4 + yy;
            float v = acc[xx][yy];
            if (n < 800) v += tb[n];
            C[(size_t)m * N + n] = v;
        }
    }
}

// ---------------------------------------------------------------------------
// Persistent BiLSTM v8: r7 protocol (proven), gate-folded dot partition.
// Thread (d=tid&7, sl=tid>>3; tid<200): 4 gate-rows of dim d, k-slice sl*32..+31,
// all 4 batches. wreg[4][32] in VGPRs; hb staggered (+4 floats / 32-block) for
// conflict-free 8-way-broadcast b128 reads. Reduce: tid<128 sums 25 slices + xq.
__global__ __launch_bounds__(256) void k_lstm(const float* __restrict__ xW,
                                              const float* __restrict__ Whhf, const float* __restrict__ Whhb,
                                              float* __restrict__ lstm, int* __restrict__ flags)
{
    __shared__ float hb[4][HB_ROW];     // staggered h_{t-1}
    __shared__ float gsum[25][32][4];   // [slice][g*8+d][b]
    __shared__ float gg[128];           // reduced gates: idx (g<<5)|(d<<2)|b
    int wg = blockIdx.x;
    int dir = wg >= NWGD ? 1 : 0;
    int wgd = dir ? wg - NWGD : wg;
    const float* Whh = dir ? Whhb : Whhf;
    const float* xWd = xW + dir * 3200;
    int tid = threadIdx.x;
    bool dotth = tid < 200;
    int d = tid & 7, sl = tid >> 3;     // valid for dotth (sl 0..24)
    int k0 = sl * 32;
    // reduce mapping: u = (rg<<5)|(rd<<2)|rb
    int rb = tid & 3, rd = (tid >> 2) & 7, rg = tid >> 5;
    int lane = tid & 63;

    float wreg[4][32];
    if (dotth) {
        #pragma unroll
        for (int g = 0; g < 4; g++) {
            const float* wp = Whh + (size_t)(g * 800 + wgd * DPW + d) * 800 + k0;
            #pragma unroll
            for (int q = 0; q < 32; q += 4)
                *(float4*)&wreg[g][q] = *(const float4*)&wp[q];
        }
    }
    for (int i = tid; i < 4 * HB_ROW; i += 256) (&hb[0][0])[i] = 0.f;
    __syncthreads();

    float cst = 0.f;                    // cell state (tid<32)
    int fbase = dir * NWGD;

    for (int step = 0; step < 129; step++) {
        int t = dir ? (128 - step) : step;
        float xq = 0.f;
        if (tid < 128)
            xq = xWd[(size_t)(rb * T129 + t) * 6400 + rg * 800 + wgd * DPW + rd];
        if (step > 0) {
            // hot poll by ALL waves
            {
                bool mine = (lane < 25);
                int base = fbase + lane * 4;
                long long iters = 0;
                for (;;) {
                    int mn = step;
                    if (mine) {
                        int f0 = __hip_atomic_load(&flags[base + 0], __ATOMIC_RELAXED, __HIP_MEMORY_SCOPE_AGENT);
                        int f1 = __hip_atomic_load(&flags[base + 1], __ATOMIC_RELAXED, __HIP_MEMORY_SCOPE_AGENT);
                        int f2 = __hip_atomic_load(&flags[base + 2], __ATOMIC_RELAXED, __HIP_MEMORY_SCOPE_AGENT);
                        int f3 = __hip_atomic_load(&flags[base + 3], __ATOMIC_RELAXED, __HIP_MEMORY_SCOPE_AGENT);
                        mn = min(min(f0, f1), min(f2, f3));
                    }
                    if (__all(mn >= step)) break;
                    if (++iters > 50000000LL) break;
                }
            }
            int tprev = dir ? (t + 1) : (t - 1);
            if (tid < 200) {
                const f32x4* p0 = (const f32x4*)(lstm + (size_t)((0 * T129 + tprev) * 1600) + dir * 800) + tid;
                const f32x4* p1 = (const f32x4*)(lstm + (size_t)((1 * T129 + tprev) * 1600) + dir * 800) + tid;
                const f32x4* p2 = (const f32x4*)(lstm + (size_t)((2 * T129 + tprev) * 1600) + dir * 800) + tid;
                const f32x4* p3 = (const f32x4*)(lstm + (size_t)((3 * T129 + tprev) * 1600) + dir * 800) + tid;
                f32x4 v0, v1, v2, v3;
                asm volatile(
                    "global_load_dwordx4 %0, %4, off sc0 sc1\n\t"
                    "global_load_dwordx4 %1, %5, off sc0 sc1\n\t"
                    "global_load_dwordx4 %2, %6, off sc0 sc1\n\t"
                    "global_load_dwordx4 %3, %7, off sc0 sc1\n\t"
                    "s_waitcnt vmcnt(0)"
                    : "=&v"(v0), "=&v"(v1), "=&v"(v2), "=&v"(v3)
                    : "v"(p0), "v"(p1), "v"(p2), "v"(p3)
                    : "memory");
                // staggered store: float4 index f -> f + (f>>3)
                ((f32x4*)&hb[0][0])[tid + (tid >> 3)] = v0;
                int f1i = tid + 200; ((f32x4*)&hb[0][0])[f1i % 200 + ((f1i % 200) >> 3) + 1 * 225] = v1;
                int f2i = tid + 400; ((f32x4*)&hb[0][0])[f2i % 200 + ((f2i % 200) >> 3) + 2 * 225] = v2;
                int f3i = tid + 600; ((f32x4*)&hb[0][0])[f3i % 200 + ((f3i % 200) >> 3) + 3 * 225] = v3;
            }
            __syncthreads();
        }
        if (dotth) {
            float a[4][4] = {};   // [gate][batch]
            #pragma unroll
            for (int b = 0; b < 4; b++) {
                const float* hrow = &hb[b][0];
                #pragma unroll
                for (int q = 0; q < 32; q += 4) {
                    float4 h = *(const float4*)&hrow[sl * 36 + q];
                    #pragma unroll
                    for (int g = 0; g < 4; g++)
                        a[g][b] += wreg[g][q] * h.x + wreg[g][q + 1] * h.y
                                 + wreg[g][q + 2] * h.z + wreg[g][q + 3] * h.w;
                }
            }
            #pragma unroll
            for (int g = 0; g < 4; g++)
                *(float4*)&gsum[sl][g * 8 + d][0] = make_float4(a[g][0], a[g][1], a[g][2], a[g][3]);
        }
        __syncthreads();
        if (tid < 128) {
            float s = xq;
            #pragma unroll
            for (int ss = 0; ss < 25; ss++) s += gsum[ss][rg * 8 + rd][rb];
            gg[tid] = s;
        }
        __syncthreads();
        float hv = 0.f;
        if (tid < 32) {
            int dd = tid & 7, bb2 = tid >> 3;
            float4 gv = *(const float4*)&gg[(0 << 5) | (dd << 2) | bb2];  // placeholder
            // gg layout: idx = (g<<5)|(d<<2)|b -> for fixed (d,b), gates at stride 32
            float gi = gg[(0 << 5) | (dd << 2) | bb2];
            float gf = gg[(1 << 5) | (dd << 2) | bb2];
            float gG = gg[(2 << 5) | (dd << 2) | bb2];
            float go = gg[(3 << 5) | (dd << 2) | bb2];
            (void)gv;
            float si = 1.f / (1.f + __expf(-gi));
            float sf = 1.f / (1.f + __expf(-gf));
            float so = 1.f / (1.f + __expf(-go));
            cst = sf * cst + si * tanhf(gG);
            hv = so * tanhf(cst);       // lane tid: (b=tid>>3, d=tid&7)
        }
        if (tid < 64) {
            int src = (lane & 7) * 4;
            f32x4 o;
            o.x = __shfl(hv, src + 0, 64);
            o.y = __shfl(hv, src + 1, 64);
            o.z = __shfl(hv, src + 2, 64);
            o.w = __shfl(hv, src + 3, 64);
            if (lane < 8) {
                int bb = lane >> 1, half = lane & 1;
                float* ap = lstm + (size_t)((bb * T129 + t) * 1600) + dir * 800 + wgd * DPW + half * 4;
                asm volatile("global_store_dwordx4 %0, %1, off sc0 sc1"
                             :: "v"((f32x4*)ap), "v"(o) : "memory");
            }
            asm volatile("s_waitcnt vmcnt(0)" ::: "memory");
            if (tid == 0 && step < 128)
                __hip_atomic_store(&flags[fbase + wgd], step + 1,
                                   __ATOMIC_RELAXED, __HIP_MEMORY_SCOPE_AGENT);
        }
    }
}

// ---------------------------------------------------------------------------
// Fused GAT layer (coef + softmax + aggregate), one block per (b,h). As r7.
template<int RESMODE>
__global__ __launch_bounds__(512) void k_gat_fused(const int* __restrict__ esrc, const int* __restrict__ edst,
                                                   const float* __restrict__ h1,
                                                   const float* __restrict__ asrc, const float* __restrict__ adst,
                                                   const float* __restrict__ gbias,
                                                   const float* __restrict__ res, float* __restrict__ out)
{
    __shared__ int se[384], de[384];
    __shared__ float asl[128], adl[128], ml[128], dl_[128];
    int bh = blockIdx.x;
    int b = bh >> 3, h = bh & 7;
    int t = threadIdx.x;
    if (t < 384) {
        if (t < E256) { se[t] = esrc[b * E256 + t]; de[t] = edst[b * E256 + t]; }
        else          { se[t] = t - E256;           de[t] = t - E256; }
    }
    int node = t >> 2, ch = t & 3;
    int dd0 = ch * 25;
    {
        const float* hp = h1 + (size_t)(b * S128 + node) * H800 + h * 100 + dd0;
        const float* ap = asrc + h * 100 + dd0;
        const float* dp = adst + h * 100 + dd0;
        float s1 = 0.f, s2 = 0.f;
        #pragma unroll
        for (int q = 0; q < 25; q++) { float hv = hp[q]; s1 += hv * ap[q]; s2 += hv * dp[q]; }
        s1 += __shfl_xor(s1, 1, 64); s1 += __shfl_xor(s1, 2, 64);
        s2 += __shfl_xor(s2, 1, 64); s2 += __shfl_xor(s2, 2, 64);
        if (ch == 0) { asl[node] = s1; adl[node] = s2; }
    }
    __syncthreads();
    if (t < 128) {
        float myad = adl[t];
        float m = -3.4e38f;
        for (int e = 0; e < 384; e++)
            if (de[e] == t) {
                float sc = asl[se[e]] + myad;
                sc = (sc > 0.f) ? sc : 0.2f * sc;
                m = fmaxf(m, sc);
            }
        float den = 0.f;
        for (int e = 0; e < 384; e++)
            if (de[e] == t) {
                float sc = asl[se[e]] + myad;
                sc = (sc > 0.f) ? sc : 0.2f * sc;
                den += __expf(sc - m);
            }
        ml[t] = m; dl_[t] = den;
    }
    __syncthreads();
    float acc[25] = {};
    float myad = adl[node], mym = ml[node];
    for (int e = 0; e < 384; e++) {
        if (de[e] == node) {
            int s = se[e];
            float sc = asl[s] + myad;
            sc = (sc > 0.f) ? sc : 0.2f * sc;
            float w = __expf(sc - mym);
            const float* hp = h1 + (size_t)(b * S128 + s) * H800 + h * 100 + dd0;
            #pragma unroll
            for (int q = 0; q < 25; q++) acc[q] += w * hp[q];
        }
    }
    float inv = 1.f / dl_[node];
    int n = b * S128 + node;
    size_t rrow = (RESMODE == 1) ? (size_t)(n + b + 1) * H800 : (size_t)n * H800;
    #pragma unroll
    for (int q = 0; q < 25; q++) {
        int col = h * 100 + dd0 + q;
        float v = acc[q] * inv + gbias[col];
        out[(size_t)n * H800 + col] = res[rrow + col] + fmaxf(v, 0.f);
    }
}

// ---------------------------------------------------------------------------
// Trig head, diagonal only. uv stride 1600: u = row, v = row+800.
__global__ __launch_bounds__(64) void k_trig(const float* __restrict__ uv,
                                             const float* __restrict__ W, const float* __restrict__ bias,
                                             const int* __restrict__ labels, float* __restrict__ d_out)
{
    __shared__ float s[800];
    __shared__ float lg[66];
    int bi = blockIdx.x;          // b*128+i
    int i = bi & 127;
    int l = threadIdx.x;
    const float* ur = uv + (size_t)bi * 1600;
    const float* vr = ur + 800;
    for (int k = l; k < 800; k += 64) s[k] = gelu_f(ur[k] + vr[k]);
    __syncthreads();
    float a0 = 0.f, a1 = 0.f;
    bool has2 = (l < 2);
    for (int k = 0; k < 800; k++) {
        float sv = s[k];
        a0 += sv * W[k * NE + l];
        if (has2) a1 += sv * W[k * NE + 64 + l];
    }
    lg[l] = a0 + bias[l];
    if (has2) lg[64 + l] = a1 + bias[64 + l];
    __syncthreads();
    if (l == 0) {
        float m = lg[0];
        for (int c = 1; c < NE; c++) m = fmaxf(m, lg[c]);
        float se = 0.f, sl = 0.f, bv = lg[0];
        int am = 0;
        for (int c = 0; c < NE; c++) {
            se += __expf(lg[c] - m);
            sl += lg[c];
            if (lg[c] > bv) { bv = lg[c]; am = c; }
        }
        float lse = m + __logf(se);
        int tgt = labels[(size_t)bi * S128 + i];
        float ce = (0.1f / NE) * (NE * lse - sl) + 0.9f * (lse - lg[tgt]);
        atomicAdd(d_out, ce * (1.f / 128.f));
        int r = bi * S128 + i;
        d_out[1 + r] = (float)am;
        d_out[1 + 65536 + r] = (float)am;
    }
}

// ---------------------------------------------------------------------------
// Fused rs+re logits, TWO batches per launch (blockIdx.y). uv stride 1600.
__global__ __launch_bounds__(256) void k_logits2(const float* __restrict__ uvb,
                                                 const float* __restrict__ rsW, const float* __restrict__ rsb,
                                                 const float* __restrict__ reW, const float* __restrict__ reb,
                                                 float* __restrict__ L)
{
    __shared__ float As[16][68];
    __shared__ float Bs[16][256];
    int bi = blockIdx.y;
    const float* base = uvb + (size_t)bi * 128 * 1600;
    float* Lb = L + (size_t)bi * 16384 * 256;
    int il = blockIdx.x >> 1;
    int j0 = (blockIdx.x & 1) * 64;
    const float* urow = base + (size_t)il * 1600;
    int tid = threadIdx.x;
    int tm = tid & 7, tn = tid >> 3;        // rows tm*8..+7, cols tn*8..+7
    float acc[8][8] = {};
    int ct = tid;
    int hc = (ct < 128) ? ct : (ct - 128);
    const float* Wp = (ct < 128) ? rsW : reW;
    bool cok = hc < NR;
    for (int k0 = 0; k0 < 800; k0 += 16) {
        {
            int kk = tid & 15, rrb = tid >> 4;
            float uk = urow[k0 + kk];
            #pragma unroll
            for (int q = 0; q < 4; q++) {
                int rr = rrb + q * 16;
                float xv = uk + base[(size_t)(j0 + rr) * 1600 + 800 + k0 + kk];
                As[kk][rr] = gelu_f(xv);
            }
        }
        #pragma unroll
        for (int kk2 = 0; kk2 < 16; kk2++)
            Bs[kk2][ct] = cok ? Wp[(size_t)(k0 + kk2) * NR + hc] : 0.f;
        __syncthreads();
        #pragma unroll
        for (int kk = 0; kk < 16; kk++) {
            float4 a0 = *(const float4*)&As[kk][tm * 8];
            float4 a1 = *(const float4*)&As[kk][tm * 8 + 4];
            float4 b0 = *(const float4*)&Bs[kk][tn * 8];
            float4 b1 = *(const float4*)&Bs[kk][tn * 8 + 4];
            float av[8] = {a0.x, a0.y, a0.z, a0.w, a1.x, a1.y, a1.z, a1.w};
            float bv[8] = {b0.x, b0.y, b0.z, b0.w, b1.x, b1.y, b1.z, b1.w};
            #pragma unroll
            for (int xx = 0; xx < 8; xx++)
                #pragma unroll
                for (int yy = 0; yy < 8; yy++)
                    acc[xx][yy] += av[xx] * bv[yy];
        }
        __syncthreads();
    }
    int head = tn >> 4;
    const float* bp = head ? reb : rsb;
    #pragma unroll
    for (int xx = 0; xx < 8; xx++) {
        int r = il * S128 + j0 + tm * 8 + xx;
        float* Lr = Lb + (size_t)r * 256 + tn * 8;
        #pragma unroll
        for (int hf = 0; hf < 2; hf++) {
            int c = (tn * 8 + hf * 4) & 127;
            if (c + 3 < NR) {
                float4 o = make_float4(acc[xx][hf*4+0] + bp[c+0], acc[xx][hf*4+1] + bp[c+1],
                                       acc[xx][hf*4+2] + bp[c+2], acc[xx][hf*4+3] + bp[c+3]);
                *(float4*)(Lr + hf * 4) = o;
            } else {
                #pragma unroll
                for (int q = 0; q < 4; q++)
                    if (c + q < NR) Lr[hf * 4 + q] = acc[xx][hf*4+q] + bp[c+q];
            }
        }
    }
}

// CE loss + symmetric argmax, both heads, batch PAIR (32768 rows).
__global__ __launch_bounds__(256) void k_loss2(const float* __restrict__ L,
                                               const int* __restrict__ lab0, const int* __restrict__ lab1,
                                               float* __restrict__ res0, float* __restrict__ res1,
                                               float* __restrict__ lossptr)
{
    __shared__ float wsum[4];
    int wv = threadIdx.x >> 6, l = threadIdx.x & 63;
    int rr = blockIdx.x * 4 + wv;         // [0, 32768)
    int bi = rr >> 14;
    int r = rr & 16383;
    int i = r >> 7, j = r & 127;
    size_t bioff = (size_t)bi * 16384;
    float ces = 0.f;
    if (i != j) {
        const float* row  = L + (bioff + r) * 256;
        const float* prow = L + (bioff + ((j << 7) | i)) * 256;
        bool v2 = (l < NR - 64);
        #pragma unroll
        for (int hd = 0; hd < 2; hd++) {
            const float* rw = row + hd * 128;
            const float* pw = prow + hd * 128;
            float x1 = rw[l];
            float x2 = v2 ? rw[l + 64] : -3.4e38f;
            float m = fmaxf(x1, x2);
            #pragma unroll
            for (int s = 32; s; s >>= 1) m = fmaxf(m, __shfl_xor(m, s, 64));
            float se = __expf(x1 - m) + (v2 ? __expf(x2 - m) : 0.f);
            float sl = x1 + (v2 ? x2 : 0.f);
            #pragma unroll
            for (int s = 32; s; s >>= 1) { se += __shfl_xor(se, s, 64); sl += __shfl_xor(sl, s, 64); }
            float lse = m + __logf(se);
            int tgt = (hd ? lab1 : lab0)[bioff + r];
            float lt = rw[tgt];
            ces += (0.1f / NR) * (NR * lse - sl) + 0.9f * (lse - lt);
            float y1 = x1 + pw[l];
            float y2 = v2 ? (x2 + pw[l + 64]) : -3.4e38f;
            float bv; int bidx;
            if (y2 > y1) { bv = y2; bidx = l + 64; } else { bv = y1; bidx = l; }
            #pragma unroll
            for (int s = 32; s; s >>= 1) {
                float ov = __shfl_xor(bv, s, 64);
                int oi = __shfl_xor(bidx, s, 64);
                if (ov > bv || (ov == bv && oi < bidx)) { bv = ov; bidx = oi; }
            }
            if (l == 0) (hd ? res1 : res0)[bioff + r] = (float)bidx;
        }
    }
    if (l == 0) wsum[wv] = ces;
    __syncthreads();
    if (threadIdx.x == 0) {
        float s = (wsum[0] + wsum[1] + wsum[2] + wsum[3]) * (1.f / 16256.f);
        atomicAdd(lossptr, s);
    }
}

// ---------------------------------------------------------------------------
extern "C" void kernel_launch(void* const* d_in, const int* in_sizes, int n_in,
                              void* d_out, int out_size, void* d_ws, size_t ws_size,
                              hipStream_t stream)
{
    (void)in_sizes; (void)n_in; (void)out_size; (void)ws_size;
    const float* bert  = (const float*)d_in[0];
    const int*   pids  = (const int*)d_in[1];
    const int*   esrc  = (const int*)d_in[2];
    const int*   edst  = (const int*)d_in[3];
    const int*   slab  = (const int*)d_in[4];
    const int*   elab  = (const int*)d_in[5];
    const float* ptab  = (const float*)d_in[6];
    const float* Wih_f = (const float*)d_in[7];
    const float* Whh_f = (const float*)d_in[8];
    const float* bl_f  = (const float*)d_in[9];
    const float* Wih_b = (const float*)d_in[10];
    const float* Whh_b = (const float*)d_in[11];
    const float* bl_b  = (const float*)d_in[12];
    const float* fcW   = (const float*)d_in[13];
    const float* fcb   = (const float*)d_in[14];
    const float* tW    = (const float*)d_in[15];
    const float* tb    = (const float*)d_in[16];
    const float* gatW  = (const float*)d_in[17];
    const float* asrc  = (const float*)d_in[18];
    const float* adst  = (const float*)d_in[19];
    const float* gbias = (const float*)d_in[20];
    const float* trigW = (const float*)d_in[21];
    const float* trigb = (const float*)d_in[22];
    const float* rsW   = (const float*)d_in[23];
    const float* rsb   = (const float*)d_in[24];
    const float* reW   = (const float*)d_in[25];
    const float* reb   = (const float*)d_in[26];
    float* out = (float*)d_out;

    float* ws = (float*)d_ws;
    size_t off = 0;
    auto alloc = [&](size_t n) { float* p = ws + off; off += (n + 255) & ~(size_t)255; return p; };
    float* uv    = alloc((size_t)512 * 1600);     // live late (trig/logits)
    int*   flags = (int*)alloc(512);
    float* R     = ws + off;                      // overlay region
    size_t roff = 0;
    auto ralloc = [&](size_t n) { float* p = R + roff; roff += (n + 255) & ~(size_t)255; return p; };
    float* x    = ralloc(516 * 800);
    float* xW   = ralloc((size_t)516 * 6400);
    float* lstm = ralloc((size_t)516 * 1600);
    float* xg   = ralloc(516 * 800);
    float* h1   = ralloc(512 * 800);
    float* g1   = ralloc(512 * 800);
    float* g2   = ralloc(512 * 800);
    float* Lbuf = R;   // overlays dead temps; 2 batches x 16384 x 256 floats

    hipMemsetAsync(d_out, 0, 4, stream);                 // loss accumulator
    hipMemsetAsync(flags, 0, 2 * NWGD * sizeof(int), stream);

    k_embed<<<(B4 * T129 * H800 + 255) / 256, 256, 0, stream>>>(bert, pids, ptab, x);

    // merged gate-input precompute: xW[516][6400] = x @ [Wf|Wb]^T + [bf|bb]
    k_gemm_wih<<<dim3(9, 100), 256, 0, stream>>>(x, Wih_f, Wih_b, bl_f, bl_b, xW);

    k_lstm<<<2 * NWGD, 256, 0, stream>>>(xW, Whh_f, Whh_b, lstm, flags);

    // xg = x + relu(lstm @ fcW + fcb)
    k_gemm<0, 0, 1><<<dim3(9, 13), 256, 0, stream>>>(lstm, fcW, fcb, x, xg, 516, 800, 1600);

    // GAT layer 1 (input = xg[:,1:,:] view)
    k_gemm<1, 0, 0><<<dim3(8, 13), 256, 0, stream>>>(xg, gatW, nullptr, nullptr, h1, 512, 800, 800);
    k_gat_fused<1><<<32, 512, 0, stream>>>(esrc, edst, h1, asrc, adst, gbias, xg, g1);
    // GAT layer 2
    k_gemm<0, 0, 0><<<dim3(8, 13), 256, 0, stream>>>(g1, gatW, nullptr, nullptr, h1, 512, 800, 800);
    k_gat_fused<0><<<32, 512, 0, stream>>>(esrc, edst, h1, asrc, adst, gbias, g1, g2);

    // merged table split: uv[512][1600] (u | v)
    k_gemm_uv<<<dim3(8, 25), 256, 0, stream>>>(g2, tW, tb, uv);

    // trig head (diag)
    k_trig<<<512, 64, 0, stream>>>(uv, trigW, trigb, slab, out);

    // rs+re heads, 2 batches per pass
    for (int bp = 0; bp < 2; bp++) {
        k_logits2<<<dim3(256, 2), 256, 0, stream>>>(uv + (size_t)bp * 2 * 128 * 1600,
                                                    rsW, rsb, reW, reb, Lbuf);
        k_loss2<<<8192, 256, 0, stream>>>(Lbuf,
                                          slab + (size_t)bp * 2 * 16384, elab + (size_t)bp * 2 * 16384,
                                          out + 1 + (size_t)bp * 2 * 16384,
                                          out + 1 + 65536 + (size_t)bp * 2 * 16384, out);
    }
}

// Round 9
// 2481.390 us; speedup vs baseline: 2.8277x; 1.1089x over previous
//
#include <hip/hip_runtime.h>
#include <hip/hip_bf16.h>

// Problem dims
#define B4 4
#define S128 128
#define T129 129
#define H800 800
#define E256 256
#define NE 66
#define NR 122
#define DPW 8      // LSTM dims per WG
#define NWGD 100   // LSTM WGs per direction
#define FSTR 32    // flag stride in ints (128 B = one IC line per flag)

typedef float f32x4 __attribute__((ext_vector_type(4)));

#define HB_ROW 900

// ---------------------------------------------------------------------------
__device__ __forceinline__ float gelu_f(float x) {
    float t = 0.7978845608028654f * (x + 0.044715f * x * x * x);
    float e = __expf(2.f * t);
    float th = 1.f - 2.f / (e + 1.f);
    return 0.5f * x * (1.f + th);
}

// embed(m, c): element of the concatenated input x[516][800], built on the fly
__device__ __forceinline__ float embed_at(const float* __restrict__ bert,
                                          const int* __restrict__ pids,
                                          const float* __restrict__ ptab,
                                          int m, int c)
{
    if (c < 768) return bert[(size_t)m * 768 + c];
    int t = m % T129, b = m / T129;
    if (t == 0) return 0.f;
    return ptab[pids[b * S128 + t - 1] * 32 + (c - 768)];
}

// ---------------------------------------------------------------------------
// Generic fp32 tiled GEMM. AMODE 1: xg-view row. BTRANS 1: A@B^T.
template<int AMODE, int BTRANS, int EPI>
__global__ __launch_bounds__(256) void k_gemm(const float* __restrict__ A, const float* __restrict__ Bm,
                                              const float* __restrict__ bias, const float* __restrict__ res,
                                              float* __restrict__ C, int M, int N, int K)
{
    __shared__ float As[16][68];
    __shared__ float Bs[16][68];
    int m0 = blockIdx.x * 64, n0 = blockIdx.y * 64;
    int tid = threadIdx.x;
    int tm = tid & 15, tn = tid >> 4;
    float acc[4][4] = {};
    for (int k0 = 0; k0 < K; k0 += 16) {
        {
            int kk = tid & 15, mmb = tid >> 4;
            #pragma unroll
            for (int q = 0; q < 4; q++) {
                int mm = mmb + q * 16;
                int m = m0 + mm;
                float v = 0.f;
                if (m < M) {
                    int row = (AMODE == 1) ? (m + (m >> 7) + 1) : m;
                    v = A[(size_t)row * K + k0 + kk];
                }
                As[kk][mm] = v;
            }
        }
        if (BTRANS == 0) {
            int nn = (tid & 15) * 4, kk2 = tid >> 4;
            int n = n0 + nn;
            float t0, t1, t2, t3;
            if (n + 3 < N) {
                const float4 bv = *(const float4*)&Bm[(size_t)(k0 + kk2) * N + n];
                t0 = bv.x; t1 = bv.y; t2 = bv.z; t3 = bv.w;
            } else {
                t0 = (n + 0 < N) ? Bm[(size_t)(k0 + kk2) * N + n + 0] : 0.f;
                t1 = (n + 1 < N) ? Bm[(size_t)(k0 + kk2) * N + n + 1] : 0.f;
                t2 = (n + 2 < N) ? Bm[(size_t)(k0 + kk2) * N + n + 2] : 0.f;
                t3 = (n + 3 < N) ? Bm[(size_t)(k0 + kk2) * N + n + 3] : 0.f;
            }
            Bs[kk2][nn + 0] = t0; Bs[kk2][nn + 1] = t1; Bs[kk2][nn + 2] = t2; Bs[kk2][nn + 3] = t3;
        } else {
            int kk = tid & 15, nnb = tid >> 4;
            #pragma unroll
            for (int q = 0; q < 4; q++) {
                int nn = nnb + q * 16;
                int n = n0 + nn;
                Bs[kk][nn] = (n < N) ? Bm[(size_t)n * K + k0 + kk] : 0.f;
            }
        }
        __syncthreads();
        #pragma unroll
        for (int kk = 0; kk < 16; kk++) {
            float4 a = *(const float4*)&As[kk][tm * 4];
            float4 bb = *(const float4*)&Bs[kk][tn * 4];
            float av[4] = {a.x, a.y, a.z, a.w};
            float bv[4] = {bb.x, bb.y, bb.z, bb.w};
            #pragma unroll
            for (int xx = 0; xx < 4; xx++)
                #pragma unroll
                for (int yy = 0; yy < 4; yy++)
                    acc[xx][yy] += av[xx] * bv[yy];
        }
        __syncthreads();
    }
    #pragma unroll
    for (int xx = 0; xx < 4; xx++) {
        int m = m0 + tm * 4 + xx;
        if (m >= M) continue;
        #pragma unroll
        for (int yy = 0; yy < 4; yy++) {
            int n = n0 + tn * 4 + yy;
            if (n >= N) continue;
            float v = acc[xx][yy];
            if (bias) v += bias[n];
            if (EPI == 1) v = res[(size_t)m * N + n] + fmaxf(v, 0.f);
            C[(size_t)m * N + n] = v;
        }
    }
}

// ---------------------------------------------------------------------------
// Merged Wih GEMM with FUSED EMBED A-tile:
// C[516][6400] = embed(x) @ [Wih_f | Wih_b]^T + [bl_f | bl_b].
__global__ __launch_bounds__(256) void k_gemm_wih(const float* __restrict__ bert,
                                                  const int* __restrict__ pids,
                                                  const float* __restrict__ ptab,
                                                  const float* __restrict__ Wf, const float* __restrict__ Wb,
                                                  const float* __restrict__ bf, const float* __restrict__ bb_,
                                                  float* __restrict__ C)
{
    __shared__ float As[16][68];
    __shared__ float Bs[16][68];
    const int M = 516, K = 800, N = 6400;
    int m0 = blockIdx.x * 64, n0 = blockIdx.y * 64;
    const float* W  = (n0 < 3200) ? Wf : Wb;
    const float* bi = (n0 < 3200) ? bf : bb_;
    int nb = (n0 < 3200) ? n0 : (n0 - 3200);
    int tid = threadIdx.x;
    int tm = tid & 15, tn = tid >> 4;
    int kk_s = tid & 15, mmb = tid >> 4;
    int mrow[4]; int pofs[4]; bool mok[4];
    #pragma unroll
    for (int q = 0; q < 4; q++) {
        int m = m0 + mmb + q * 16;
        mrow[q] = m;
        mok[q] = m < M;
        int t = m % T129, b = m / T129;
        pofs[q] = (mok[q] && t > 0) ? pids[b * S128 + t - 1] * 32 : -1;
    }
    float acc[4][4] = {};
    for (int k0 = 0; k0 < K; k0 += 16) {
        {
            int c = k0 + kk_s;
            #pragma unroll
            for (int q = 0; q < 4; q++) {
                float v = 0.f;
                if (mok[q]) {
                    if (c < 768) v = bert[(size_t)mrow[q] * 768 + c];
                    else         v = (pofs[q] < 0) ? 0.f : ptab[pofs[q] + c - 768];
                }
                As[kk_s][mmb + q * 16] = v;
            }
        }
        {
            int kk = tid & 15, nnb = tid >> 4;
            #pragma unroll
            for (int q = 0; q < 4; q++) {
                int nn = nnb + q * 16;
                Bs[kk][nn] = W[(size_t)(nb + nn) * K + k0 + kk];
            }
        }
        __syncthreads();
        #pragma unroll
        for (int kk = 0; kk < 16; kk++) {
            float4 a = *(const float4*)&As[kk][tm * 4];
            float4 bb = *(const float4*)&Bs[kk][tn * 4];
            float av[4] = {a.x, a.y, a.z, a.w};
            float bv[4] = {bb.x, bb.y, bb.z, bb.w};
            #pragma unroll
            for (int xx = 0; xx < 4; xx++)
                #pragma unroll
                for (int yy = 0; yy < 4; yy++)
                    acc[xx][yy] += av[xx] * bv[yy];
        }
        __syncthreads();
    }
    #pragma unroll
    for (int xx = 0; xx < 4; xx++) {
        int m = m0 + tm * 4 + xx;
        if (m >= M) continue;
        #pragma unroll
        for (int yy = 0; yy < 4; yy++) {
            int n = n0 + tn * 4 + yy;
            C[(size_t)m * N + n] = acc[xx][yy] + bi[nb + (n - n0)];
        }
    }
}

// ---------------------------------------------------------------------------
// fc GEMM with FUSED EMBED residual: xg = embed(x) + relu(lstm @ fcW + fcb).
__global__ __launch_bounds__(256) void k_gemm_fc(const float* __restrict__ A, const float* __restrict__ Bm,
                                                 const float* __restrict__ bias,
                                                 const float* __restrict__ bert, const int* __restrict__ pids,
                                                 const float* __restrict__ ptab, float* __restrict__ C)
{
    __shared__ float As[16][68];
    __shared__ float Bs[16][68];
    const int M = 516, N = 800, K = 1600;
    int m0 = blockIdx.x * 64, n0 = blockIdx.y * 64;
    int tid = threadIdx.x;
    int tm = tid & 15, tn = tid >> 4;
    float acc[4][4] = {};
    for (int k0 = 0; k0 < K; k0 += 16) {
        {
            int kk = tid & 15, mmb = tid >> 4;
            #pragma unroll
            for (int q = 0; q < 4; q++) {
                int mm = mmb + q * 16;
                int m = m0 + mm;
                As[kk][mm] = (m < M) ? A[(size_t)m * K + k0 + kk] : 0.f;
            }
        }
        {
            int nn = (tid & 15) * 4, kk2 = tid >> 4;
            int n = n0 + nn;
            if (n + 3 < N) {
                *(float4*)&Bs[kk2][nn] = *(const float4*)&Bm[(size_t)(k0 + kk2) * N + n];
            } else {
                #pragma unroll
                for (int q = 0; q < 4; q++)
                    Bs[kk2][nn + q] = (n + q < N) ? Bm[(size_t)(k0 + kk2) * N + n + q] : 0.f;
            }
        }
        __syncthreads();
        #pragma unroll
        for (int kk = 0; kk < 16; kk++) {
            float4 a = *(const float4*)&As[kk][tm * 4];
            float4 bb = *(const float4*)&Bs[kk][tn * 4];
            float av[4] = {a.x, a.y, a.z, a.w};
            float bv[4] = {bb.x, bb.y, bb.z, bb.w};
            #pragma unroll
            for (int xx = 0; xx < 4; xx++)
                #pragma unroll
                for (int yy = 0; yy < 4; yy++)
                    acc[xx][yy] += av[xx] * bv[yy];
        }
        __syncthreads();
    }
    #pragma unroll
    for (int xx = 0; xx < 4; xx++) {
        int m = m0 + tm * 4 + xx;
        if (m >= M) continue;
        #pragma unroll
        for (int yy = 0; yy < 4; yy++) {
            int n = n0 + tn * 4 + yy;
            if (n >= N) continue;
            float v = fmaxf(acc[xx][yy] + bias[n], 0.f);
            C[(size_t)m * N + n] = embed_at(bert, pids, ptab, m, n) + v;
        }
    }
}

// ---------------------------------------------------------------------------
// Merged table GEMM: uv[512][1600]; col n<800: g2@tW[:800] + tb; else g2@tW[800:].
__global__ __launch_bounds__(256) void k_gemm_uv(const float* __restrict__ A, const float* __restrict__ tW,
                                                 const float* __restrict__ tb, float* __restrict__ C)
{
    __shared__ float As[16][68];
    __shared__ float Bs[16][68];
    const int M = 512, K = 800, N = 1600;
    int m0 = blockIdx.x * 64, n0 = blockIdx.y * 64;
    int tid = threadIdx.x;
    int tm = tid & 15, tn = tid >> 4;
    float acc[4][4] = {};
    for (int k0 = 0; k0 < K; k0 += 16) {
        {
            int kk = tid & 15, mmb = tid >> 4;
            #pragma unroll
            for (int q = 0; q < 4; q++) {
                int mm = mmb + q * 16;
                As[kk][mm] = A[(size_t)(m0 + mm) * K + k0 + kk];
            }
        }
        {
            int nn = (tid & 15) * 4, kk2 = tid >> 4;
            #pragma unroll
            for (int q = 0; q < 4; q++) {
                int n = n0 + nn + q;
                Bs[kk2][nn + q] = (n < 800) ? tW[(size_t)(k0 + kk2) * 800 + n]
                                            : tW[(size_t)(800 + k0 + kk2) * 800 + (n - 800)];
            }
        }
        __syncthreads();
        #pragma unroll
        for (int kk = 0; kk < 16; kk++) {
            float4 a = *(const float4*)&As[kk][tm * 4];
            float4 bb = *(const float4*)&Bs[kk][tn * 4];
            float av[4] = {a.x, a.y, a.z, a.w};
            float bv[4] = {bb.x, bb.y, bb.z, bb.w};
            #pragma unroll
            for (int xx = 0; xx < 4; xx++)
                #pragma unroll
                for (int yy = 0; yy < 4; yy++)
                    acc[xx][yy] += av[xx] * bv[yy];
        }
        __syncthreads();
    }
    #pragma unroll
    for (int xx = 0; xx < 4; xx++) {
        int m = m0 + tm * 4 + xx;
        #pragma unroll
        for (int yy = 0; yy < 4; yy++) {
            int n = n0 + tn * 4 + yy;
            float v = acc[xx][yy];
            if (n < 800) v += tb[n];
            C[(size_t)m * N + n] = v;
        }
    }
}

// ---------------------------------------------------------------------------
// Persistent BiLSTM v9 = v8 with one-IC-line-per-flag padding (FSTR=32 ints).
__global__ __launch_bounds__(256) void k_lstm(const float* __restrict__ xW,
                                              const float* __restrict__ Whhf, const float* __restrict__ Whhb,
                                              float* __restrict__ lstm, int* __restrict__ flags)
{
    __shared__ float hb[4][HB_ROW];     // staggered h_{t-1}
    __shared__ float gsum[25][32][4];   // [slice][g*8+d][b]
    __shared__ float gg[128];           // reduced gates: idx (g<<5)|(d<<2)|b
    int wg = blockIdx.x;
    int dir = wg >= NWGD ? 1 : 0;
    int wgd = dir ? wg - NWGD : wg;
    const float* Whh = dir ? Whhb : Whhf;
    const float* xWd = xW + dir * 3200;
    int tid = threadIdx.x;
    bool dotth = tid < 200;
    int d = tid & 7, sl = tid >> 3;     // valid for dotth (sl 0..24)
    int k0 = sl * 32;
    int rb = tid & 3, rd = (tid >> 2) & 7, rg = tid >> 5;
    int lane = tid & 63;

    float wreg[4][32];
    if (dotth) {
        #pragma unroll
        for (int g = 0; g < 4; g++) {
            const float* wp = Whh + (size_t)(g * 800 + wgd * DPW + d) * 800 + k0;
            #pragma unroll
            for (int q = 0; q < 32; q += 4)
                *(float4*)&wreg[g][q] = *(const float4*)&wp[q];
        }
    }
    for (int i = tid; i < 4 * HB_ROW; i += 256) (&hb[0][0])[i] = 0.f;
    __syncthreads();

    float cst = 0.f;                    // cell state (tid<32)
    int fid = dir * NWGD + wgd;

    for (int step = 0; step < 129; step++) {
        int t = dir ? (128 - step) : step;
        float xq = 0.f;
        if (tid < 128)
            xq = xWd[(size_t)(rb * T129 + t) * 6400 + rg * 800 + wgd * DPW + rd];
        if (step > 0) {
            {
                bool mine = (lane < 25);
                int base = dir * NWGD + lane * 4;
                long long iters = 0;
                for (;;) {
                    int mn = step;
                    if (mine) {
                        int f0 = __hip_atomic_load(&flags[(base + 0) * FSTR], __ATOMIC_RELAXED, __HIP_MEMORY_SCOPE_AGENT);
                        int f1 = __hip_atomic_load(&flags[(base + 1) * FSTR], __ATOMIC_RELAXED, __HIP_MEMORY_SCOPE_AGENT);
                        int f2 = __hip_atomic_load(&flags[(base + 2) * FSTR], __ATOMIC_RELAXED, __HIP_MEMORY_SCOPE_AGENT);
                        int f3 = __hip_atomic_load(&flags[(base + 3) * FSTR], __ATOMIC_RELAXED, __HIP_MEMORY_SCOPE_AGENT);
                        mn = min(min(f0, f1), min(f2, f3));
                    }
                    if (__all(mn >= step)) break;
                    if (++iters > 50000000LL) break;
                }
            }
            int tprev = dir ? (t + 1) : (t - 1);
            if (tid < 200) {
                const f32x4* p0 = (const f32x4*)(lstm + (size_t)((0 * T129 + tprev) * 1600) + dir * 800) + tid;
                const f32x4* p1 = (const f32x4*)(lstm + (size_t)((1 * T129 + tprev) * 1600) + dir * 800) + tid;
                const f32x4* p2 = (const f32x4*)(lstm + (size_t)((2 * T129 + tprev) * 1600) + dir * 800) + tid;
                const f32x4* p3 = (const f32x4*)(lstm + (size_t)((3 * T129 + tprev) * 1600) + dir * 800) + tid;
                f32x4 v0, v1, v2, v3;
                asm volatile(
                    "global_load_dwordx4 %0, %4, off sc0 sc1\n\t"
                    "global_load_dwordx4 %1, %5, off sc0 sc1\n\t"
                    "global_load_dwordx4 %2, %6, off sc0 sc1\n\t"
                    "global_load_dwordx4 %3, %7, off sc0 sc1\n\t"
                    "s_waitcnt vmcnt(0)"
                    : "=&v"(v0), "=&v"(v1), "=&v"(v2), "=&v"(v3)
                    : "v"(p0), "v"(p1), "v"(p2), "v"(p3)
                    : "memory");
                ((f32x4*)&hb[0][0])[tid + (tid >> 3)] = v0;
                int f1i = tid + 200; ((f32x4*)&hb[0][0])[f1i % 200 + ((f1i % 200) >> 3) + 1 * 225] = v1;
                int f2i = tid + 400; ((f32x4*)&hb[0][0])[f2i % 200 + ((f2i % 200) >> 3) + 2 * 225] = v2;
                int f3i = tid + 600; ((f32x4*)&hb[0][0])[f3i % 200 + ((f3i % 200) >> 3) + 3 * 225] = v3;
            }
            __syncthreads();
        }
        if (dotth) {
            float a[4][4] = {};   // [gate][batch]
            #pragma unroll
            for (int b = 0; b < 4; b++) {
                const float* hrow = &hb[b][0];
                #pragma unroll
                for (int q = 0; q < 32; q += 4) {
                    float4 h = *(const float4*)&hrow[sl * 36 + q];
                    #pragma unroll
                    for (int g = 0; g < 4; g++)
                        a[g][b] += wreg[g][q] * h.x + wreg[g][q + 1] * h.y
                                 + wreg[g][q + 2] * h.z + wreg[g][q + 3] * h.w;
                }
            }
            #pragma unroll
            for (int g = 0; g < 4; g++)
                *(float4*)&gsum[sl][g * 8 + d][0] = make_float4(a[g][0], a[g][1], a[g][2], a[g][3]);
        }
        __syncthreads();
        if (tid < 128) {
            float s = xq;
            #pragma unroll
            for (int ss = 0; ss < 25; ss++) s += gsum[ss][rg * 8 + rd][rb];
            gg[tid] = s;
        }
        __syncthreads();
        float hv = 0.f;
        if (tid < 32) {
            int dd = tid & 7, bb2 = tid >> 3;
            float gi = gg[(0 << 5) | (dd << 2) | bb2];
            float gf = gg[(1 << 5) | (dd << 2) | bb2];
            float gG = gg[(2 << 5) | (dd << 2) | bb2];
            float go = gg[(3 << 5) | (dd << 2) | bb2];
            float si = 1.f / (1.f + __expf(-gi));
            float sf = 1.f / (1.f + __expf(-gf));
            float so = 1.f / (1.f + __expf(-go));
            cst = sf * cst + si * tanhf(gG);
            hv = so * tanhf(cst);
        }
        if (tid < 64) {
            int src = (lane & 7) * 4;
            f32x4 o;
            o.x = __shfl(hv, src + 0, 64);
            o.y = __shfl(hv, src + 1, 64);
            o.z = __shfl(hv, src + 2, 64);
            o.w = __shfl(hv, src + 3, 64);
            if (lane < 8) {
                int bb = lane >> 1, half = lane & 1;
                float* ap = lstm + (size_t)((bb * T129 + t) * 1600) + dir * 800 + wgd * DPW + half * 4;
                asm volatile("global_store_dwordx4 %0, %1, off sc0 sc1"
                             :: "v"((f32x4*)ap), "v"(o) : "memory");
            }
            asm volatile("s_waitcnt vmcnt(0)" ::: "memory");
            if (tid == 0 && step < 128)
                __hip_atomic_store(&flags[fid * FSTR], step + 1,
                                   __ATOMIC_RELAXED, __HIP_MEMORY_SCOPE_AGENT);
        }
    }
}

// ---------------------------------------------------------------------------
// Fused GAT layer (coef + softmax + aggregate), one block per (b,h).
template<int RESMODE>
__global__ __launch_bounds__(512) void k_gat_fused(const int* __restrict__ esrc, const int* __restrict__ edst,
                                                   const float* __restrict__ h1,
                                                   const float* __restrict__ asrc, const float* __restrict__ adst,
                                                   const float* __restrict__ gbias,
                                                   const float* __restrict__ res, float* __restrict__ out)
{
    __shared__ int se[384], de[384];
    __shared__ float asl[128], adl[128], ml[128], dl_[128];
    int bh = blockIdx.x;
    int b = bh >> 3, h = bh & 7;
    int t = threadIdx.x;
    if (t < 384) {
        if (t < E256) { se[t] = esrc[b * E256 + t]; de[t] = edst[b * E256 + t]; }
        else          { se[t] = t - E256;           de[t] = t - E256; }
    }
    int node = t >> 2, ch = t & 3;
    int dd0 = ch * 25;
    {
        const float* hp = h1 + (size_t)(b * S128 + node) * H800 + h * 100 + dd0;
        const float* ap = asrc + h * 100 + dd0;
        const float* dp = adst + h * 100 + dd0;
        float s1 = 0.f, s2 = 0.f;
        #pragma unroll
        for (int q = 0; q < 25; q++) { float hv = hp[q]; s1 += hv * ap[q]; s2 += hv * dp[q]; }
        s1 += __shfl_xor(s1, 1, 64); s1 += __shfl_xor(s1, 2, 64);
        s2 += __shfl_xor(s2, 1, 64); s2 += __shfl_xor(s2, 2, 64);
        if (ch == 0) { asl[node] = s1; adl[node] = s2; }
    }
    __syncthreads();
    if (t < 128) {
        float myad = adl[t];
        float m = -3.4e38f;
        for (int e = 0; e < 384; e++)
            if (de[e] == t) {
                float sc = asl[se[e]] + myad;
                sc = (sc > 0.f) ? sc : 0.2f * sc;
                m = fmaxf(m, sc);
            }
        float den = 0.f;
        for (int e = 0; e < 384; e++)
            if (de[e] == t) {
                float sc = asl[se[e]] + myad;
                sc = (sc > 0.f) ? sc : 0.2f * sc;
                den += __expf(sc - m);
            }
        ml[t] = m; dl_[t] = den;
    }
    __syncthreads();
    float acc[25] = {};
    float myad = adl[node], mym = ml[node];
    for (int e = 0; e < 384; e++) {
        if (de[e] == node) {
            int s = se[e];
            float sc = asl[s] + myad;
            sc = (sc > 0.f) ? sc : 0.2f * sc;
            float w = __expf(sc - mym);
            const float* hp = h1 + (size_t)(b * S128 + s) * H800 + h * 100 + dd0;
            #pragma unroll
            for (int q = 0; q < 25; q++) acc[q] += w * hp[q];
        }
    }
    float inv = 1.f / dl_[node];
    int n = b * S128 + node;
    size_t rrow = (RESMODE == 1) ? (size_t)(n + b + 1) * H800 : (size_t)n * H800;
    #pragma unroll
    for (int q = 0; q < 25; q++) {
        int col = h * 100 + dd0 + q;
        float v = acc[q] * inv + gbias[col];
        out[(size_t)n * H800 + col] = res[rrow + col] + fmaxf(v, 0.f);
    }
}

// ---------------------------------------------------------------------------
// Trig head, diagonal only. uv stride 1600: u = row, v = row+800.
__global__ __launch_bounds__(64) void k_trig(const float* __restrict__ uv,
                                             const float* __restrict__ W, const float* __restrict__ bias,
                                             const int* __restrict__ labels, float* __restrict__ d_out)
{
    __shared__ float s[800];
    __shared__ float lg[66];
    int bi = blockIdx.x;          // b*128+i
    int i = bi & 127;
    int l = threadIdx.x;
    const float* ur = uv + (size_t)bi * 1600;
    const float* vr = ur + 800;
    for (int k = l; k < 800; k += 64) s[k] = gelu_f(ur[k] + vr[k]);
    __syncthreads();
    float a0 = 0.f, a1 = 0.f;
    bool has2 = (l < 2);
    for (int k = 0; k < 800; k++) {
        float sv = s[k];
        a0 += sv * W[k * NE + l];
        if (has2) a1 += sv * W[k * NE + 64 + l];
    }
    lg[l] = a0 + bias[l];
    if (has2) lg[64 + l] = a1 + bias[64 + l];
    __syncthreads();
    if (l == 0) {
        float m = lg[0];
        for (int c = 1; c < NE; c++) m = fmaxf(m, lg[c]);
        float se = 0.f, sl = 0.f, bv = lg[0];
        int am = 0;
        for (int c = 0; c < NE; c++) {
            se += __expf(lg[c] - m);
            sl += lg[c];
            if (lg[c] > bv) { bv = lg[c]; am = c; }
        }
        float lse = m + __logf(se);
        int tgt = labels[(size_t)bi * S128 + i];
        float ce = (0.1f / NE) * (NE * lse - sl) + 0.9f * (lse - lg[tgt]);
        atomicAdd(d_out, ce * (1.f / 128.f));
        int r = bi * S128 + i;
        d_out[1 + r] = (float)am;
        d_out[1 + 65536 + r] = (float)am;
    }
}

// ---------------------------------------------------------------------------
// Fused rs+re logits, TWO batches per launch (blockIdx.y). uv stride 1600.
__global__ __launch_bounds__(256) void k_logits2(const float* __restrict__ uvb,
                                                 const float* __restrict__ rsW, const float* __restrict__ rsb,
                                                 const float* __restrict__ reW, const float* __restrict__ reb,
                                                 float* __restrict__ L)
{
    __shared__ float As[16][68];
    __shared__ float Bs[16][256];
    int bi = blockIdx.y;
    const float* base = uvb + (size_t)bi * 128 * 1600;
    float* Lb = L + (size_t)bi * 16384 * 256;
    int il = blockIdx.x >> 1;
    int j0 = (blockIdx.x & 1) * 64;
    const float* urow = base + (size_t)il * 1600;
    int tid = threadIdx.x;
    int tm = tid & 7, tn = tid >> 3;        // rows tm*8..+7, cols tn*8..+7
    float acc[8][8] = {};
    int ct = tid;
    int hc = (ct < 128) ? ct : (ct - 128);
    const float* Wp = (ct < 128) ? rsW : reW;
    bool cok = hc < NR;
    for (int k0 = 0; k0 < 800; k0 += 16) {
        {
            int kk = tid & 15, rrb = tid >> 4;
            float uk = urow[k0 + kk];
            #pragma unroll
            for (int q = 0; q < 4; q++) {
                int rr = rrb + q * 16;
                float xv = uk + base[(size_t)(j0 + rr) * 1600 + 800 + k0 + kk];
                As[kk][rr] = gelu_f(xv);
            }
        }
        #pragma unroll
        for (int kk2 = 0; kk2 < 16; kk2++)
            Bs[kk2][ct] = cok ? Wp[(size_t)(k0 + kk2) * NR + hc] : 0.f;
        __syncthreads();
        #pragma unroll
        for (int kk = 0; kk < 16; kk++) {
            float4 a0 = *(const float4*)&As[kk][tm * 8];
            float4 a1 = *(const float4*)&As[kk][tm * 8 + 4];
            float4 b0 = *(const float4*)&Bs[kk][tn * 8];
            float4 b1 = *(const float4*)&Bs[kk][tn * 8 + 4];
            float av[8] = {a0.x, a0.y, a0.z, a0.w, a1.x, a1.y, a1.z, a1.w};
            float bv[8] = {b0.x, b0.y, b0.z, b0.w, b1.x, b1.y, b1.z, b1.w};
            #pragma unroll
            for (int xx = 0; xx < 8; xx++)
                #pragma unroll
                for (int yy = 0; yy < 8; yy++)
                    acc[xx][yy] += av[xx] * bv[yy];
        }
        __syncthreads();
    }
    int head = tn >> 4;
    const float* bp = head ? reb : rsb;
    #pragma unroll
    for (int xx = 0; xx < 8; xx++) {
        int r = il * S128 + j0 + tm * 8 + xx;
        float* Lr = Lb + (size_t)r * 256 + tn * 8;
        #pragma unroll
        for (int hf = 0; hf < 2; hf++) {
            int c = (tn * 8 + hf * 4) & 127;
            if (c + 3 < NR) {
                float4 o = make_float4(acc[xx][hf*4+0] + bp[c+0], acc[xx][hf*4+1] + bp[c+1],
                                       acc[xx][hf*4+2] + bp[c+2], acc[xx][hf*4+3] + bp[c+3]);
                *(float4*)(Lr + hf * 4) = o;
            } else {
                #pragma unroll
                for (int q = 0; q < 4; q++)
                    if (c + q < NR) Lr[hf * 4 + q] = acc[xx][hf*4+q] + bp[c+q];
            }
        }
    }
}

// CE loss + symmetric argmax, both heads, batch PAIR (32768 rows).
__global__ __launch_bounds__(256) void k_loss2(const float* __restrict__ L,
                                               const int* __restrict__ lab0, const int* __restrict__ lab1,
                                               float* __restrict__ res0, float* __restrict__ res1,
                                               float* __restrict__ lossptr)
{
    __shared__ float wsum[4];
    int wv = threadIdx.x >> 6, l = threadIdx.x & 63;
    int rr = blockIdx.x * 4 + wv;         // [0, 32768)
    int bi = rr >> 14;
    int r = rr & 16383;
    int i = r >> 7, j = r & 127;
    size_t bioff = (size_t)bi * 16384;
    float ces = 0.f;
    if (i != j) {
        const float* row  = L + (bioff + r) * 256;
        const float* prow = L + (bioff + ((j << 7) | i)) * 256;
        bool v2 = (l < NR - 64);
        #pragma unroll
        for (int hd = 0; hd < 2; hd++) {
            const float* rw = row + hd * 128;
            const float* pw = prow + hd * 128;
            float x1 = rw[l];
            float x2 = v2 ? rw[l + 64] : -3.4e38f;
            float m = fmaxf(x1, x2);
            #pragma unroll
            for (int s = 32; s; s >>= 1) m = fmaxf(m, __shfl_xor(m, s, 64));
            float se = __expf(x1 - m) + (v2 ? __expf(x2 - m) : 0.f);
            float sl = x1 + (v2 ? x2 : 0.f);
            #pragma unroll
            for (int s = 32; s; s >>= 1) { se += __shfl_xor(se, s, 64); sl += __shfl_xor(sl, s, 64); }
            float lse = m + __logf(se);
            int tgt = (hd ? lab1 : lab0)[bioff + r];
            float lt = rw[tgt];
            ces += (0.1f / NR) * (NR * lse - sl) + 0.9f * (lse - lt);
            float y1 = x1 + pw[l];
            float y2 = v2 ? (x2 + pw[l + 64]) : -3.4e38f;
            float bv; int bidx;
            if (y2 > y1) { bv = y2; bidx = l + 64; } else { bv = y1; bidx = l; }
            #pragma unroll
            for (int s = 32; s; s >>= 1) {
                float ov = __shfl_xor(bv, s, 64);
                int oi = __shfl_xor(bidx, s, 64);
                if (ov > bv || (ov == bv && oi < bidx)) { bv = ov; bidx = oi; }
            }
            if (l == 0) (hd ? res1 : res0)[bioff + r] = (float)bidx;
        }
    }
    if (l == 0) wsum[wv] = ces;
    __syncthreads();
    if (threadIdx.x == 0) {
        float s = (wsum[0] + wsum[1] + wsum[2] + wsum[3]) * (1.f / 16256.f);
        atomicAdd(lossptr, s);
    }
}

// ---------------------------------------------------------------------------
extern "C" void kernel_launch(void* const* d_in, const int* in_sizes, int n_in,
                              void* d_out, int out_size, void* d_ws, size_t ws_size,
                              hipStream_t stream)
{
    (void)in_sizes; (void)n_in; (void)out_size; (void)ws_size;
    const float* bert  = (const float*)d_in[0];
    const int*   pids  = (const int*)d_in[1];
    const int*   esrc  = (const int*)d_in[2];
    const int*   edst  = (const int*)d_in[3];
    const int*   slab  = (const int*)d_in[4];
    const int*   elab  = (const int*)d_in[5];
    const float* ptab  = (const float*)d_in[6];
    const float* Wih_f = (const float*)d_in[7];
    const float* Whh_f = (const float*)d_in[8];
    const float* bl_f  = (const float*)d_in[9];
    const float* Wih_b = (const float*)d_in[10];
    const float* Whh_b = (const float*)d_in[11];
    const float* bl_b  = (const float*)d_in[12];
    const float* fcW   = (const float*)d_in[13];
    const float* fcb   = (const float*)d_in[14];
    const float* tW    = (const float*)d_in[15];
    const float* tb    = (const float*)d_in[16];
    const float* gatW  = (const float*)d_in[17];
    const float* asrc  = (const float*)d_in[18];
    const float* adst  = (const float*)d_in[19];
    const float* gbias = (const float*)d_in[20];
    const float* trigW = (const float*)d_in[21];
    const float* trigb = (const float*)d_in[22];
    const float* rsW   = (const float*)d_in[23];
    const float* rsb   = (const float*)d_in[24];
    const float* reW   = (const float*)d_in[25];
    const float* reb   = (const float*)d_in[26];
    float* out = (float*)d_out;

    float* ws = (float*)d_ws;
    size_t off = 0;
    auto alloc = [&](size_t n) { float* p = ws + off; off += (n + 255) & ~(size_t)255; return p; };
    float* uv    = alloc((size_t)512 * 1600);     // live late (trig/logits)
    int*   flags = (int*)alloc(2 * NWGD * FSTR);  // one 128B line per flag
    float* R     = ws + off;                      // overlay region
    size_t roff = 0;
    auto ralloc = [&](size_t n) { float* p = R + roff; roff += (n + 255) & ~(size_t)255; return p; };
    float* xW   = ralloc((size_t)516 * 6400);
    float* lstm = ralloc((size_t)516 * 1600);
    float* xg   = ralloc(516 * 800);
    float* h1   = ralloc(512 * 800);
    float* g1   = ralloc(512 * 800);
    float* g2   = ralloc(512 * 800);
    float* Lbuf = R;   // overlays dead temps; 2 batches x 16384 x 256 floats

    hipMemsetAsync(d_out, 0, 4, stream);                 // loss accumulator
    hipMemsetAsync(flags, 0, 2 * NWGD * FSTR * sizeof(int), stream);

    // merged gate-input precompute with fused embed
    k_gemm_wih<<<dim3(9, 100), 256, 0, stream>>>(bert, pids, ptab, Wih_f, Wih_b, bl_f, bl_b, xW);

    k_lstm<<<2 * NWGD, 256, 0, stream>>>(xW, Whh_f, Whh_b, lstm, flags);

    // xg = embed(x) + relu(lstm @ fcW + fcb)
    k_gemm_fc<<<dim3(9, 13), 256, 0, stream>>>(lstm, fcW, fcb, bert, pids, ptab, xg);

    // GAT layer 1 (input = xg[:,1:,:] view)
    k_gemm<1, 0, 0><<<dim3(8, 13), 256, 0, stream>>>(xg, gatW, nullptr, nullptr, h1, 512, 800, 800);
    k_gat_fused<1><<<32, 512, 0, stream>>>(esrc, edst, h1, asrc, adst, gbias, xg, g1);
    // GAT layer 2
    k_gemm<0, 0, 0><<<dim3(8, 13), 256, 0, stream>>>(g1, gatW, nullptr, nullptr, h1, 512, 800, 800);
    k_gat_fused<0><<<32, 512, 0, stream>>>(esrc, edst, h1, asrc, adst, gbias, g1, g2);

    // merged table split: uv[512][1600] (u | v)
    k_gemm_uv<<<dim3(8, 25), 256, 0, stream>>>(g2, tW, tb, uv);

    // trig head (diag)
    k_trig<<<512, 64, 0, stream>>>(uv, trigW, trigb, slab, out);

    // rs+re heads, 2 batches per pass
    for (int bp = 0; bp < 2; bp++) {
        k_logits2<<<dim3(256, 2), 256, 0, stream>>>(uv + (size_t)bp * 2 * 128 * 1600,
                                                    rsW, rsb, reW, reb, Lbuf);
        k_loss2<<<8192, 256, 0, stream>>>(Lbuf,
                                          slab + (size_t)bp * 2 * 16384, elab + (size_t)bp * 2 * 16384,
                                          out + 1 + (size_t)bp * 2 * 16384,
                                          out + 1 + 65536 + (size_t)bp * 2 * 16384, out);
    }
}